// Round 2
// baseline (21745.410 us; speedup 1.0000x reference)
//
#include <hip/hip_runtime.h>
#include <hip/hip_bf16.h>

// GraphProcessor: S=16,B=64,C=128,H=W=11,P=121, 3 iterations.
// All big intermediates stored bf16 (compute f32). ws need: ~100-115MB.
#define S_   16
#define B_   64
#define SBn  1024
#define C_   128
#define P_   121
#define CP_  15488
static const long NEl = 15859712L; // SBn*CP_

typedef __hip_bfloat16 bf16t;

__device__ __forceinline__ float ldb(const bf16t* p){ return __bfloat162float(*p); }
__device__ __forceinline__ bf16t f2b(float v){ return __float2bfloat16(v); }

// ---------- dtype detect: flag=1 if inputs are f32, 0 if bf16 ----------
__global__ void detect_kernel(const unsigned short* __restrict__ x, int* __restrict__ flag){
    if(blockIdx.x==0 && threadIdx.x==0){
        int crazy=0;
        for(int i=0;i<512;i++){
            unsigned e=(x[i]>>7)&0xFF;
            if(e!=0 && (e<64 || e>191)) crazy++;
        }
        *flag = (crazy>40)?1:0;
    }
}

// ---------- convert input to f32 (weights) ----------
__global__ void cvt_kernel(float* __restrict__ dst, const void* __restrict__ src, long n, const int* __restrict__ flag){
    long i=(long)blockIdx.x*blockDim.x+threadIdx.x;
    long st=(long)gridDim.x*blockDim.x;
    int f=*flag;
    if(f){
        const float* s=(const float*)src;
        for(;i<n;i+=st) dst[i]=s[i];
    }else{
        const unsigned short* s=(const unsigned short*)src;
        for(;i<n;i+=st){ unsigned u=((unsigned)s[i])<<16; dst[i]=__uint_as_float(u); }
    }
}

// ---------- convert input to bf16 (x) ----------
__global__ void cvtb_kernel(bf16t* __restrict__ dst, const void* __restrict__ src, long n, const int* __restrict__ flag){
    long i=(long)blockIdx.x*blockDim.x+threadIdx.x;
    long st=(long)gridDim.x*blockDim.x;
    int f=*flag;
    if(f){
        const float* s=(const float*)src;
        for(;i<n;i+=st) dst[i]=f2b(s[i]);
    }else{
        const unsigned short* s=(const unsigned short*)src;
        bf16t* d=dst;
        for(;i<n;i+=st){ ((unsigned short*)d)[i]=s[i]; }
    }
}

// ---------- fold w_lin @ w_msg[:, :C] into W2, and edge bias into b2l/b2r ----------
__global__ __launch_bounds__(128) void prep_msg_kernel(float* __restrict__ W2, float* __restrict__ b2l, float* __restrict__ b2r,
                                                       const float* __restrict__ wlin, const float* __restrict__ wmsg, const float* __restrict__ bmsg){
    int d=blockIdx.x, c=threadIdx.x;
    float acc=0.f;
    for(int o2=0;o2<C_;o2++) acc += wlin[d*C_+o2]*wmsg[o2*(C_+1)+c];
    W2[d*C_+c]=acc;
    if(c<2){
        float e=(c==0)?1.f:-1.f; float a=0.f;
        for(int o2=0;o2<C_;o2++) a += wlin[d*C_+o2]*(bmsg[o2]+e*wmsg[o2*(C_+1)+C_]);
        if(c==0) b2l[d]=a; else b2r[d]=a;
    }
}

// ---------- generic conv: KS=1 (channel matmul, optional S-shift) / KS=3 (SAME 3x3, concat in0|in1) ----------
// MODE 0: out = acc+bias
// MODE 1 (zr): oc<C -> out(Z)=sigmoid ; oc>=C -> aux0(RH)=sigmoid*in1   (Cout=256, gridDim.y=2)
// MODE 2 (hhat): out(NH) = (1-z)*h + z*tanh(acc+bias) + h, z=aux0, h=aux1  (out may alias in0)
template<int KS, int ICC, int MODE>
__global__ __launch_bounds__(256) void convgen(
        bf16t* __restrict__ out, const bf16t* __restrict__ in0, const bf16t* __restrict__ in1,
        const float* __restrict__ W, const float* __restrict__ bias, int shift,
        bf16t* __restrict__ aux0, const bf16t* __restrict__ aux1)
{
    constexpr int CIN  = (KS==3)?256:128;
    constexpr int KK   = KS*KS;
    constexpr int TILE = (KS==3)?169:P_;   // 13x13 padded or 121
    constexpr int LWSTR= ICC*KK+1;         // +1 pad: bank-conflict-free weight rows
    __shared__ float lin[ICC*TILE];
    __shared__ float lw[128*LWSTR];
    int sb=blockIdx.x;
    int ocbase=blockIdx.y*128;
    int t=threadIdx.x;
    int ocg=t>>4, pg=t&15;          // 16 oc-groups x 8 oc ; 16 pixel-groups x 8 px
    int off[8]; int pp[8];
    #pragma unroll
    for(int j=0;j<8;j++){
        int p=pg*8+j; pp[j]=p;
        int pc=(p<P_)?p:(P_-1);     // clamp: invalid pixels read valid LDS, results discarded
        off[j]=(KS==3)? ((pc/11)*13+(pc%11)) : pc;
    }
    float acc[8][8];
    #pragma unroll
    for(int j=0;j<8;j++){
        #pragma unroll
        for(int k=0;k<8;k++) acc[j][k]=0.f;
    }

    int ssb=sb+shift;
    bool vsrc=(ssb>=0 && ssb<SBn);
    const bf16t* src0 = in0 + (size_t)(vsrc?ssb:0)*CP_;
    const bf16t* src1c = (KS==3)? (in1 + (size_t)sb*CP_) : (const bf16t*)nullptr;

    for(int ic0=0; ic0<CIN; ic0+=ICC){
        __syncthreads();
        if(KS==3){
            for(int i=t;i<ICC*169;i+=256){
                int ch=i/169, r=i-ch*169;
                int py=r/13-1, px=(r-(r/13)*13)-1;
                float v=0.f;
                if(py>=0&&py<11&&px>=0&&px<11){
                    int gic=ic0+ch;
                    const bf16t* sp=(gic<128)? (in0+(size_t)sb*CP_+(size_t)gic*P_)
                                             : (src1c+(size_t)(gic-128)*P_);
                    v=ldb(sp+py*11+px);
                }
                lin[i]=v;
            }
        }else{
            for(int i=t;i<ICC*P_;i+=256){
                int ch=i/P_, r=i-ch*P_;
                lin[i]= vsrc ? ldb(src0+(size_t)(ic0+ch)*P_+r) : 0.f;
            }
        }
        for(int i=t;i<128*ICC*KK;i+=256){
            int oc=i/(ICC*KK), r=i-oc*(ICC*KK);
            lw[oc*LWSTR+r] = W[(size_t)(ocbase+oc)*CIN*KK + (size_t)ic0*KK + r];
        }
        __syncthreads();

        for(int ic=0; ic<ICC; ic++){
            if(KS==3){
                #pragma unroll
                for(int tap=0; tap<9; tap++){
                    float w[8];
                    #pragma unroll
                    for(int k=0;k<8;k++) w[k]=lw[(ocg*8+k)*LWSTR + ic*9 + tap];
                    int d=(tap/3)*13+(tap%3);
                    #pragma unroll
                    for(int j=0;j<8;j++){
                        float v=lin[ic*169 + off[j] + d];
                        #pragma unroll
                        for(int k=0;k<8;k++) acc[j][k]=fmaf(w[k],v,acc[j][k]);
                    }
                }
            }else{
                float w[8];
                #pragma unroll
                for(int k=0;k<8;k++) w[k]=lw[(ocg*8+k)*LWSTR + ic];
                #pragma unroll
                for(int j=0;j<8;j++){
                    float v=lin[ic*P_ + off[j]];
                    #pragma unroll
                    for(int k=0;k<8;k++) acc[j][k]=fmaf(w[k],v,acc[j][k]);
                }
            }
        }
    }

    #pragma unroll
    for(int j=0;j<8;j++){
        int p=pp[j];
        if(p>=P_) continue;
        #pragma unroll
        for(int k=0;k<8;k++){
            int oc=ocbase+ocg*8+k;
            float a=acc[j][k]+bias[oc];
            if(MODE==0){
                out[(size_t)sb*CP_+(size_t)oc*P_+p]=f2b(a);
            }else if(MODE==1){
                float sg=1.f/(1.f+__expf(-a));
                if(oc<C_) out[(size_t)sb*CP_+(size_t)oc*P_+p]=f2b(sg);
                else{ size_t ii=(size_t)sb*CP_+(size_t)(oc-C_)*P_+p; aux0[ii]=f2b(sg*ldb(in1+ii)); }
            }else{
                float ht=tanhf(a);
                size_t ii=(size_t)sb*CP_+(size_t)oc*P_+p;
                float z=ldb(aux0+ii); float hv=ldb(aux1+ii);
                out[ii]=f2b((1.f-z)*hv + z*ht + hv);   // h_new + h
            }
        }
    }
}

// ---------- attention logits+softmax: att[p][j] = softmax_j( scale * sum_c q[c,p]*k[c,j] ) ----------
__global__ __launch_bounds__(256) void attn_kernel(float* __restrict__ att, const bf16t* __restrict__ qb,
                                                   const bf16t* __restrict__ kb, float scale, int sb0){
    __shared__ float lk[P_*129];   // k transposed, stride 129 -> conflict-free
    __shared__ float red[8];
    int lb=blockIdx.x, sb=lb+sb0, t=threadIdx.x;
    const bf16t* kp=kb+(size_t)sb*CP_;
    for(int i=t;i<CP_;i+=256){ int c=i/P_, j=i-c*P_; lk[j*129+c]=ldb(kp+i); }
    __syncthreads();
    int grp=t>>7, j=t&127, wid=t>>6;
    const bf16t* qp=qb+(size_t)sb*CP_;
    float* ap=att+(size_t)lb*P_*P_;
    for(int p0=0;p0<P_;p0+=2){
        int p=p0+grp;
        bool act=(p<P_)&&(j<P_);
        float acc=0.f;
        if(act){
            const float* lkr=lk+j*129;
            #pragma unroll 8
            for(int c=0;c<C_;c++) acc += ldb(qp+(size_t)c*P_+p)*lkr[c];
        }
        float lg = act? acc*scale : -3.0e38f;
        float mx=lg;
        #pragma unroll
        for(int o2=32;o2;o2>>=1) mx=fmaxf(mx,__shfl_xor(mx,o2));
        if((t&63)==0) red[wid]=mx;
        __syncthreads();
        mx=fmaxf(red[grp*2],red[grp*2+1]);
        float e = act? __expf(lg-mx) : 0.f;
        float sm=e;
        #pragma unroll
        for(int o2=32;o2;o2>>=1) sm+=__shfl_xor(sm,o2);
        if((t&63)==0) red[4+wid]=sm;
        __syncthreads();
        sm=red[4+grp*2]+red[4+grp*2+1];
        if(act) ap[p*P_+j]=e/sm;
        __syncthreads();
    }
}

// ---------- out[c,p] = alpha * sum_j att[p,j]*v[c,j] (+ resid). SAFE for out==vb. ----------
__global__ __launch_bounds__(256) void av_kernel(bf16t* __restrict__ out, const float* __restrict__ att,
                                                 const bf16t* __restrict__ vb, const bf16t* __restrict__ resid,
                                                 const float* __restrict__ alphap, int sb0){
    __shared__ float la[P_*P_];
    __shared__ float vrow[2][P_+1];
    int lb=blockIdx.x, sb=lb+sb0, t=threadIdx.x;
    const float* ap=att+(size_t)lb*P_*P_;
    for(int i=t;i<P_*P_;i+=256) la[i]=ap[i];
    float al = alphap? *alphap : 1.f;
    int p=t&127, ch=t>>7;
    const bf16t* vbase=vb+(size_t)sb*CP_;
    bf16t* obase=out+(size_t)sb*CP_;
    const bf16t* rbase = resid? resid+(size_t)sb*CP_ : (const bf16t*)nullptr;
    for(int c0=0;c0<C_;c0+=2){
        __syncthreads();                 // (first pass: also covers la staging)
        if(t<2*P_){ int cc=t/P_, jj=t-cc*P_; vrow[cc][jj]=ldb(vbase+(size_t)(c0+cc)*P_+jj); }
        __syncthreads();
        if(p<P_){
            const float* lar=la+p*P_;
            float acc=0.f;
            #pragma unroll 8
            for(int j=0;j<P_;j++) acc+=lar[j]*vrow[ch][j];
            size_t oi=(size_t)(c0+ch)*P_+p;
            float r = rbase? (al*acc+ldb(rbase+oi)) : acc;
            obase[oi]=f2b(r);
        }
    }
}

// ---------- g[o] = sigmoid( b_gate[o] + sum_c w_gate[o,c] * mean_p m[c,p] ) ----------
__global__ __launch_bounds__(128) void gate_kernel(float* __restrict__ g, const bf16t* __restrict__ m,
                                                   const float* __restrict__ wg, const float* __restrict__ bg){
    __shared__ float mb[C_];
    int sb=blockIdx.x, t=threadIdx.x;
    const bf16t* mp=m+(size_t)sb*CP_+(size_t)t*P_;
    float s=0.f;
    for(int j=0;j<P_;j++) s+=ldb(mp+j);
    mb[t]=s*(1.f/(float)P_);
    __syncthreads();
    const float* wr=wg+(size_t)t*C_;
    float acc=bg[t];
    #pragma unroll 8
    for(int c2=0;c2<C_;c2++) acc+=wr[c2]*mb[c2];
    g[(size_t)sb*C_+t]=1.f/(1.f+__expf(-acc));
}

// ---------- inter = (accum? inter:0) + m*g*mask  (inter may alias m) ----------
__global__ void apply_gate_kernel(bf16t* __restrict__ inter, const bf16t* __restrict__ m,
                                  const float* __restrict__ g, int isleft, int accum){
    long idx=(long)blockIdx.x*blockDim.x+threadIdx.x;
    long st=(long)gridDim.x*blockDim.x;
    for(; idx<NEl; idx+=st){
        int sb=(int)(idx/CP_);
        int c=(int)((idx-(long)sb*CP_)/P_);
        int s=sb>>6;
        bool on = isleft ? (s>=1) : (s<=S_-2);
        float v = on ? ldb(m+idx)*g[sb*C_+c] : 0.f;
        inter[idx] = f2b(accum ? ldb(inter+idx)+v : v);
    }
}

// ---------- a = w*a + (1-w)*inter ----------
__global__ void comb_kernel(bf16t* __restrict__ a, const bf16t* __restrict__ inter, const float* __restrict__ wptr){
    float w=*wptr;
    long idx=(long)blockIdx.x*blockDim.x+threadIdx.x;
    long st=(long)gridDim.x*blockDim.x;
    for(; idx<NEl; idx+=st) a[idx]=f2b(w*ldb(a+idx)+(1.f-w)*ldb(inter+idx));
}

// ---------- LayerNorm over (C,H,W) per (s,b); writes h and final output on last iter ----------
__global__ __launch_bounds__(256) void ln_kernel(bf16t* __restrict__ hout, void* __restrict__ fout,
                                                 const bf16t* __restrict__ nh, const float* __restrict__ gam,
                                                 const float* __restrict__ bet, int last, const int* __restrict__ flag){
    __shared__ float rbuf[8];
    int sb=blockIdx.x, t=threadIdx.x;
    const bf16t* src=nh+(size_t)sb*CP_;
    float s=0.f,s2=0.f;
    for(int i=t;i<CP_;i+=256){ float v=ldb(src+i); s+=v; s2+=v*v; }
    #pragma unroll
    for(int o2=32;o2;o2>>=1){ s+=__shfl_xor(s,o2); s2+=__shfl_xor(s2,o2); }
    int wid=t>>6;
    if((t&63)==0){ rbuf[wid]=s; rbuf[4+wid]=s2; }
    __syncthreads();
    float S=rbuf[0]+rbuf[1]+rbuf[2]+rbuf[3];
    float S2=rbuf[4]+rbuf[5]+rbuf[6]+rbuf[7];
    float mu=S*(1.f/(float)CP_);
    float var=S2*(1.f/(float)CP_)-mu*mu;
    float rstd=rsqrtf(var+1e-5f);
    int f = last ? *flag : 0;
    bf16t* ho=hout+(size_t)sb*CP_;
    for(int i=t;i<CP_;i+=256){
        float v=(ldb(src+i)-mu)*rstd*gam[i]+bet[i];
        ho[i]=f2b(v);
        if(last){
            size_t oi=(size_t)sb*CP_+i;
            if(f) ((float*)fout)[oi]=v;
            else  ((bf16t*)fout)[oi]=f2b(v);
        }
    }
}

extern "C" void kernel_launch(void* const* d_in, const int* in_sizes, int n_in,
                              void* d_out, int out_size, void* d_ws, size_t ws_size,
                              hipStream_t stream) {
    (void)in_sizes; (void)n_in; (void)out_size;
    char* base=(char*)d_ws;
    size_t off=0;
    auto alloc=[&](size_t bytes){ void* p=base+off; off+=(bytes+255)&~(size_t)255; return p; };
    bf16t* hbuf=(bf16t*)alloc((size_t)NEl*2);
    bf16t* A   =(bf16t*)alloc((size_t)NEl*2);   // q / intra / comb / NH
    bf16t* Bb  =(bf16t*)alloc((size_t)NEl*2);   // k / yy / m_right / Z
    bf16t* D   =(bf16t*)d_out;                  // v / m_left / inter / RH / final
    float* wqf=(float*)alloc(16384*4); float* bqf=(float*)alloc(128*4);
    float* wkf=(float*)alloc(16384*4); float* bkf=(float*)alloc(128*4);
    float* wvf=(float*)alloc(16384*4); float* bvf=(float*)alloc(128*4);
    float* wgf=(float*)alloc(16384*4); float* bgf=(float*)alloc(128*4);
    float* wzrf=(float*)alloc(589824*4); float* bzrf=(float*)alloc(256*4);
    float* whf=(float*)alloc(294912*4);  float* bhf=(float*)alloc(128*4);
    float* gamf=(float*)alloc(15488*4);  float* betf=(float*)alloc(15488*4);
    float* wmsgf=(float*)alloc(16512*4); float* wlinf=(float*)alloc(16384*4); float* bmsgf=(float*)alloc(128*4);
    float* W2=(float*)alloc(16384*4); float* b2l=(float*)alloc(128*4); float* b2r=(float*)alloc(128*4);
    float* alphaf=(float*)alloc(4); float* weightf=(float*)alloc(4);
    float* gbuf=(float*)alloc((size_t)SBn*C_*4);
    int* flag=(int*)alloc(4);
    // att chunk: use whatever ws remains (deterministic for fixed ws_size)
    size_t rem = (ws_size>off)? ws_size-off : 0;
    int CH = (int)(rem/((size_t)P_*P_*4));
    if(CH>SBn) CH=SBn;
    if(CH<16) return;  // ws too small even for minimal layout (~102MB)
    float* att=(float*)alloc((size_t)CH*P_*P_*4);

    detect_kernel<<<1,64,0,stream>>>((const unsigned short*)d_in[0], flag);
    auto CV=[&](float* dst,int idx,long n){
        int g=(int)((n+255)/256); if(g>4096)g=4096; if(g<1)g=1;
        cvt_kernel<<<g,256,0,stream>>>(dst,d_in[idx],n,flag);
    };
    cvtb_kernel<<<4096,256,0,stream>>>(hbuf,d_in[0],NEl,flag);
    CV(wqf,1,16384);  CV(bqf,2,128);
    CV(wkf,3,16384);  CV(bkf,4,128);
    CV(wvf,5,16384);  CV(bvf,6,128);
    CV(alphaf,7,1);
    CV(wmsgf,8,16512); CV(bmsgf,9,128); CV(wlinf,10,16384);
    CV(weightf,11,1);
    CV(wgf,12,16384); CV(bgf,13,128);
    CV(wzrf,14,589824); CV(bzrf,15,256);
    CV(whf,16,294912);  CV(bhf,17,128);
    CV(gamf,18,15488);  CV(betf,19,15488);
    prep_msg_kernel<<<C_,C_,0,stream>>>(W2,b2l,b2r,wlinf,wmsgf,bmsgf);

    const float scale=0.08838834764831845f; // C^-0.5

    for(int it=0; it<3; ++it){
        // q->A, k->B, v->D
        convgen<1,32,0><<<dim3(SBn,1),256,0,stream>>>(A,hbuf,nullptr,wqf,bqf,0,nullptr,nullptr);
        convgen<1,32,0><<<dim3(SBn,1),256,0,stream>>>(Bb,hbuf,nullptr,wkf,bkf,0,nullptr,nullptr);
        convgen<1,32,0><<<dim3(SBn,1),256,0,stream>>>(D,hbuf,nullptr,wvf,bvf,0,nullptr,nullptr);
        // intra attention: att(q=A,k=B); intra = alpha*att@v(D) + h -> A (per-chunk in place over q)
        for(int s0=0;s0<SBn;s0+=CH){
            int nb=(SBn-s0<CH)?(SBn-s0):CH;
            attn_kernel<<<nb,256,0,stream>>>(att,A,Bb,scale,s0);
            av_kernel<<<nb,256,0,stream>>>(A,att,D,hbuf,alphaf,s0);
        }
        // left message: yy->B (shifted h), m->D, gate, inter=m*g*mask -> D (in place)
        convgen<1,32,0><<<dim3(SBn,1),256,0,stream>>>(Bb,hbuf,nullptr,W2,b2l,-B_,nullptr,nullptr);
        for(int s0=0;s0<SBn;s0+=CH){
            int nb=(SBn-s0<CH)?(SBn-s0):CH;
            attn_kernel<<<nb,256,0,stream>>>(att,hbuf,Bb,1.0f,s0);
            av_kernel<<<nb,256,0,stream>>>(D,att,Bb,nullptr,nullptr,s0);
        }
        gate_kernel<<<SBn,C_,0,stream>>>(gbuf,D,wgf,bgf);
        apply_gate_kernel<<<2048,256,0,stream>>>(D,D,gbuf,1,0);
        // right message: yy->B, m->B (in-place av), inter(D) += m*g*mask
        convgen<1,32,0><<<dim3(SBn,1),256,0,stream>>>(Bb,hbuf,nullptr,W2,b2r,B_,nullptr,nullptr);
        for(int s0=0;s0<SBn;s0+=CH){
            int nb=(SBn-s0<CH)?(SBn-s0):CH;
            attn_kernel<<<nb,256,0,stream>>>(att,hbuf,Bb,1.0f,s0);
            av_kernel<<<nb,256,0,stream>>>(Bb,att,Bb,nullptr,nullptr,s0);   // in place
        }
        gate_kernel<<<SBn,C_,0,stream>>>(gbuf,Bb,wgf,bgf);
        apply_gate_kernel<<<2048,256,0,stream>>>(D,Bb,gbuf,0,1);
        // combine: A = w*A + (1-w)*D
        comb_kernel<<<2048,256,0,stream>>>(A,D,weightf);
        // GRU: zr conv([A,h]) -> Z->B, RH=r*h->D ; hhat conv([A,D]) -> NH->A (in place)
        convgen<3,8,1><<<dim3(SBn,2),256,0,stream>>>(Bb,A,hbuf,wzrf,bzrf,0,D,nullptr);
        convgen<3,8,2><<<dim3(SBn,1),256,0,stream>>>(A,A,D,whf,bhf,0,Bb,hbuf);
        // LayerNorm(NH=A) -> h (and final output to d_out on last iter)
        ln_kernel<<<SBn,256,0,stream>>>(hbuf,d_out,A,gamf,betf,(it==2)?1:0,flag);
    }
}

// Round 3
// 11601.730 us; speedup vs baseline: 1.8743x; 1.8743x over previous
//
#include <hip/hip_runtime.h>
#include <hip/hip_bf16.h>

// GraphProcessor: S=16,B=64,C=128,H=W=11,P=121, 3 iterations.
// bf16 storage, f32 compute. 3x3 convs via MFMA implicit GEMM.
#define S_   16
#define B_   64
#define SBn  1024
#define C_   128
#define P_   121
#define CP_  15488
static const long NEl = 15859712L; // SBn*CP_

typedef __hip_bfloat16 bf16t;
typedef __attribute__((ext_vector_type(8))) short bf16x8;
typedef __attribute__((ext_vector_type(4))) float f32x4;

__device__ __forceinline__ float ldb(const bf16t* p){ return __bfloat162float(*p); }
__device__ __forceinline__ bf16t f2b(float v){ return __float2bfloat16(v); }

// ---------- dtype detect: flag=1 if inputs are f32, 0 if bf16 ----------
__global__ void detect_kernel(const unsigned short* __restrict__ x, int* __restrict__ flag){
    if(blockIdx.x==0 && threadIdx.x==0){
        int crazy=0;
        for(int i=0;i<512;i++){
            unsigned e=(x[i]>>7)&0xFF;
            if(e!=0 && (e<64 || e>191)) crazy++;
        }
        *flag = (crazy>40)?1:0;
    }
}

// ---------- convert input to f32 (weights) ----------
__global__ void cvt_kernel(float* __restrict__ dst, const void* __restrict__ src, long n, const int* __restrict__ flag){
    long i=(long)blockIdx.x*blockDim.x+threadIdx.x;
    long st=(long)gridDim.x*blockDim.x;
    int f=*flag;
    if(f){
        const float* s=(const float*)src;
        for(;i<n;i+=st) dst[i]=s[i];
    }else{
        const unsigned short* s=(const unsigned short*)src;
        for(;i<n;i+=st){ unsigned u=((unsigned)s[i])<<16; dst[i]=__uint_as_float(u); }
    }
}

// ---------- convert input to bf16 (x) ----------
__global__ void cvtb_kernel(bf16t* __restrict__ dst, const void* __restrict__ src, long n, const int* __restrict__ flag){
    long i=(long)blockIdx.x*blockDim.x+threadIdx.x;
    long st=(long)gridDim.x*blockDim.x;
    int f=*flag;
    if(f){
        const float* s=(const float*)src;
        for(;i<n;i+=st) dst[i]=f2b(s[i]);
    }else{
        const unsigned short* s=(const unsigned short*)src;
        for(;i<n;i+=st){ ((unsigned short*)dst)[i]=s[i]; }
    }
}

// ---------- fold w_lin @ w_msg[:, :C] into W2, and edge bias into b2l/b2r ----------
__global__ __launch_bounds__(128) void prep_msg_kernel(float* __restrict__ W2, float* __restrict__ b2l, float* __restrict__ b2r,
                                                       const float* __restrict__ wlin, const float* __restrict__ wmsg, const float* __restrict__ bmsg){
    int d=blockIdx.x, c=threadIdx.x;
    float acc=0.f;
    for(int o2=0;o2<C_;o2++) acc += wlin[d*C_+o2]*wmsg[o2*(C_+1)+c];
    W2[d*C_+c]=acc;
    if(c<2){
        float e=(c==0)?1.f:-1.f; float a=0.f;
        for(int o2=0;o2<C_;o2++) a += wlin[d*C_+o2]*(bmsg[o2]+e*wmsg[o2*(C_+1)+C_]);
        if(c==0) b2l[d]=a; else b2r[d]=a;
    }
}

// ---------- transform conv weight f32 [OC][256][3][3] -> bf16 [tap][OC][256] ----------
__global__ void prep_w3(bf16t* __restrict__ dst, const float* __restrict__ src, int OC){
    int idx=blockIdx.x*blockDim.x+threadIdx.x;
    int tot=OC*256*9;
    if(idx>=tot) return;
    int tap=idx%9; int ic=(idx/9)&255; int oc=idx/(9*256);
    dst[((size_t)tap*OC+oc)*256+ic]=f2b(src[idx]);
}

// ---------- 1x1 conv (channel matmul, optional S-shift), f32 VALU ----------
template<int ICC>
__global__ __launch_bounds__(256) void convgen1(
        bf16t* __restrict__ out, const bf16t* __restrict__ in0,
        const float* __restrict__ W, const float* __restrict__ bias, int shift)
{
    constexpr int LWSTR= ICC+1;
    __shared__ float lin[ICC*P_];
    __shared__ float lw[128*LWSTR];
    int sb=blockIdx.x;
    int t=threadIdx.x;
    int ocg=t>>4, pg=t&15;
    int off[8]; int pp[8];
    #pragma unroll
    for(int j=0;j<8;j++){
        int p=pg*8+j; pp[j]=p;
        off[j]=(p<P_)?p:(P_-1);
    }
    float acc[8][8];
    #pragma unroll
    for(int j=0;j<8;j++){
        #pragma unroll
        for(int k=0;k<8;k++) acc[j][k]=0.f;
    }
    int ssb=sb+shift;
    bool vsrc=(ssb>=0 && ssb<SBn);
    const bf16t* src0 = in0 + (size_t)(vsrc?ssb:0)*CP_;

    for(int ic0=0; ic0<C_; ic0+=ICC){
        __syncthreads();
        for(int i=t;i<ICC*P_;i+=256){
            int ch=i/P_, r=i-ch*P_;
            lin[i]= vsrc ? ldb(src0+(size_t)(ic0+ch)*P_+r) : 0.f;
        }
        for(int i=t;i<128*ICC;i+=256){
            int oc=i/ICC, r=i-oc*ICC;
            lw[oc*LWSTR+r] = W[(size_t)oc*C_ + ic0 + r];
        }
        __syncthreads();
        for(int ic=0; ic<ICC; ic++){
            float w[8];
            #pragma unroll
            for(int k=0;k<8;k++) w[k]=lw[(ocg*8+k)*LWSTR + ic];
            #pragma unroll
            for(int j=0;j<8;j++){
                float v=lin[ic*P_ + off[j]];
                #pragma unroll
                for(int k=0;k<8;k++) acc[j][k]=fmaf(w[k],v,acc[j][k]);
            }
        }
    }
    #pragma unroll
    for(int j=0;j<8;j++){
        int p=pp[j];
        if(p>=P_) continue;
        #pragma unroll
        for(int k=0;k<8;k++){
            int oc=ocg*8+k;
            out[(size_t)sb*CP_+(size_t)oc*P_+p]=f2b(acc[j][k]+bias[oc]);
        }
    }
}

// ---------- 3x3 SAME conv over concat(in0|in1) via MFMA implicit GEMM ----------
// MODE 1 (zr): blockIdx.y=0 -> out(Z)=sigmoid ; y=1 -> aux0(RH)=sigmoid*in1
// MODE 2 (hhat): out(NH) = (1-z)*h + z*tanh(acc+bias) + h, z=aux0, h=aux1 (out may alias in0)
template<int MODE>
__global__ __launch_bounds__(256) void conv3_mfma(
        bf16t* __restrict__ out, const bf16t* __restrict__ in0, const bf16t* __restrict__ in1,
        const bf16t* __restrict__ Wt, const float* __restrict__ bias,
        bf16t* __restrict__ aux0, const bf16t* __restrict__ aux1)
{
    constexpr int OC  = (MODE==1)?256:128;
    constexpr int STR = 136;                  // bf16 elems: 272B = 17*16B (b128-aligned), bank-step 4
    __shared__ bf16t lin[169*STR];            // padded 13x13 tile, [pixel][ic]
    int sb=blockIdx.x;
    int ocbase=blockIdx.y*128;
    int t=threadIdx.x;
    int lane=t&63, w=t>>6;
    int ocr=w>>1, pcr=w&1;                    // 2x2 wave grid
    int col=lane&15, kg=lane>>4;

    int boff[4]; bool pv[4];
    #pragma unroll
    for(int nt=0;nt<4;nt++){
        int p=(pcr*4+nt)*16+col;
        pv[nt]=(p<P_);
        int pc=pv[nt]?p:(P_-1);
        boff[nt]=((pc/11)*13+(pc%11))*STR + kg*8;   // window top-left pixel * stride + k-group
    }
    f32x4 acc[4][4];
    #pragma unroll
    for(int i=0;i<4;i++){
        #pragma unroll
        for(int j=0;j<4;j++) acc[i][j]=(f32x4){0.f,0.f,0.f,0.f};
    }

    // zero the border pixels (48 of them) once
    for(int i2=t;i2<48*128;i2+=256){
        int bi=i2>>7, ic=i2&127;
        int pix;
        if(bi<13) pix=bi;
        else if(bi<26) pix=156+(bi-13);
        else { int j2=bi-26; pix=(1+(j2>>1))*13 + ((j2&1)?12:0); }
        lin[pix*STR+ic]=f2b(0.f);
    }

    const bf16t* srcs[2]={ in0+(size_t)sb*CP_, in1+(size_t)sb*CP_ };

    for(int half=0; half<2; ++half){
        __syncthreads();
        const bf16t* src=srcs[half];
        for(int i2=t;i2<128*P_;i2+=256){
            int ic=i2/P_, p=i2-ic*P_;
            int pix=(p/11+1)*13+(p%11+1);
            lin[pix*STR+ic]=src[(size_t)ic*P_+p];
        }
        __syncthreads();

        for(int tap=0;tap<9;++tap){
            int d=((tap/3)*13+(tap%3))*STR;
            const bf16t* wp = Wt + ((size_t)(tap*OC)+ocbase+ocr*64+col)*256 + half*128 + kg*8;
            #pragma unroll
            for(int icb=0;icb<4;icb++){
                bf16x8 af[4];
                #pragma unroll
                for(int mt=0;mt<4;mt++) af[mt]=*(const bf16x8*)(wp + (size_t)mt*16*256 + icb*32);
                bf16x8 bfv[4];
                #pragma unroll
                for(int nt=0;nt<4;nt++) bfv[nt]=*(const bf16x8*)(lin + boff[nt] + d + icb*32);
                #pragma unroll
                for(int mt=0;mt<4;mt++){
                    #pragma unroll
                    for(int nt=0;nt<4;nt++)
                        acc[mt][nt]=__builtin_amdgcn_mfma_f32_16x16x32_bf16(af[mt],bfv[nt],acc[mt][nt],0,0,0);
                }
            }
        }
    }

    // epilogue: C layout col=lane&15, row=kg*4+r
    #pragma unroll
    for(int mt=0;mt<4;mt++){
        int ocl=(ocr*4+mt)*16 + kg*4;
        #pragma unroll
        for(int nt=0;nt<4;nt++){
            if(!pv[nt]) continue;
            int p=(pcr*4+nt)*16+col;
            #pragma unroll
            for(int r=0;r<4;r++){
                int oc=ocl+r;
                float a=acc[mt][nt][r]+bias[ocbase+oc];
                size_t oi=(size_t)sb*CP_+(size_t)oc*P_+p;
                if(MODE==1){
                    float sg=1.f/(1.f+__expf(-a));
                    if(ocbase==0) out[oi]=f2b(sg);
                    else          aux0[oi]=f2b(sg*ldb(in1+oi));
                }else{
                    float ht=tanhf(a);
                    float z=ldb(aux0+oi), hv=ldb(aux1+oi);
                    out[oi]=f2b((1.f-z)*hv+z*ht+hv);   // h_new + h
                }
            }
        }
    }
}

// ---------- attention logits+softmax ----------
__global__ __launch_bounds__(256) void attn_kernel(float* __restrict__ att, const bf16t* __restrict__ qb,
                                                   const bf16t* __restrict__ kb, float scale, int sb0){
    __shared__ float lk[P_*129];
    __shared__ float red[8];
    int lb=blockIdx.x, sb=lb+sb0, t=threadIdx.x;
    const bf16t* kp=kb+(size_t)sb*CP_;
    for(int i=t;i<CP_;i+=256){ int c=i/P_, j=i-c*P_; lk[j*129+c]=ldb(kp+i); }
    __syncthreads();
    int grp=t>>7, j=t&127, wid=t>>6;
    const bf16t* qp=qb+(size_t)sb*CP_;
    float* ap=att+(size_t)lb*P_*P_;
    for(int p0=0;p0<P_;p0+=2){
        int p=p0+grp;
        bool act=(p<P_)&&(j<P_);
        float acc=0.f;
        if(act){
            const float* lkr=lk+j*129;
            #pragma unroll 8
            for(int c=0;c<C_;c++) acc += ldb(qp+(size_t)c*P_+p)*lkr[c];
        }
        float lg = act? acc*scale : -3.0e38f;
        float mx=lg;
        #pragma unroll
        for(int o2=32;o2;o2>>=1) mx=fmaxf(mx,__shfl_xor(mx,o2));
        if((t&63)==0) red[wid]=mx;
        __syncthreads();
        mx=fmaxf(red[grp*2],red[grp*2+1]);
        float e = act? __expf(lg-mx) : 0.f;
        float sm=e;
        #pragma unroll
        for(int o2=32;o2;o2>>=1) sm+=__shfl_xor(sm,o2);
        if((t&63)==0) red[4+wid]=sm;
        __syncthreads();
        sm=red[4+grp*2]+red[4+grp*2+1];
        if(act) ap[p*P_+j]=e/sm;
        __syncthreads();
    }
}

// ---------- out[c,p] = alpha * sum_j att[p,j]*v[c,j] (+ resid). SAFE for out==vb. ----------
__global__ __launch_bounds__(256) void av_kernel(bf16t* __restrict__ out, const float* __restrict__ att,
                                                 const bf16t* __restrict__ vb, const bf16t* __restrict__ resid,
                                                 const float* __restrict__ alphap, int sb0){
    __shared__ float la[P_*P_];
    __shared__ float vrow[2][P_+1];
    int lb=blockIdx.x, sb=lb+sb0, t=threadIdx.x;
    const float* ap=att+(size_t)lb*P_*P_;
    for(int i=t;i<P_*P_;i+=256) la[i]=ap[i];
    float al = alphap? *alphap : 1.f;
    int p=t&127, ch=t>>7;
    const bf16t* vbase=vb+(size_t)sb*CP_;
    bf16t* obase=out+(size_t)sb*CP_;
    const bf16t* rbase = resid? resid+(size_t)sb*CP_ : (const bf16t*)nullptr;
    for(int c0=0;c0<C_;c0+=2){
        __syncthreads();
        if(t<2*P_){ int cc=t/P_, jj=t-cc*P_; vrow[cc][jj]=ldb(vbase+(size_t)(c0+cc)*P_+jj); }
        __syncthreads();
        if(p<P_){
            const float* lar=la+p*P_;
            float acc=0.f;
            #pragma unroll 8
            for(int j=0;j<P_;j++) acc+=lar[j]*vrow[ch][j];
            size_t oi=(size_t)(c0+ch)*P_+p;
            float r = rbase? (al*acc+ldb(rbase+oi)) : acc;
            obase[oi]=f2b(r);
        }
    }
}

// ---------- g[o] = sigmoid( b_gate[o] + sum_c w_gate[o,c] * mean_p m[c,p] ) ----------
__global__ __launch_bounds__(128) void gate_kernel(float* __restrict__ g, const bf16t* __restrict__ m,
                                                   const float* __restrict__ wg, const float* __restrict__ bg){
    __shared__ float mb[C_];
    int sb=blockIdx.x, t=threadIdx.x;
    const bf16t* mp=m+(size_t)sb*CP_+(size_t)t*P_;
    float s=0.f;
    for(int j=0;j<P_;j++) s+=ldb(mp+j);
    mb[t]=s*(1.f/(float)P_);
    __syncthreads();
    const float* wr=wg+(size_t)t*C_;
    float acc=bg[t];
    #pragma unroll 8
    for(int c2=0;c2<C_;c2++) acc+=wr[c2]*mb[c2];
    g[(size_t)sb*C_+t]=1.f/(1.f+__expf(-acc));
}

// ---------- inter = (accum? inter:0) + m*g*mask  (inter may alias m) ----------
__global__ void apply_gate_kernel(bf16t* __restrict__ inter, const bf16t* __restrict__ m,
                                  const float* __restrict__ g, int isleft, int accum){
    long idx=(long)blockIdx.x*blockDim.x+threadIdx.x;
    long st=(long)gridDim.x*blockDim.x;
    for(; idx<NEl; idx+=st){
        int sb=(int)(idx/CP_);
        int c=(int)((idx-(long)sb*CP_)/P_);
        int s=sb>>6;
        bool on = isleft ? (s>=1) : (s<=S_-2);
        float v = on ? ldb(m+idx)*g[sb*C_+c] : 0.f;
        inter[idx] = f2b(accum ? ldb(inter+idx)+v : v);
    }
}

// ---------- a = w*a + (1-w)*inter ----------
__global__ void comb_kernel(bf16t* __restrict__ a, const bf16t* __restrict__ inter, const float* __restrict__ wptr){
    float w=*wptr;
    long idx=(long)blockIdx.x*blockDim.x+threadIdx.x;
    long st=(long)gridDim.x*blockDim.x;
    for(; idx<NEl; idx+=st) a[idx]=f2b(w*ldb(a+idx)+(1.f-w)*ldb(inter+idx));
}

// ---------- LayerNorm over (C,H,W) per (s,b) ----------
__global__ __launch_bounds__(256) void ln_kernel(bf16t* __restrict__ hout, void* __restrict__ fout,
                                                 const bf16t* __restrict__ nh, const float* __restrict__ gam,
                                                 const float* __restrict__ bet, int last, const int* __restrict__ flag){
    __shared__ float rbuf[8];
    int sb=blockIdx.x, t=threadIdx.x;
    const bf16t* src=nh+(size_t)sb*CP_;
    float s=0.f,s2=0.f;
    for(int i=t;i<CP_;i+=256){ float v=ldb(src+i); s+=v; s2+=v*v; }
    #pragma unroll
    for(int o2=32;o2;o2>>=1){ s+=__shfl_xor(s,o2); s2+=__shfl_xor(s2,o2); }
    int wid=t>>6;
    if((t&63)==0){ rbuf[wid]=s; rbuf[4+wid]=s2; }
    __syncthreads();
    float S=rbuf[0]+rbuf[1]+rbuf[2]+rbuf[3];
    float S2=rbuf[4]+rbuf[5]+rbuf[6]+rbuf[7];
    float mu=S*(1.f/(float)CP_);
    float var=S2*(1.f/(float)CP_)-mu*mu;
    float rstd=rsqrtf(var+1e-5f);
    int f = last ? *flag : 0;
    bf16t* ho=hout+(size_t)sb*CP_;
    for(int i=t;i<CP_;i+=256){
        float v=(ldb(src+i)-mu)*rstd*gam[i]+bet[i];
        ho[i]=f2b(v);
        if(last){
            size_t oi=(size_t)sb*CP_+i;
            if(f) ((float*)fout)[oi]=v;
            else  ((bf16t*)fout)[oi]=f2b(v);
        }
    }
}

extern "C" void kernel_launch(void* const* d_in, const int* in_sizes, int n_in,
                              void* d_out, int out_size, void* d_ws, size_t ws_size,
                              hipStream_t stream) {
    (void)in_sizes; (void)n_in; (void)out_size;
    char* base=(char*)d_ws;
    size_t off=0;
    auto alloc=[&](size_t bytes){ void* p=base+off; off+=(bytes+255)&~(size_t)255; return p; };
    bf16t* hbuf=(bf16t*)alloc((size_t)NEl*2);
    bf16t* A   =(bf16t*)alloc((size_t)NEl*2);   // q / intra / comb / NH
    bf16t* Bb  =(bf16t*)alloc((size_t)NEl*2);   // k / yy / m_right / Z
    bf16t* D   =(bf16t*)d_out;                  // v / m_left / inter / RH / final
    float* wqf=(float*)alloc(16384*4); float* bqf=(float*)alloc(128*4);
    float* wkf=(float*)alloc(16384*4); float* bkf=(float*)alloc(128*4);
    float* wvf=(float*)alloc(16384*4); float* bvf=(float*)alloc(128*4);
    float* wgf=(float*)alloc(16384*4); float* bgf=(float*)alloc(128*4);
    float* wzrf=(float*)alloc(589824*4); float* bzrf=(float*)alloc(256*4);
    float* whf=(float*)alloc(294912*4);  float* bhf=(float*)alloc(128*4);
    float* gamf=(float*)alloc(15488*4);  float* betf=(float*)alloc(15488*4);
    float* wmsgf=(float*)alloc(16512*4); float* wlinf=(float*)alloc(16384*4); float* bmsgf=(float*)alloc(128*4);
    float* W2=(float*)alloc(16384*4); float* b2l=(float*)alloc(128*4); float* b2r=(float*)alloc(128*4);
    float* alphaf=(float*)alloc(4); float* weightf=(float*)alloc(4);
    float* gbuf=(float*)alloc((size_t)SBn*C_*4);
    bf16t* wzrT=(bf16t*)alloc((size_t)589824*2);  // [tap][256][256]
    bf16t* whT =(bf16t*)alloc((size_t)294912*2);  // [tap][128][256]
    int* flag=(int*)alloc(4);
    size_t rem = (ws_size>off)? ws_size-off : 0;
    int CH = (int)(rem/((size_t)P_*P_*4));
    if(CH>SBn) CH=SBn;
    if(CH<16) return;  // ws too small (~104MB needed)
    float* att=(float*)alloc((size_t)CH*P_*P_*4);

    detect_kernel<<<1,64,0,stream>>>((const unsigned short*)d_in[0], flag);
    auto CV=[&](float* dst,int idx,long n){
        int g=(int)((n+255)/256); if(g>4096)g=4096; if(g<1)g=1;
        cvt_kernel<<<g,256,0,stream>>>(dst,d_in[idx],n,flag);
    };
    cvtb_kernel<<<4096,256,0,stream>>>(hbuf,d_in[0],NEl,flag);
    CV(wqf,1,16384);  CV(bqf,2,128);
    CV(wkf,3,16384);  CV(bkf,4,128);
    CV(wvf,5,16384);  CV(bvf,6,128);
    CV(alphaf,7,1);
    CV(wmsgf,8,16512); CV(bmsgf,9,128); CV(wlinf,10,16384);
    CV(weightf,11,1);
    CV(wgf,12,16384); CV(bgf,13,128);
    CV(wzrf,14,589824); CV(bzrf,15,256);
    CV(whf,16,294912);  CV(bhf,17,128);
    CV(gamf,18,15488);  CV(betf,19,15488);
    prep_msg_kernel<<<C_,C_,0,stream>>>(W2,b2l,b2r,wlinf,wmsgf,bmsgf);
    prep_w3<<<(256*2304+255)/256,256,0,stream>>>(wzrT,wzrf,256);
    prep_w3<<<(128*2304+255)/256,256,0,stream>>>(whT,whf,128);

    const float scale=0.08838834764831845f; // C^-0.5

    for(int it=0; it<3; ++it){
        // q->A, k->B, v->D
        convgen1<32><<<SBn,256,0,stream>>>(A,hbuf,wqf,bqf,0);
        convgen1<32><<<SBn,256,0,stream>>>(Bb,hbuf,wkf,bkf,0);
        convgen1<32><<<SBn,256,0,stream>>>(D,hbuf,wvf,bvf,0);
        // intra attention: intra = alpha*att@v + h -> A
        for(int s0=0;s0<SBn;s0+=CH){
            int nb=(SBn-s0<CH)?(SBn-s0):CH;
            attn_kernel<<<nb,256,0,stream>>>(att,A,Bb,scale,s0);
            av_kernel<<<nb,256,0,stream>>>(A,att,D,hbuf,alphaf,s0);
        }
        // left message: yy->B (shifted h), m->D, gate, inter=m*g*mask -> D
        convgen1<32><<<SBn,256,0,stream>>>(Bb,hbuf,W2,b2l,-B_);
        for(int s0=0;s0<SBn;s0+=CH){
            int nb=(SBn-s0<CH)?(SBn-s0):CH;
            attn_kernel<<<nb,256,0,stream>>>(att,hbuf,Bb,1.0f,s0);
            av_kernel<<<nb,256,0,stream>>>(D,att,Bb,nullptr,nullptr,s0);
        }
        gate_kernel<<<SBn,C_,0,stream>>>(gbuf,D,wgf,bgf);
        apply_gate_kernel<<<2048,256,0,stream>>>(D,D,gbuf,1,0);
        // right message: yy->B, m->B (in place), inter(D) += m*g*mask
        convgen1<32><<<SBn,256,0,stream>>>(Bb,hbuf,W2,b2r,B_);
        for(int s0=0;s0<SBn;s0+=CH){
            int nb=(SBn-s0<CH)?(SBn-s0):CH;
            attn_kernel<<<nb,256,0,stream>>>(att,hbuf,Bb,1.0f,s0);
            av_kernel<<<nb,256,0,stream>>>(Bb,att,Bb,nullptr,nullptr,s0);
        }
        gate_kernel<<<SBn,C_,0,stream>>>(gbuf,Bb,wgf,bgf);
        apply_gate_kernel<<<2048,256,0,stream>>>(D,Bb,gbuf,0,1);
        // combine: A = w*A + (1-w)*D
        comb_kernel<<<2048,256,0,stream>>>(A,D,weightf);
        // GRU via MFMA: zr conv([A,h]) -> Z->B, RH=sigmoid*h->D ; hhat conv([A,RH=D]) -> NH->A
        conv3_mfma<1><<<dim3(SBn,2),256,0,stream>>>(Bb,A,hbuf,wzrT,bzrf,D,nullptr);
        conv3_mfma<2><<<dim3(SBn,1),256,0,stream>>>(A,A,D,whT,bhf,Bb,hbuf);
        // LayerNorm(NH=A) -> h (and final output on last iter)
        ln_kernel<<<SBn,256,0,stream>>>(hbuf,d_out,A,gamf,betf,(it==2)?1:0,flag);
    }
}

// Round 4
// 2369.030 us; speedup vs baseline: 9.1790x; 4.8973x over previous
//
#include <hip/hip_runtime.h>
#include <hip/hip_bf16.h>

// GraphProcessor: S=16,B=64,C=128,H=W=11,P=121, 3 iterations.
// All big tensors transposed [sb][p][128ch] bf16; MFMA everywhere matmul-shaped.
#define S_   16
#define B_   64
#define SBn  1024
#define C_   128
#define P_   121
#define CP_  15488
#define PNT_ 16384   // padded natural tile (128 rows x 128 cols) for v/yy
static const long NEl = 15859712L; // SBn*CP_

typedef __hip_bfloat16 bf16t;
typedef __attribute__((ext_vector_type(8))) short bf16x8;
typedef __attribute__((ext_vector_type(4))) float f32x4;
typedef __attribute__((ext_vector_type(4))) unsigned short us4;

__device__ __forceinline__ float ldb(const bf16t* p){ return __bfloat162float(*p); }
__device__ __forceinline__ float b2f(unsigned short u){ unsigned x=((unsigned)u)<<16; float f; __builtin_memcpy(&f,&x,4); return f; }
__device__ __forceinline__ unsigned short f2bu(float v){ __hip_bfloat16 b=__float2bfloat16(v); unsigned short u; __builtin_memcpy(&u,&b,2); return u; }
__device__ __forceinline__ float ldin(const void* s, long i, int f){
    return f ? ((const float*)s)[i] : b2f(((const unsigned short*)s)[i]);
}

// ---------- dtype detect: flag=1 if inputs are f32, 0 if bf16 ----------
__global__ void detect_kernel(const unsigned short* __restrict__ x, int* __restrict__ flag){
    if(blockIdx.x==0 && threadIdx.x==0){
        int crazy=0;
        for(int i=0;i<512;i++){
            unsigned e=(x[i]>>7)&0xFF;
            if(e!=0 && (e<64 || e>191)) crazy++;
        }
        *flag=(crazy>40)?1:0;
    }
}

// ---------- raw input -> f32 ----------
__global__ void cvt_kernel(float* __restrict__ dst, const void* __restrict__ src, long n, const int* __restrict__ flag){
    long i=(long)blockIdx.x*blockDim.x+threadIdx.x;
    long st=(long)gridDim.x*blockDim.x;
    int f=*flag;
    for(;i<n;i+=st) dst[i]=ldin(src,i,f);
}

// ---------- x [sb][c][p] -> hT [sb][p][c] bf16 ----------
__global__ __launch_bounds__(256) void cvtT_kernel(bf16t* __restrict__ hT, const void* __restrict__ x, const int* __restrict__ flag){
    int sb=blockIdx.x, t=threadIdx.x; int f=*flag;
    for(int i=t;i<CP_;i+=256){
        int c=i/P_, p=i-c*P_;
        float v=ldin(x,(long)sb*CP_+i,f);
        hT[(size_t)sb*CP_+(size_t)p*C_+c]=__float2bfloat16(v);
    }
}

// ---------- fold w_lin @ w_msg[:, :C] into W2 (f32), edge bias into b2l/b2r ----------
__global__ __launch_bounds__(128) void prep_msg_kernel(float* __restrict__ W2, float* __restrict__ b2l, float* __restrict__ b2r,
        const void* __restrict__ wlin, const void* __restrict__ wmsg, const void* __restrict__ bmsg, const int* __restrict__ flag){
    int d=blockIdx.x, c=threadIdx.x; int f=*flag;
    float acc=0.f;
    for(int o2=0;o2<C_;o2++) acc += ldin(wlin,(long)d*C_+o2,f)*ldin(wmsg,(long)o2*(C_+1)+c,f);
    W2[d*C_+c]=acc;
    if(c<2){
        float e=(c==0)?1.f:-1.f; float a=0.f;
        for(int o2=0;o2<C_;o2++) a += ldin(wlin,(long)d*C_+o2,f)*(ldin(bmsg,o2,f)+e*ldin(wmsg,(long)o2*(C_+1)+C_,f));
        if(c==0) b2l[d]=a; else b2r[d]=a;
    }
}

// ---------- 1x1 weight [oc][128ic] -> tiled bf16 [icb(4)][oc(128)][32] ----------
template<int RAW>
__global__ void prep_w1t(bf16t* __restrict__ dst, const void* __restrict__ src, const int* __restrict__ flag){
    int idx=blockIdx.x*blockDim.x+threadIdx.x;
    if(idx>=16384) return;
    int r=idx&31, oc=(idx>>5)&127, icb=idx>>12;
    float v = RAW? ldin(src,(long)oc*C_+icb*32+r,*flag) : ((const float*)src)[(long)oc*C_+icb*32+r];
    dst[idx]=__float2bfloat16(v);
}

// ---------- 3x3 weight [oc][256ic][3][3] -> tiled bf16 [tap][icb(8)][oc][32] ----------
__global__ void prep_w3t(bf16t* __restrict__ dst, const void* __restrict__ src, const int* __restrict__ flag, int OC){
    int idx=blockIdx.x*blockDim.x+threadIdx.x;
    int tot=OC*2304;
    if(idx>=tot) return;
    int r=idx&31; int rest=idx>>5; int oc=rest%OC; int g2=rest/OC; int icb=g2&7, tap=g2>>3;
    float v=ldin(src,((long)(oc*256+icb*32+r))*9+tap,*flag);
    dst[idx]=__float2bfloat16(v);
}

// ---------- gamma/beta [c][p] -> transposed f32 [p][c] ----------
__global__ void prep_gbt(float* __restrict__ gamT, float* __restrict__ betT,
                         const void* __restrict__ gam, const void* __restrict__ bet, const int* __restrict__ flag){
    int idx=blockIdx.x*blockDim.x+threadIdx.x;
    if(idx>=CP_) return;
    int c=idx/P_, p=idx-c*P_; int f=*flag;
    gamT[p*C_+c]=ldin(gam,idx,f);
    betT[p*C_+c]=ldin(bet,idx,f);
}

// ---------- 1x1 conv via MFMA: M=oc, N=p, K=ic=128. A=W tiled, B=inT direct. ----------
// ST_T: store transposed [p][oc] (vector 8B). ST_N: store natural padded [oc][128] (zeros in pad cols).
template<int ST_T,int ST_N>
__global__ __launch_bounds__(256) void conv1_mfma(
    bf16t* __restrict__ outT, bf16t* __restrict__ outN,
    const bf16t* __restrict__ inT, const bf16t* __restrict__ Wt,
    const float* __restrict__ bias, int shift)
{
    int sb=blockIdx.x, t=threadIdx.x, lane=t&63, w=t>>6;
    int ocr=w>>1, pcr=w&1, l15=lane&15, kg=lane>>4;
    f32x4 acc[4][4];
    #pragma unroll
    for(int i=0;i<4;i++){
        #pragma unroll
        for(int j=0;j<4;j++) acc[i][j]=(f32x4){0.f,0.f,0.f,0.f};
    }
    int ssb=sb+shift; bool vs=(ssb>=0&&ssb<SBn);
    if(vs){
        const bf16t* src=inT+(size_t)ssb*CP_;
        #pragma unroll
        for(int kc=0;kc<4;kc++){
            bf16x8 a[4],b[4];
            #pragma unroll
            for(int mt=0;mt<4;mt++) a[mt]=*(const bf16x8*)(Wt+((size_t)(kc*C_+ocr*64+mt*16+l15))*32+kg*8);
            #pragma unroll
            for(int nt=0;nt<4;nt++) b[nt]=*(const bf16x8*)(src+(size_t)(pcr*64+nt*16+l15)*C_+kc*32+kg*8);
            #pragma unroll
            for(int mt=0;mt<4;mt++){
                #pragma unroll
                for(int nt=0;nt<4;nt++)
                    acc[mt][nt]=__builtin_amdgcn_mfma_f32_16x16x32_bf16(a[mt],b[nt],acc[mt][nt],0,0,0);
            }
        }
    }
    #pragma unroll
    for(int mt=0;mt<4;mt++){
        int oc0=ocr*64+mt*16+kg*4;
        float bs[4];
        #pragma unroll
        for(int r=0;r<4;r++) bs[r]=bias[oc0+r];
        #pragma unroll
        for(int nt=0;nt<4;nt++){
            int p=pcr*64+nt*16+l15;
            float v0[4];
            #pragma unroll
            for(int r=0;r<4;r++) v0[r]=acc[mt][nt][r]+bs[r];
            if(ST_T && p<P_){
                us4 pk={f2bu(v0[0]),f2bu(v0[1]),f2bu(v0[2]),f2bu(v0[3])};
                *(us4*)(outT+(size_t)sb*CP_+(size_t)p*C_+oc0)=pk;
            }
            if(ST_N){
                #pragma unroll
                for(int r=0;r<4;r++) outN[(size_t)sb*PNT_+(size_t)(oc0+r)*128+p]=__float2bfloat16(p<P_? v0[r]:0.f);
            }
        }
    }
}

// ---------- fused attention per (s,b): S=A^T B -> softmax -> out^T = V @ P ----------
// MSG=0 (intra): out = w*(alpha*PV + hT). MSG=1: out = PV (mT).
template<int MSG>
__global__ __launch_bounds__(256) void attn_fused(
    bf16t* __restrict__ out, const bf16t* __restrict__ aT, const bf16t* __restrict__ kTb,
    const bf16t* __restrict__ vN, const bf16t* __restrict__ hTb,
    const float* __restrict__ alphap, const float* __restrict__ wp)
{
    __shared__ bf16t lds[128*136];  // kT staging, then P
    int sb=blockIdx.x, t=threadIdx.x, lane=t&63, w=t>>6;
    int l15=lane&15, kg=lane>>4;
    {
        const bf16t* kp=kTb+(size_t)sb*CP_;
        bf16x8 z;
        #pragma unroll
        for(int e=0;e<8;e++) z[e]=0;
        for(int i=t;i<2048;i+=256){
            int r=i>>4, cc=(i&15)*8;
            bf16x8 v=(r<P_)? *(const bf16x8*)(kp+(size_t)r*C_+cc) : z;
            *(bf16x8*)(lds+r*136+cc)=v;
        }
    }
    __syncthreads();
    const float scale = MSG? 1.0f : 0.08838834764831845f;
    f32x4 acc[2][8];
    #pragma unroll
    for(int i=0;i<2;i++){
        #pragma unroll
        for(int j=0;j<8;j++) acc[i][j]=(f32x4){0.f,0.f,0.f,0.f};
    }
    const bf16t* ap=aT+(size_t)sb*CP_;
    int m0=w*32;
    #pragma unroll
    for(int kc=0;kc<4;kc++){
        bf16x8 af[2];
        #pragma unroll
        for(int mt=0;mt<2;mt++) af[mt]=*(const bf16x8*)(ap+(size_t)(m0+mt*16+l15)*C_+kc*32+kg*8);
        #pragma unroll
        for(int nt=0;nt<8;nt++){
            bf16x8 bf_=*(const bf16x8*)(lds+(nt*16+l15)*136+kc*32+kg*8);
            #pragma unroll
            for(int mt=0;mt<2;mt++) acc[mt][nt]=__builtin_amdgcn_mfma_f32_16x16x32_bf16(af[mt],bf_,acc[mt][nt],0,0,0);
        }
    }
    // softmax over j (cols), rows p independent
    #pragma unroll
    for(int mt=0;mt<2;mt++){
        #pragma unroll
        for(int nt=0;nt<8;nt++){
            #pragma unroll
            for(int r=0;r<4;r++) acc[mt][nt][r]*=scale;
        }
        if(l15>=9){
            #pragma unroll
            for(int r=0;r<4;r++) acc[mt][7][r]=-3.0e38f;
        }
        #pragma unroll
        for(int r=0;r<4;r++){
            float mx=acc[mt][0][r];
            #pragma unroll
            for(int nt=1;nt<8;nt++) mx=fmaxf(mx,acc[mt][nt][r]);
            #pragma unroll
            for(int o=1;o<16;o<<=1) mx=fmaxf(mx,__shfl_xor(mx,o));
            float s=0.f;
            #pragma unroll
            for(int nt=0;nt<8;nt++){ float e=__expf(acc[mt][nt][r]-mx); acc[mt][nt][r]=e; s+=e; }
            #pragma unroll
            for(int o=1;o<16;o<<=1) s+=__shfl_xor(s,o);
            float rs=1.f/s;
            #pragma unroll
            for(int nt=0;nt<8;nt++) acc[mt][nt][r]*=rs;
        }
    }
    __syncthreads();   // all waves done reading kT
    #pragma unroll
    for(int mt=0;mt<2;mt++){
        #pragma unroll
        for(int r=0;r<4;r++){
            int p=m0+mt*16+kg*4+r;
            #pragma unroll
            for(int nt=0;nt<8;nt++) lds[p*136+nt*16+l15]=__float2bfloat16(acc[mt][nt][r]);
        }
    }
    __syncthreads();
    // PV: M=c (A=v natural padded), N=p (B=P lds), K=j
    f32x4 pacc[2][8];
    #pragma unroll
    for(int i=0;i<2;i++){
        #pragma unroll
        for(int j=0;j<8;j++) pacc[i][j]=(f32x4){0.f,0.f,0.f,0.f};
    }
    const bf16t* vp=vN+(size_t)sb*PNT_;
    #pragma unroll
    for(int jc=0;jc<4;jc++){
        bf16x8 af[2];
        #pragma unroll
        for(int mt=0;mt<2;mt++) af[mt]=*(const bf16x8*)(vp+(size_t)(m0+mt*16+l15)*128+jc*32+kg*8);
        #pragma unroll
        for(int nt=0;nt<8;nt++){
            bf16x8 pb=*(const bf16x8*)(lds+(nt*16+l15)*136+jc*32+kg*8);
            #pragma unroll
            for(int mt=0;mt<2;mt++) pacc[mt][nt]=__builtin_amdgcn_mfma_f32_16x16x32_bf16(af[mt],pb,pacc[mt][nt],0,0,0);
        }
    }
    bf16t* ob=out+(size_t)sb*CP_;
    float al=1.f, wv=1.f;
    if(!MSG){ al=*alphap; wv=*wp; }
    #pragma unroll
    for(int mt=0;mt<2;mt++){
        int c0=m0+mt*16+kg*4;
        #pragma unroll
        for(int nt=0;nt<8;nt++){
            int p=nt*16+l15;
            if(p>=P_) continue;
            us4 pk;
            if(MSG){
                #pragma unroll
                for(int r=0;r<4;r++) pk[r]=f2bu(pacc[mt][nt][r]);
            }else{
                us4 hv=*(const us4*)(hTb+(size_t)sb*CP_+(size_t)p*C_+c0);
                #pragma unroll
                for(int r=0;r<4;r++) pk[r]=f2bu(wv*(al*pacc[mt][nt][r]+b2f(hv[r])));
            }
            *(us4*)(ob+(size_t)p*C_+c0)=pk;
        }
    }
}

// ---------- 3x3 SAME conv (concat in0T|in1T) via MFMA, GRU-fused epilogues ----------
// MODE 1 (zr): ocb==0 -> o0 = sigmoid (Z); ocb==128 -> o1 = sigmoid * hT (RH)
// MODE 2 (hhat): o0 = (1-z)h + z*tanh + h  (z=zT, h=hTb); out may alias in0T
template<int MODE>
__global__ __launch_bounds__(256) void conv3_mfma(
    bf16t* __restrict__ o0, bf16t* __restrict__ o1,
    const bf16t* __restrict__ in0T, const bf16t* __restrict__ in1T,
    const bf16t* __restrict__ Wt, const float* __restrict__ bias,
    const bf16t* __restrict__ zT, const bf16t* __restrict__ hTb)
{
    constexpr int OC=(MODE==1)?256:128;
    __shared__ bf16t lin[169*136];
    int sb=blockIdx.x, ocb=blockIdx.y*128;
    int t=threadIdx.x, lane=t&63, w=t>>6;
    int ocr=w>>1, pcr=w&1, l15=lane&15, kg=lane>>4;
    int boff[4]; bool pv_[4];
    #pragma unroll
    for(int nt=0;nt<4;nt++){
        int p=pcr*64+nt*16+l15;
        pv_[nt]=(p<P_); int pc=pv_[nt]?p:(P_-1);
        boff[nt]=((pc/11)*13+(pc%11))*136+kg*8;
    }
    f32x4 acc[4][4];
    #pragma unroll
    for(int i=0;i<4;i++){
        #pragma unroll
        for(int j=0;j<4;j++) acc[i][j]=(f32x4){0.f,0.f,0.f,0.f};
    }
    {
        bf16x8 z;
        #pragma unroll
        for(int e=0;e<8;e++) z[e]=0;
        for(int i=t;i<48*16;i+=256){
            int bi=i>>4, cc=(i&15)*8;
            int pix;
            if(bi<13) pix=bi;
            else if(bi<26) pix=156+(bi-13);
            else { int j2=bi-26; pix=(1+(j2>>1))*13+((j2&1)?12:0); }
            *(bf16x8*)(lin+pix*136+cc)=z;
        }
    }
    for(int hi=0;hi<2;hi++){
        __syncthreads();
        const bf16t* src=(hi? in1T:in0T)+(size_t)sb*CP_;
        for(int i=t;i<1936;i+=256){
            int p=i>>4, cc=(i&15)*8;
            int pix=(p/11+1)*13+(p%11)+1;
            *(bf16x8*)(lin+pix*136+cc)=*(const bf16x8*)(src+(size_t)p*C_+cc);
        }
        __syncthreads();
        for(int tap=0;tap<9;tap++){
            int d=((tap/3)*13+(tap%3))*136;
            #pragma unroll
            for(int icb=0;icb<4;icb++){
                bf16x8 a[4],b[4];
                #pragma unroll
                for(int mt=0;mt<4;mt++)
                    a[mt]=*(const bf16x8*)(Wt+((size_t)((tap*8+hi*4+icb)*OC+ocb+ocr*64+mt*16+l15))*32+kg*8);
                #pragma unroll
                for(int nt=0;nt<4;nt++) b[nt]=*(const bf16x8*)(lin+boff[nt]+d+icb*32);
                #pragma unroll
                for(int mt=0;mt<4;mt++){
                    #pragma unroll
                    for(int nt=0;nt<4;nt++)
                        acc[mt][nt]=__builtin_amdgcn_mfma_f32_16x16x32_bf16(a[mt],b[nt],acc[mt][nt],0,0,0);
                }
            }
        }
    }
    #pragma unroll
    for(int mt=0;mt<4;mt++){
        int ocl=ocr*64+mt*16+kg*4;
        #pragma unroll
        for(int nt=0;nt<4;nt++){
            if(!pv_[nt]) continue;
            int p=pcr*64+nt*16+l15;
            size_t tb=(size_t)sb*CP_+(size_t)p*C_+ocl;
            us4 pk;
            if(MODE==1){
                if(ocb==0){
                    #pragma unroll
                    for(int r=0;r<4;r++){ float a=acc[mt][nt][r]+bias[ocl+r]; pk[r]=f2bu(1.f/(1.f+__expf(-a))); }
                    *(us4*)(o0+tb)=pk;
                }else{
                    us4 hv=*(const us4*)(hTb+tb);
                    #pragma unroll
                    for(int r=0;r<4;r++){ float a=acc[mt][nt][r]+bias[128+ocl+r]; float sg=1.f/(1.f+__expf(-a)); pk[r]=f2bu(sg*b2f(hv[r])); }
                    *(us4*)(o1+tb)=pk;
                }
            }else{
                us4 hv=*(const us4*)(hTb+tb);
                us4 zv=*(const us4*)(zT+tb);
                #pragma unroll
                for(int r=0;r<4;r++){
                    float a=acc[mt][nt][r]+bias[ocl+r];
                    float ht=tanhf(a);
                    float z=b2f(zv[r]), h=b2f(hv[r]);
                    pk[r]=f2bu((1.f-z)*h+z*ht+h);
                }
                *(us4*)(o0+tb)=pk;
            }
        }
    }
}

// ---------- g[c] = sigmoid(b_gate + W_gate @ mean_p mT) ----------
__global__ __launch_bounds__(128) void gate_kernel(float* __restrict__ g, const bf16t* __restrict__ mT,
        const void* __restrict__ wg, const void* __restrict__ bg, const int* __restrict__ flag){
    __shared__ float mb[C_];
    int sb=blockIdx.x, c=threadIdx.x, f=*flag;
    const bf16t* mp=mT+(size_t)sb*CP_+c;
    float s=0.f;
    for(int p=0;p<P_;p++) s+=ldb(mp+(size_t)p*C_);
    mb[c]=s*(1.f/121.f);
    __syncthreads();
    float acc=ldin(bg,c,f);
    #pragma unroll 8
    for(int c2=0;c2<C_;c2++) acc+=ldin(wg,(long)c*C_+c2,f)*mb[c2];
    g[(size_t)sb*C_+c]=1.f/(1.f+__expf(-acc));
}

// ---------- comb accumulate: b2 += (1-w)*mT*g*mask ----------
__global__ void apply_gate_kernel(bf16t* __restrict__ b2, const bf16t* __restrict__ mT,
        const float* __restrict__ g, const float* __restrict__ wp, int isleft){
    float w1m=1.f-*wp;
    long n4=NEl>>2;
    long idx=(long)blockIdx.x*blockDim.x+threadIdx.x;
    long st=(long)gridDim.x*blockDim.x;
    for(;idx<n4;idx+=st){
        long basei=idx<<2;
        int sb=(int)(basei/CP_);
        int rem=(int)(basei-(long)sb*CP_);
        int c=rem&127;
        int s=sb>>6;
        bool on=isleft? (s>=1):(s<=S_-2);
        if(!on) continue;
        us4 bv=*(const us4*)(b2+basei);
        us4 mv=*(const us4*)(mT+basei);
        const float* gp=g+(size_t)sb*C_+c;
        #pragma unroll
        for(int e=0;e<4;e++) bv[e]=f2bu(b2f(bv[e])+w1m*b2f(mv[e])*gp[e]);
        *(us4*)(b2+basei)=bv;
    }
}

// ---------- LayerNorm over tile per (s,b); writes hT (+ natural final out) ----------
__global__ __launch_bounds__(256) void ln_kernel(bf16t* __restrict__ hT, void* __restrict__ fout,
        const bf16t* __restrict__ nh, const float* __restrict__ gamT, const float* __restrict__ betT,
        int last, const int* __restrict__ flag){
    __shared__ float rbuf[8];
    int sb=blockIdx.x, t=threadIdx.x;
    const bf16t* src=nh+(size_t)sb*CP_;
    float s=0.f,s2=0.f;
    for(int i=t;i<CP_;i+=256){ float v=ldb(src+i); s+=v; s2+=v*v; }
    #pragma unroll
    for(int o=32;o;o>>=1){ s+=__shfl_xor(s,o); s2+=__shfl_xor(s2,o); }
    int wid=t>>6;
    if((t&63)==0){ rbuf[wid]=s; rbuf[4+wid]=s2; }
    __syncthreads();
    float S=rbuf[0]+rbuf[1]+rbuf[2]+rbuf[3];
    float S2=rbuf[4]+rbuf[5]+rbuf[6]+rbuf[7];
    float mu=S*(1.f/(float)CP_);
    float var=S2*(1.f/(float)CP_)-mu*mu;
    float rstd=rsqrtf(var+1e-5f);
    int f=last? *flag:0;
    bf16t* ho=hT+(size_t)sb*CP_;
    for(int i=t;i<CP_;i+=256){
        float v=(ldb(src+i)-mu)*rstd*gamT[i]+betT[i];
        ho[i]=__float2bfloat16(v);
        if(last){
            int p=i>>7, c=i&127;
            size_t oi=(size_t)sb*CP_+(size_t)c*P_+p;
            if(f) ((float*)fout)[oi]=v;
            else  ((bf16t*)fout)[oi]=__float2bfloat16(v);
        }
    }
}

extern "C" void kernel_launch(void* const* d_in, const int* in_sizes, int n_in,
                              void* d_out, int out_size, void* d_ws, size_t ws_size,
                              hipStream_t stream) {
    (void)in_sizes; (void)n_in; (void)out_size;
    char* base=(char*)d_ws;
    size_t off=0;
    auto alloc=[&](size_t bytes){ void* p=base+off; off+=(bytes+255)&~(size_t)255; return p; };
    bf16t* b1=(bf16t*)alloc((size_t)NEl*2+4096);          // hT
    bf16t* b2=(bf16t*)alloc((size_t)NEl*2+4096);          // qT/intra/comb/NH
    bf16t* b3=(bf16t*)alloc((size_t)SBn*PNT_*2+4096);     // v,yy (padded natural) / RHT
    bf16t* b4=(bf16t*)d_out;                              // kT/yyT/mT/ZT/final
    bf16t* wqT=(bf16t*)alloc(16384*2);
    bf16t* wkT=(bf16t*)alloc(16384*2);
    bf16t* wvT=(bf16t*)alloc(16384*2);
    bf16t* w2T=(bf16t*)alloc(16384*2);
    bf16t* wzrT=(bf16t*)alloc((size_t)589824*2);
    bf16t* whT =(bf16t*)alloc((size_t)294912*2);
    float* W2f=(float*)alloc(16384*4);
    float* b2l=(float*)alloc(128*4); float* b2r=(float*)alloc(128*4);
    float* bqf=(float*)alloc(128*4); float* bkf=(float*)alloc(128*4); float* bvf=(float*)alloc(128*4);
    float* bzrf=(float*)alloc(256*4); float* bhf=(float*)alloc(128*4);
    float* gamT=(float*)alloc(15488*4); float* betT=(float*)alloc(15488*4);
    float* alphaf=(float*)alloc(4); float* weightf=(float*)alloc(4);
    float* gbuf=(float*)alloc((size_t)SBn*C_*4);
    int* flag=(int*)alloc(4);
    if(ws_size<off) return;  // ~100MB needed

    detect_kernel<<<1,64,0,stream>>>((const unsigned short*)d_in[0],flag);
    cvtT_kernel<<<SBn,256,0,stream>>>(b1,d_in[0],flag);
    prep_w1t<1><<<64,256,0,stream>>>(wqT,d_in[1],flag);
    cvt_kernel<<<1,128,0,stream>>>(bqf,d_in[2],128,flag);
    prep_w1t<1><<<64,256,0,stream>>>(wkT,d_in[3],flag);
    cvt_kernel<<<1,128,0,stream>>>(bkf,d_in[4],128,flag);
    prep_w1t<1><<<64,256,0,stream>>>(wvT,d_in[5],flag);
    cvt_kernel<<<1,128,0,stream>>>(bvf,d_in[6],128,flag);
    cvt_kernel<<<1,64,0,stream>>>(alphaf,d_in[7],1,flag);
    prep_msg_kernel<<<C_,C_,0,stream>>>(W2f,b2l,b2r,d_in[10],d_in[8],d_in[9],flag);
    prep_w1t<0><<<64,256,0,stream>>>(w2T,W2f,flag);
    cvt_kernel<<<1,64,0,stream>>>(weightf,d_in[11],1,flag);
    prep_w3t<<<(256*2304+255)/256,256,0,stream>>>(wzrT,d_in[14],flag,256);
    cvt_kernel<<<1,256,0,stream>>>(bzrf,d_in[15],256,flag);
    prep_w3t<<<(128*2304+255)/256,256,0,stream>>>(whT,d_in[16],flag,128);
    cvt_kernel<<<1,128,0,stream>>>(bhf,d_in[17],128,flag);
    prep_gbt<<<(CP_+255)/256,256,0,stream>>>(gamT,betT,d_in[18],d_in[19],flag);

    for(int it=0; it<3; ++it){
        // q->b2 (T), k->b4 (T), v->b3 (natural padded)
        conv1_mfma<1,0><<<SBn,256,0,stream>>>(b2,nullptr,b1,wqT,bqf,0);
        conv1_mfma<1,0><<<SBn,256,0,stream>>>(b4,nullptr,b1,wkT,bkf,0);
        conv1_mfma<0,1><<<SBn,256,0,stream>>>(nullptr,b3,b1,wvT,bvf,0);
        // intra: b2 = w*(alpha*PV + h)
        attn_fused<0><<<SBn,256,0,stream>>>(b2,b2,b4,b3,b1,alphaf,weightf);
        // left message: yyT->b4, yy->b3; mT->b4; gate; b2 += (1-w)*m*g*maskL
        conv1_mfma<1,1><<<SBn,256,0,stream>>>(b4,b3,b1,w2T,b2l,-B_);
        attn_fused<1><<<SBn,256,0,stream>>>(b4,b1,b4,b3,nullptr,nullptr,nullptr);
        gate_kernel<<<SBn,128,0,stream>>>(gbuf,b4,d_in[12],d_in[13],flag);
        apply_gate_kernel<<<2048,256,0,stream>>>(b2,b4,gbuf,weightf,1);
        // right message
        conv1_mfma<1,1><<<SBn,256,0,stream>>>(b4,b3,b1,w2T,b2r,B_);
        attn_fused<1><<<SBn,256,0,stream>>>(b4,b1,b4,b3,nullptr,nullptr,nullptr);
        gate_kernel<<<SBn,128,0,stream>>>(gbuf,b4,d_in[12],d_in[13],flag);
        apply_gate_kernel<<<2048,256,0,stream>>>(b2,b4,gbuf,weightf,0);
        // GRU: zr([comb|h]) -> Z->b4, RH->b3 ; hhat([comb|RH]) -> NH->b2
        conv3_mfma<1><<<dim3(SBn,2),256,0,stream>>>(b4,b3,b2,b1,wzrT,bzrf,nullptr,b1);
        conv3_mfma<2><<<dim3(SBn,1),256,0,stream>>>(b2,nullptr,b2,b3,whT,bhf,b4,b1);
        // LN -> hT (b1), final natural out on last iter
        ln_kernel<<<SBn,256,0,stream>>>(b1,d_out,b2,gamT,betT,(it==2)?1:0,flag);
    }
}

// Round 5
// 1777.297 us; speedup vs baseline: 12.2351x; 1.3329x over previous
//
#include <hip/hip_runtime.h>
#include <hip/hip_bf16.h>

// GraphProcessor: S=16,B=64,C=128,H=W=11,P=121, 3 iterations.
// All big tensors transposed [sb][p][128ch] bf16; MFMA everywhere matmul-shaped.
#define S_   16
#define B_   64
#define SBn  1024
#define C_   128
#define P_   121
#define CP_  15488
#define PNT_ 16384   // padded natural tile (128 rows x 128 cols) for v/yy
static const long NEl = 15859712L; // SBn*CP_

typedef __hip_bfloat16 bf16t;
typedef __attribute__((ext_vector_type(8))) short bf16x8;
typedef __attribute__((ext_vector_type(4))) float f32x4;
typedef __attribute__((ext_vector_type(4))) unsigned short us4;

__device__ __forceinline__ float ldb(const bf16t* p){ return __bfloat162float(*p); }
__device__ __forceinline__ float b2f(unsigned short u){ unsigned x=((unsigned)u)<<16; float f; __builtin_memcpy(&f,&x,4); return f; }
__device__ __forceinline__ unsigned short f2bu(float v){ __hip_bfloat16 b=__float2bfloat16(v); unsigned short u; __builtin_memcpy(&u,&b,2); return u; }
__device__ __forceinline__ float ldin(const void* s, long i, int f){
    return f ? ((const float*)s)[i] : b2f(((const unsigned short*)s)[i]);
}

// ---------- dtype detect: flag=1 if inputs are f32, 0 if bf16 ----------
__global__ void detect_kernel(const unsigned short* __restrict__ x, int* __restrict__ flag){
    if(blockIdx.x==0 && threadIdx.x==0){
        int crazy=0;
        for(int i=0;i<512;i++){
            unsigned e=(x[i]>>7)&0xFF;
            if(e!=0 && (e<64 || e>191)) crazy++;
        }
        *flag=(crazy>40)?1:0;
    }
}

// ---------- raw input -> f32 ----------
__global__ void cvt_kernel(float* __restrict__ dst, const void* __restrict__ src, long n, const int* __restrict__ flag){
    long i=(long)blockIdx.x*blockDim.x+threadIdx.x;
    long st=(long)gridDim.x*blockDim.x;
    int f=*flag;
    for(;i<n;i+=st) dst[i]=ldin(src,i,f);
}

// ---------- x [sb][c][p] -> hT [sb][p][c] bf16 ----------
__global__ __launch_bounds__(256) void cvtT_kernel(bf16t* __restrict__ hT, const void* __restrict__ x, const int* __restrict__ flag){
    int sb=blockIdx.x, t=threadIdx.x; int f=*flag;
    for(int i=t;i<CP_;i+=256){
        int c=i/P_, p=i-c*P_;
        float v=ldin(x,(long)sb*CP_+i,f);
        hT[(size_t)sb*CP_+(size_t)p*C_+c]=__float2bfloat16(v);
    }
}

// ---------- fold w_lin @ w_msg[:, :C] into W2 (f32), edge bias into b2l/b2r ----------
__global__ __launch_bounds__(128) void prep_msg_kernel(float* __restrict__ W2, float* __restrict__ b2l, float* __restrict__ b2r,
        const void* __restrict__ wlin, const void* __restrict__ wmsg, const void* __restrict__ bmsg, const int* __restrict__ flag){
    int d=blockIdx.x, c=threadIdx.x; int f=*flag;
    float acc=0.f;
    for(int o2=0;o2<C_;o2++) acc += ldin(wlin,(long)d*C_+o2,f)*ldin(wmsg,(long)o2*(C_+1)+c,f);
    W2[d*C_+c]=acc;
    if(c<2){
        float e=(c==0)?1.f:-1.f; float a=0.f;
        for(int o2=0;o2<C_;o2++) a += ldin(wlin,(long)d*C_+o2,f)*(ldin(bmsg,o2,f)+e*ldin(wmsg,(long)o2*(C_+1)+C_,f));
        if(c==0) b2l[d]=a; else b2r[d]=a;
    }
}

// ---------- 1x1 weight [oc][128ic] -> tiled bf16 [icb(4)][oc(128)][32] ----------
template<int RAW>
__global__ void prep_w1t(bf16t* __restrict__ dst, const void* __restrict__ src, const int* __restrict__ flag){
    int idx=blockIdx.x*blockDim.x+threadIdx.x;
    if(idx>=16384) return;
    int r=idx&31, oc=(idx>>5)&127, icb=idx>>12;
    float v = RAW? ldin(src,(long)oc*C_+icb*32+r,*flag) : ((const float*)src)[(long)oc*C_+icb*32+r];
    dst[idx]=__float2bfloat16(v);
}

// ---------- 3x3 weight [oc][256ic][3][3] -> tiled bf16 [tap][icb(8)][oc][32] ----------
__global__ void prep_w3t(bf16t* __restrict__ dst, const void* __restrict__ src, const int* __restrict__ flag, int OC){
    int idx=blockIdx.x*blockDim.x+threadIdx.x;
    int tot=OC*2304;
    if(idx>=tot) return;
    int r=idx&31; int rest=idx>>5; int oc=rest%OC; int g2=rest/OC; int icb=g2&7, tap=g2>>3;
    float v=ldin(src,((long)(oc*256+icb*32+r))*9+tap,*flag);
    dst[idx]=__float2bfloat16(v);
}

// ---------- gamma/beta [c][p] -> transposed f32 [p][c] ----------
__global__ void prep_gbt(float* __restrict__ gamT, float* __restrict__ betT,
                         const void* __restrict__ gam, const void* __restrict__ bet, const int* __restrict__ flag){
    int idx=blockIdx.x*blockDim.x+threadIdx.x;
    if(idx>=CP_) return;
    int c=idx/P_, p=idx-c*P_; int f=*flag;
    gamT[p*C_+c]=ldin(gam,idx,f);
    betT[p*C_+c]=ldin(bet,idx,f);
}

// ---------- w_gate [c][k] -> transposed f32 [k][c]; b_gate -> f32 ----------
__global__ void prep_wgt(float* __restrict__ wgT, float* __restrict__ bg2,
                         const void* __restrict__ wg, const void* __restrict__ bg, const int* __restrict__ flag){
    int idx=blockIdx.x*blockDim.x+threadIdx.x;
    int f=*flag;
    if(idx<16384){ int k=idx>>7, c=idx&127; wgT[idx]=ldin(wg,(long)c*C_+k,f); }
    if(idx<128) bg2[idx]=ldin(bg,idx,f);
}

// ---------- shared 128x128x128 MFMA tile helpers ----------
__device__ __forceinline__ void mm_tile(f32x4 (&acc)[4][4], const bf16t* __restrict__ src,
                                        const bf16t* __restrict__ Wt, int ocr,int pcr,int l15,int kg){
    #pragma unroll
    for(int kc=0;kc<4;kc++){
        bf16x8 a[4],b[4];
        #pragma unroll
        for(int mt=0;mt<4;mt++) a[mt]=*(const bf16x8*)(Wt+((size_t)(kc*C_+ocr*64+mt*16+l15))*32+kg*8);
        #pragma unroll
        for(int nt=0;nt<4;nt++) b[nt]=*(const bf16x8*)(src+(size_t)(pcr*64+nt*16+l15)*C_+kc*32+kg*8);
        #pragma unroll
        for(int mt=0;mt<4;mt++){
            #pragma unroll
            for(int nt=0;nt<4;nt++)
                acc[mt][nt]=__builtin_amdgcn_mfma_f32_16x16x32_bf16(a[mt],b[nt],acc[mt][nt],0,0,0);
        }
    }
}
__device__ __forceinline__ void epiT(bf16t* __restrict__ outT, f32x4 (&acc)[4][4], const float* __restrict__ bias,
                                     int sb,int ocr,int pcr,int l15,int kg){
    #pragma unroll
    for(int mt=0;mt<4;mt++){
        int oc0=ocr*64+mt*16+kg*4;
        #pragma unroll
        for(int nt=0;nt<4;nt++){
            int p=pcr*64+nt*16+l15;
            if(p>=P_) continue;
            us4 pk;
            #pragma unroll
            for(int r=0;r<4;r++) pk[r]=f2bu(acc[mt][nt][r]+bias[oc0+r]);
            *(us4*)(outT+(size_t)sb*CP_+(size_t)p*C_+oc0)=pk;
        }
    }
}
__device__ __forceinline__ void epiN(bf16t* __restrict__ outN, f32x4 (&acc)[4][4], const float* __restrict__ bias,
                                     int sb,int ocr,int pcr,int l15,int kg){
    #pragma unroll
    for(int mt=0;mt<4;mt++){
        int oc0=ocr*64+mt*16+kg*4;
        #pragma unroll
        for(int nt=0;nt<4;nt++){
            int p=pcr*64+nt*16+l15;
            #pragma unroll
            for(int r=0;r<4;r++)
                outN[(size_t)sb*PNT_+(size_t)(oc0+r)*128+p]=__float2bfloat16(p<P_? acc[mt][nt][r]+bias[oc0+r] : 0.f);
        }
    }
}

// ---------- fused q,k,v 1x1 convs: one pass over hT ----------
__global__ __launch_bounds__(256) void conv1_qkv(
    bf16t* __restrict__ qT, bf16t* __restrict__ kT, bf16t* __restrict__ vN,
    const bf16t* __restrict__ inT,
    const bf16t* __restrict__ WqT, const bf16t* __restrict__ WkT, const bf16t* __restrict__ WvT,
    const float* __restrict__ bq, const float* __restrict__ bk, const float* __restrict__ bv)
{
    int sb=blockIdx.x,t=threadIdx.x,lane=t&63,w=t>>6;
    int ocr=w>>1,pcr=w&1,l15=lane&15,kg=lane>>4;
    const bf16t* src=inT+(size_t)sb*CP_;
    f32x4 acc[4][4];
    #pragma unroll
    for(int i=0;i<4;i++){
        #pragma unroll
        for(int j=0;j<4;j++) acc[i][j]=(f32x4){0.f,0.f,0.f,0.f};
    }
    mm_tile(acc,src,WqT,ocr,pcr,l15,kg); epiT(qT,acc,bq,sb,ocr,pcr,l15,kg);
    #pragma unroll
    for(int i=0;i<4;i++){
        #pragma unroll
        for(int j=0;j<4;j++) acc[i][j]=(f32x4){0.f,0.f,0.f,0.f};
    }
    mm_tile(acc,src,WkT,ocr,pcr,l15,kg); epiT(kT,acc,bk,sb,ocr,pcr,l15,kg);
    #pragma unroll
    for(int i=0;i<4;i++){
        #pragma unroll
        for(int j=0;j<4;j++) acc[i][j]=(f32x4){0.f,0.f,0.f,0.f};
    }
    mm_tile(acc,src,WvT,ocr,pcr,l15,kg); epiN(vN,acc,bv,sb,ocr,pcr,l15,kg);
}

// ---------- msg 1x1 conv (restricted grid, shifted source): writes yyT + yyN ----------
__global__ __launch_bounds__(256) void conv1_msg(
    bf16t* __restrict__ yT, bf16t* __restrict__ yN, const bf16t* __restrict__ inT,
    const bf16t* __restrict__ Wt, const float* __restrict__ bias, int sb0, int shift)
{
    int sb=sb0+blockIdx.x;
    int t=threadIdx.x,lane=t&63,w=t>>6;
    int ocr=w>>1,pcr=w&1,l15=lane&15,kg=lane>>4;
    const bf16t* src=inT+(size_t)(sb+shift)*CP_;
    f32x4 acc[4][4];
    #pragma unroll
    for(int i=0;i<4;i++){
        #pragma unroll
        for(int j=0;j<4;j++) acc[i][j]=(f32x4){0.f,0.f,0.f,0.f};
    }
    mm_tile(acc,src,Wt,ocr,pcr,l15,kg);
    epiT(yT,acc,bias,sb,ocr,pcr,l15,kg);
    epiN(yN,acc,bias,sb,ocr,pcr,l15,kg);
}

// ---------- fused intra attention per (s,b): S=A^T B -> softmax -> out^T = V @ P ----------
// out = w*(alpha*PV + hT)
__global__ __launch_bounds__(256) void attn_fused(
    bf16t* __restrict__ out, const bf16t* __restrict__ aT, const bf16t* __restrict__ kTb,
    const bf16t* __restrict__ vN, const bf16t* __restrict__ hTb,
    const float* __restrict__ alphap, const float* __restrict__ wp)
{
    __shared__ bf16t lds[128*136];  // kT staging, then P
    int sb=blockIdx.x, t=threadIdx.x, lane=t&63, w=t>>6;
    int l15=lane&15, kg=lane>>4;
    {
        const bf16t* kp=kTb+(size_t)sb*CP_;
        bf16x8 z;
        #pragma unroll
        for(int e=0;e<8;e++) z[e]=0;
        for(int i=t;i<2048;i+=256){
            int r=i>>4, cc=(i&15)*8;
            bf16x8 v=(r<P_)? *(const bf16x8*)(kp+(size_t)r*C_+cc) : z;
            *(bf16x8*)(lds+r*136+cc)=v;
        }
    }
    __syncthreads();
    const float scale = 0.08838834764831845f;
    f32x4 acc[2][8];
    #pragma unroll
    for(int i=0;i<2;i++){
        #pragma unroll
        for(int j=0;j<8;j++) acc[i][j]=(f32x4){0.f,0.f,0.f,0.f};
    }
    const bf16t* ap=aT+(size_t)sb*CP_;
    int m0=w*32;
    #pragma unroll
    for(int kc=0;kc<4;kc++){
        bf16x8 af[2];
        #pragma unroll
        for(int mt=0;mt<2;mt++) af[mt]=*(const bf16x8*)(ap+(size_t)(m0+mt*16+l15)*C_+kc*32+kg*8);
        #pragma unroll
        for(int nt=0;nt<8;nt++){
            bf16x8 bf_=*(const bf16x8*)(lds+(nt*16+l15)*136+kc*32+kg*8);
            #pragma unroll
            for(int mt=0;mt<2;mt++) acc[mt][nt]=__builtin_amdgcn_mfma_f32_16x16x32_bf16(af[mt],bf_,acc[mt][nt],0,0,0);
        }
    }
    #pragma unroll
    for(int mt=0;mt<2;mt++){
        #pragma unroll
        for(int nt=0;nt<8;nt++){
            #pragma unroll
            for(int r=0;r<4;r++) acc[mt][nt][r]*=scale;
        }
        if(l15>=9){
            #pragma unroll
            for(int r=0;r<4;r++) acc[mt][7][r]=-3.0e38f;
        }
        #pragma unroll
        for(int r=0;r<4;r++){
            float mx=acc[mt][0][r];
            #pragma unroll
            for(int nt=1;nt<8;nt++) mx=fmaxf(mx,acc[mt][nt][r]);
            #pragma unroll
            for(int o=1;o<16;o<<=1) mx=fmaxf(mx,__shfl_xor(mx,o));
            float s=0.f;
            #pragma unroll
            for(int nt=0;nt<8;nt++){ float e=__expf(acc[mt][nt][r]-mx); acc[mt][nt][r]=e; s+=e; }
            #pragma unroll
            for(int o=1;o<16;o<<=1) s+=__shfl_xor(s,o);
            float rs=1.f/s;
            #pragma unroll
            for(int nt=0;nt<8;nt++) acc[mt][nt][r]*=rs;
        }
    }
    __syncthreads();
    #pragma unroll
    for(int mt=0;mt<2;mt++){
        #pragma unroll
        for(int r=0;r<4;r++){
            int p=m0+mt*16+kg*4+r;
            #pragma unroll
            for(int nt=0;nt<8;nt++) lds[p*136+nt*16+l15]=__float2bfloat16(acc[mt][nt][r]);
        }
    }
    __syncthreads();
    f32x4 pacc[2][8];
    #pragma unroll
    for(int i=0;i<2;i++){
        #pragma unroll
        for(int j=0;j<8;j++) pacc[i][j]=(f32x4){0.f,0.f,0.f,0.f};
    }
    const bf16t* vp=vN+(size_t)sb*PNT_;
    #pragma unroll
    for(int jc=0;jc<4;jc++){
        bf16x8 af[2];
        #pragma unroll
        for(int mt=0;mt<2;mt++) af[mt]=*(const bf16x8*)(vp+(size_t)(m0+mt*16+l15)*128+jc*32+kg*8);
        #pragma unroll
        for(int nt=0;nt<8;nt++){
            bf16x8 pb=*(const bf16x8*)(lds+(nt*16+l15)*136+jc*32+kg*8);
            #pragma unroll
            for(int mt=0;mt<2;mt++) pacc[mt][nt]=__builtin_amdgcn_mfma_f32_16x16x32_bf16(af[mt],pb,pacc[mt][nt],0,0,0);
        }
    }
    bf16t* ob=out+(size_t)sb*CP_;
    float al=*alphap, wv=*wp;
    #pragma unroll
    for(int mt=0;mt<2;mt++){
        int c0=m0+mt*16+kg*4;
        #pragma unroll
        for(int nt=0;nt<8;nt++){
            int p=nt*16+l15;
            if(p>=P_) continue;
            us4 hv=*(const us4*)(hTb+(size_t)sb*CP_+(size_t)p*C_+c0);
            us4 pk;
            #pragma unroll
            for(int r=0;r<4;r++) pk[r]=f2bu(wv*(al*pacc[mt][nt][r]+b2f(hv[r])));
            *(us4*)(ob+(size_t)p*C_+c0)=pk;
        }
    }
}

// ---------- fused msg attention + gate + masked accumulate into comb ----------
// comb += (1-w) * g[c] * (att(h,yy) @ yy)[c,p]   for the 960 unmasked sb (grid-restricted)
__global__ __launch_bounds__(256) void msg_fused(
    bf16t* __restrict__ comb, const bf16t* __restrict__ hT, const bf16t* __restrict__ yyT,
    const bf16t* __restrict__ yyN, const float* __restrict__ wgT, const float* __restrict__ bgf,
    const float* __restrict__ wp, int sb0)
{
    __shared__ bf16t lds[128*136];
    int sb=sb0+blockIdx.x, t=threadIdx.x, lane=t&63, w=t>>6;
    int l15=lane&15, kg=lane>>4;
    {
        const bf16t* kp=yyT+(size_t)sb*CP_;
        bf16x8 z;
        #pragma unroll
        for(int e=0;e<8;e++) z[e]=0;
        for(int i=t;i<2048;i+=256){
            int r=i>>4, cc=(i&15)*8;
            bf16x8 v=(r<P_)? *(const bf16x8*)(kp+(size_t)r*C_+cc) : z;
            *(bf16x8*)(lds+r*136+cc)=v;
        }
    }
    __syncthreads();
    f32x4 acc[2][8];
    #pragma unroll
    for(int i=0;i<2;i++){
        #pragma unroll
        for(int j=0;j<8;j++) acc[i][j]=(f32x4){0.f,0.f,0.f,0.f};
    }
    const bf16t* ap=hT+(size_t)sb*CP_;
    int m0=w*32;
    #pragma unroll
    for(int kc=0;kc<4;kc++){
        bf16x8 af[2];
        #pragma unroll
        for(int mt=0;mt<2;mt++) af[mt]=*(const bf16x8*)(ap+(size_t)(m0+mt*16+l15)*C_+kc*32+kg*8);
        #pragma unroll
        for(int nt=0;nt<8;nt++){
            bf16x8 bf_=*(const bf16x8*)(lds+(nt*16+l15)*136+kc*32+kg*8);
            #pragma unroll
            for(int mt=0;mt<2;mt++) acc[mt][nt]=__builtin_amdgcn_mfma_f32_16x16x32_bf16(af[mt],bf_,acc[mt][nt],0,0,0);
        }
    }
    #pragma unroll
    for(int mt=0;mt<2;mt++){
        if(l15>=9){
            #pragma unroll
            for(int r=0;r<4;r++) acc[mt][7][r]=-3.0e38f;
        }
        #pragma unroll
        for(int r=0;r<4;r++){
            float mx=acc[mt][0][r];
            #pragma unroll
            for(int nt=1;nt<8;nt++) mx=fmaxf(mx,acc[mt][nt][r]);
            #pragma unroll
            for(int o=1;o<16;o<<=1) mx=fmaxf(mx,__shfl_xor(mx,o));
            float s=0.f;
            #pragma unroll
            for(int nt=0;nt<8;nt++){ float e=__expf(acc[mt][nt][r]-mx); acc[mt][nt][r]=e; s+=e; }
            #pragma unroll
            for(int o=1;o<16;o<<=1) s+=__shfl_xor(s,o);
            float rs=1.f/s;
            #pragma unroll
            for(int nt=0;nt<8;nt++) acc[mt][nt][r]*=rs;
        }
    }
    __syncthreads();
    #pragma unroll
    for(int mt=0;mt<2;mt++){
        #pragma unroll
        for(int r=0;r<4;r++){
            int p=m0+mt*16+kg*4+r;
            #pragma unroll
            for(int nt=0;nt<8;nt++) lds[p*136+nt*16+l15]=__float2bfloat16(acc[mt][nt][r]);
        }
    }
    __syncthreads();
    f32x4 pacc[2][8];
    #pragma unroll
    for(int i=0;i<2;i++){
        #pragma unroll
        for(int j=0;j<8;j++) pacc[i][j]=(f32x4){0.f,0.f,0.f,0.f};
    }
    const bf16t* vp=yyN+(size_t)sb*PNT_;
    #pragma unroll
    for(int jc=0;jc<4;jc++){
        bf16x8 af[2];
        #pragma unroll
        for(int mt=0;mt<2;mt++) af[mt]=*(const bf16x8*)(vp+(size_t)(m0+mt*16+l15)*128+jc*32+kg*8);
        #pragma unroll
        for(int nt=0;nt<8;nt++){
            bf16x8 pb=*(const bf16x8*)(lds+(nt*16+l15)*136+jc*32+kg*8);
            #pragma unroll
            for(int mt=0;mt<2;mt++) pacc[mt][nt]=__builtin_amdgcn_mfma_f32_16x16x32_bf16(af[mt],pb,pacc[mt][nt],0,0,0);
        }
    }
    // ---- gate: g = sigmoid(bg + Wg @ mean_p m) computed in-block ----
    __syncthreads();               // all waves done with P in lds
    float* fl=(float*)lds;         // fl[0..127]=mean_c, fl[128..255]=g
    #pragma unroll
    for(int mt=0;mt<2;mt++){
        #pragma unroll
        for(int r=0;r<4;r++){
            float s=0.f;
            #pragma unroll
            for(int nt=0;nt<8;nt++){ float v=pacc[mt][nt][r]; if(nt==7&&l15>8) v=0.f; s+=v; }
            s+=__shfl_xor(s,1); s+=__shfl_xor(s,2); s+=__shfl_xor(s,4); s+=__shfl_xor(s,8);
            if(l15==0) fl[m0+mt*16+kg*4+r]=s*(1.f/121.f);
        }
    }
    __syncthreads();
    if(t<C_){
        float a=bgf[t];
        #pragma unroll 8
        for(int k=0;k<C_;k++) a+=wgT[k*C_+t]*fl[k];
        fl[C_+t]=1.f/(1.f+__expf(-a));
    }
    __syncthreads();
    float w1m=1.f-*wp;
    bf16t* ob=comb+(size_t)sb*CP_;
    #pragma unroll
    for(int mt=0;mt<2;mt++){
        int c0=m0+mt*16+kg*4;
        float gg[4];
        #pragma unroll
        for(int r=0;r<4;r++) gg[r]=fl[C_+c0+r];
        #pragma unroll
        for(int nt=0;nt<8;nt++){
            int p=nt*16+l15;
            if(p>=P_) continue;
            us4 bv=*(const us4*)(ob+(size_t)p*C_+c0);
            #pragma unroll
            for(int r=0;r<4;r++) bv[r]=f2bu(b2f(bv[r]) + w1m*pacc[mt][nt][r]*gg[r]);
            *(us4*)(ob+(size_t)p*C_+c0)=bv;
        }
    }
}

// ---------- 3x3 SAME conv (concat in0T|in1T) via MFMA, A-prefetch pipelined ----------
// MODE 1 (zr): ocb==0 -> o0 = sigmoid (Z); ocb==128 -> o1 = sigmoid * hT (RH)
// MODE 2 (hhat+LN): nh=(1-z)h+z*tanh+h staged to LDS, LayerNorm, write o0 = new hT
template<int MODE>
__global__ __launch_bounds__(256) void conv3_mfma(
    bf16t* __restrict__ o0, bf16t* __restrict__ o1,
    const bf16t* __restrict__ in0T, const bf16t* __restrict__ in1T,
    const bf16t* __restrict__ Wt, const float* __restrict__ bias,
    const bf16t* __restrict__ zT, const bf16t* __restrict__ hTb,
    const float* __restrict__ gamT, const float* __restrict__ betT)
{
    constexpr int OC=(MODE==1)?256:128;
    __shared__ bf16t lin[169*136];
    __shared__ float red[8];
    int sb=blockIdx.x, ocb=(MODE==1)? (int)blockIdx.y*128 : 0;
    int t=threadIdx.x, lane=t&63, w=t>>6;
    int ocr=w>>1, pcr=w&1, l15=lane&15, kg=lane>>4;
    int boff[4]; bool pv_[4];
    #pragma unroll
    for(int nt=0;nt<4;nt++){
        int p=pcr*64+nt*16+l15;
        pv_[nt]=(p<P_); int pc=pv_[nt]?p:(P_-1);
        boff[nt]=((pc/11)*13+(pc%11))*136+kg*8;
    }
    f32x4 acc[4][4];
    #pragma unroll
    for(int i=0;i<4;i++){
        #pragma unroll
        for(int j=0;j<4;j++) acc[i][j]=(f32x4){0.f,0.f,0.f,0.f};
    }
    int base_lane=(ocb+ocr*64+l15)*32+kg*8;
    bf16x8 a0[4],a1[4];
    auto LOADA=[&](bf16x8 (&dst)[4], int idx_){
        #pragma unroll
        for(int mt=0;mt<4;mt++) dst[mt]=*(const bf16x8*)(Wt+(size_t)idx_*(OC*32)+mt*512+base_lane);
    };
    int d=0;
    auto STEP=[&](bf16x8 (&aa)[4], int icb_){
        bf16x8 bb[4];
        #pragma unroll
        for(int nt=0;nt<4;nt++) bb[nt]=*(const bf16x8*)(lin+boff[nt]+d+icb_*32);
        __builtin_amdgcn_s_setprio(1);
        #pragma unroll
        for(int mt=0;mt<4;mt++){
            #pragma unroll
            for(int nt=0;nt<4;nt++)
                acc[mt][nt]=__builtin_amdgcn_mfma_f32_16x16x32_bf16(aa[mt],bb[nt],acc[mt][nt],0,0,0);
        }
        __builtin_amdgcn_s_setprio(0);
    };
    LOADA(a0,0);   // first A in flight before staging
    // zero border pixels
    {
        bf16x8 z;
        #pragma unroll
        for(int e=0;e<8;e++) z[e]=0;
        for(int i=t;i<48*16;i+=256){
            int bi=i>>4, cc=(i&15)*8;
            int pix;
            if(bi<13) pix=bi;
            else if(bi<26) pix=156+(bi-13);
            else { int j2=bi-26; pix=(1+(j2>>1))*13+((j2&1)?12:0); }
            *(bf16x8*)(lin+pix*136+cc)=z;
        }
    }
    for(int hi=0;hi<2;++hi){
        __syncthreads();
        const bf16t* src=(hi? in1T:in0T)+(size_t)sb*CP_;
        for(int i=t;i<1936;i+=256){
            int p=i>>4, cc=(i&15)*8;
            int pix=(p/11+1)*13+(p%11)+1;
            *(bf16x8*)(lin+pix*136+cc)=*(const bf16x8*)(src+(size_t)p*C_+cc);
        }
        __syncthreads();
        int idx=hi*4;
        d=0; int colc=0;
        for(int tap=0;tap<9;++tap){
            int nidx=(tap<8)? idx+8 : (hi==0? 4 : idx);
            LOADA(a1, idx+1); STEP(a0, 0);
            LOADA(a0, idx+2); STEP(a1, 1);
            LOADA(a1, idx+3); STEP(a0, 2);
            LOADA(a0, nidx);  STEP(a1, 3);
            idx=nidx;
            if(colc==2){ colc=0; d+=11*136; } else { colc++; d+=136; }
        }
    }
    if(MODE==1){
        #pragma unroll
        for(int mt=0;mt<4;mt++){
            int ocl=ocr*64+mt*16+kg*4;
            #pragma unroll
            for(int nt=0;nt<4;nt++){
                if(!pv_[nt]) continue;
                int p=pcr*64+nt*16+l15;
                size_t tb=(size_t)sb*CP_+(size_t)p*C_+ocl;
                us4 pk;
                if(ocb==0){
                    #pragma unroll
                    for(int r=0;r<4;r++){ float a=acc[mt][nt][r]+bias[ocl+r]; pk[r]=f2bu(1.f/(1.f+__expf(-a))); }
                    *(us4*)(o0+tb)=pk;
                }else{
                    us4 hv=*(const us4*)(hTb+tb);
                    #pragma unroll
                    for(int r=0;r<4;r++){ float a=acc[mt][nt][r]+bias[128+ocl+r]; float sg=1.f/(1.f+__expf(-a)); pk[r]=f2bu(sg*b2f(hv[r])); }
                    *(us4*)(o1+tb)=pk;
                }
            }
        }
    }else{
        __syncthreads();   // reuse lin for NH
        float ls=0.f, ls2=0.f;
        #pragma unroll
        for(int mt=0;mt<4;mt++){
            int ocl=ocr*64+mt*16+kg*4;
            #pragma unroll
            for(int nt=0;nt<4;nt++){
                if(!pv_[nt]) continue;
                int p=pcr*64+nt*16+l15;
                size_t tb=(size_t)sb*CP_+(size_t)p*C_+ocl;
                us4 hv=*(const us4*)(hTb+tb);
                us4 zv=*(const us4*)(zT+tb);
                us4 pk;
                #pragma unroll
                for(int r=0;r<4;r++){
                    float a=acc[mt][nt][r]+bias[ocl+r];
                    float ht=tanhf(a);
                    float z=b2f(zv[r]), h=b2f(hv[r]);
                    unsigned short u=f2bu((1.f-z)*h+z*ht+h);
                    pk[r]=u;
                    float nr=b2f(u); ls+=nr; ls2+=nr*nr;
                }
                *(us4*)((unsigned short*)lin + p*C_+ocl)=pk;
            }
        }
        #pragma unroll
        for(int o=32;o;o>>=1){ ls+=__shfl_xor(ls,o); ls2+=__shfl_xor(ls2,o); }
        if(lane==0){ red[w]=ls; red[4+w]=ls2; }
        __syncthreads();
        float S=red[0]+red[1]+red[2]+red[3];
        float S2=red[4]+red[5]+red[6]+red[7];
        float mu=S*(1.f/(float)CP_);
        float var=S2*(1.f/(float)CP_)-mu*mu;
        float rstd=rsqrtf(var+1e-5f);
        bf16t* ho=o0+(size_t)sb*CP_;
        for(int i=t;i<CP_;i+=256){
            float v=(ldb(lin+i)-mu)*rstd*gamT[i]+betT[i];
            ho[i]=__float2bfloat16(v);
        }
    }
}

// ---------- final: hT [p][c] -> natural [c][p] output ----------
__global__ __launch_bounds__(256) void finalT_kernel(void* __restrict__ fout, const bf16t* __restrict__ hT, const int* __restrict__ flag){
    __shared__ bf16t tl[CP_];
    int sb=blockIdx.x, t=threadIdx.x, f=*flag;
    for(int i=t;i<CP_;i+=256) tl[i]=hT[(size_t)sb*CP_+i];
    __syncthreads();
    for(int i=t;i<CP_;i+=256){
        int c=i/P_, p=i-c*P_;
        float v=ldb(tl+p*C_+c);
        size_t oi=(size_t)sb*CP_+i;
        if(f) ((float*)fout)[oi]=v;
        else  ((bf16t*)fout)[oi]=__float2bfloat16(v);
    }
}

extern "C" void kernel_launch(void* const* d_in, const int* in_sizes, int n_in,
                              void* d_out, int out_size, void* d_ws, size_t ws_size,
                              hipStream_t stream) {
    (void)in_sizes; (void)n_in; (void)out_size;
    char* base=(char*)d_ws;
    size_t off=0;
    auto alloc=[&](size_t bytes){ void* p=base+off; off+=(bytes+255)&~(size_t)255; return p; };
    bf16t* b1=(bf16t*)alloc((size_t)NEl*2+4096);          // hT
    bf16t* b2=(bf16t*)alloc((size_t)NEl*2+4096);          // qT/intra/comb
    bf16t* b3=(bf16t*)alloc((size_t)SBn*PNT_*2+4096);     // v,yy (padded natural) / RH
    bf16t* b4=(bf16t*)d_out;                              // kT/yyT/Z/final
    bf16t* wqT=(bf16t*)alloc(16384*2);
    bf16t* wkT=(bf16t*)alloc(16384*2);
    bf16t* wvT=(bf16t*)alloc(16384*2);
    bf16t* w2T=(bf16t*)alloc(16384*2);
    bf16t* wzrT=(bf16t*)alloc((size_t)589824*2);
    bf16t* whT =(bf16t*)alloc((size_t)294912*2);
    float* W2f=(float*)alloc(16384*4);
    float* b2l=(float*)alloc(128*4); float* b2r=(float*)alloc(128*4);
    float* bqf=(float*)alloc(128*4); float* bkf=(float*)alloc(128*4); float* bvf=(float*)alloc(128*4);
    float* bzrf=(float*)alloc(256*4); float* bhf=(float*)alloc(128*4);
    float* gamT=(float*)alloc(15488*4); float* betT=(float*)alloc(15488*4);
    float* wgTf=(float*)alloc(16384*4); float* bgf2=(float*)alloc(128*4);
    float* alphaf=(float*)alloc(4); float* weightf=(float*)alloc(4);
    int* flag=(int*)alloc(4);
    if(ws_size<off) return;  // ~100MB needed

    detect_kernel<<<1,64,0,stream>>>((const unsigned short*)d_in[0],flag);
    cvtT_kernel<<<SBn,256,0,stream>>>(b1,d_in[0],flag);
    prep_w1t<1><<<64,256,0,stream>>>(wqT,d_in[1],flag);
    cvt_kernel<<<1,128,0,stream>>>(bqf,d_in[2],128,flag);
    prep_w1t<1><<<64,256,0,stream>>>(wkT,d_in[3],flag);
    cvt_kernel<<<1,128,0,stream>>>(bkf,d_in[4],128,flag);
    prep_w1t<1><<<64,256,0,stream>>>(wvT,d_in[5],flag);
    cvt_kernel<<<1,128,0,stream>>>(bvf,d_in[6],128,flag);
    cvt_kernel<<<1,64,0,stream>>>(alphaf,d_in[7],1,flag);
    prep_msg_kernel<<<C_,C_,0,stream>>>(W2f,b2l,b2r,d_in[10],d_in[8],d_in[9],flag);
    prep_w1t<0><<<64,256,0,stream>>>(w2T,W2f,flag);
    cvt_kernel<<<1,64,0,stream>>>(weightf,d_in[11],1,flag);
    prep_wgt<<<64,256,0,stream>>>(wgTf,bgf2,d_in[12],d_in[13],flag);
    prep_w3t<<<(256*2304+255)/256,256,0,stream>>>(wzrT,d_in[14],flag,256);
    cvt_kernel<<<1,256,0,stream>>>(bzrf,d_in[15],256,flag);
    prep_w3t<<<(128*2304+255)/256,256,0,stream>>>(whT,d_in[16],flag,128);
    cvt_kernel<<<1,128,0,stream>>>(bhf,d_in[17],128,flag);
    prep_gbt<<<(CP_+255)/256,256,0,stream>>>(gamT,betT,d_in[18],d_in[19],flag);

    for(int it=0; it<3; ++it){
        // q->b2(T), k->b4(T), v->b3(N) in one pass
        conv1_qkv<<<SBn,256,0,stream>>>(b2,b4,b3,b1,wqT,wkT,wvT,bqf,bkf,bvf);
        // intra: b2 = w*(alpha*PV + h)
        attn_fused<<<SBn,256,0,stream>>>(b2,b2,b4,b3,b1,alphaf,weightf);
        // left message (sb in [64,1024)): yy from h[sb-64]; comb += (1-w)*m*g
        conv1_msg<<<SBn-B_,256,0,stream>>>(b4,b3,b1,w2T,b2l,B_,-B_);
        msg_fused<<<SBn-B_,256,0,stream>>>(b2,b1,b4,b3,wgTf,bgf2,weightf,B_);
        // right message (sb in [0,960)): yy from h[sb+64]
        conv1_msg<<<SBn-B_,256,0,stream>>>(b4,b3,b1,w2T,b2r,0,B_);
        msg_fused<<<SBn-B_,256,0,stream>>>(b2,b1,b4,b3,wgTf,bgf2,weightf,0);
        // GRU: zr([comb|h]) -> Z->b4, RH->b3 ; hhat([comb|RH]) + LN -> new hT (b1)
        conv3_mfma<1><<<dim3(SBn,2),256,0,stream>>>(b4,b3,b2,b1,wzrT,bzrf,nullptr,b1,nullptr,nullptr);
        conv3_mfma<2><<<dim3(SBn,1),256,0,stream>>>(b1,nullptr,b2,b3,whT,bhf,b4,b1,gamT,betT);
    }
    finalT_kernel<<<SBn,256,0,stream>>>(d_out,b1,flag);
}

// Round 6
// 1573.848 us; speedup vs baseline: 13.8167x; 1.1293x over previous
//
#include <hip/hip_runtime.h>
#include <hip/hip_bf16.h>

// GraphProcessor: S=16,B=64,C=128,H=W=11,P=121, 3 iterations.
// Transposed [sb][p][128ch] bf16 storage; MFMA everywhere; deep fusion.
#define S_   16
#define B_   64
#define SBn  1024
#define C_   128
#define P_   121
#define CP_  15488
static const long NEl = 15859712L; // SBn*CP_

typedef __hip_bfloat16 bf16t;
typedef __attribute__((ext_vector_type(8))) short bf16x8;
typedef __attribute__((ext_vector_type(4))) float f32x4;
typedef __attribute__((ext_vector_type(4))) unsigned short us4;

__device__ __forceinline__ float ldb(const bf16t* p){ return __bfloat162float(*p); }
__device__ __forceinline__ float b2f(unsigned short u){ unsigned x=((unsigned)u)<<16; float f; __builtin_memcpy(&f,&x,4); return f; }
__device__ __forceinline__ unsigned short f2bu(float v){ __hip_bfloat16 b=__float2bfloat16(v); unsigned short u; __builtin_memcpy(&u,&b,2); return u; }
__device__ __forceinline__ float ldin(const void* s, long i, int f){
    return f ? ((const float*)s)[i] : b2f(((const unsigned short*)s)[i]);
}

// ---------- dtype detect: flag=1 if inputs are f32, 0 if bf16 ----------
__global__ void detect_kernel(const unsigned short* __restrict__ x, int* __restrict__ flag){
    if(blockIdx.x==0 && threadIdx.x==0){
        int crazy=0;
        for(int i=0;i<512;i++){
            unsigned e=(x[i]>>7)&0xFF;
            if(e!=0 && (e<64 || e>191)) crazy++;
        }
        *flag=(crazy>40)?1:0;
    }
}

// ---------- raw input -> f32 ----------
__global__ void cvt_kernel(float* __restrict__ dst, const void* __restrict__ src, long n, const int* __restrict__ flag){
    long i=(long)blockIdx.x*blockDim.x+threadIdx.x;
    long st=(long)gridDim.x*blockDim.x;
    int f=*flag;
    for(;i<n;i+=st) dst[i]=ldin(src,i,f);
}

// ---------- x [sb][c][p] -> hT [sb][p][c] bf16 ----------
__global__ __launch_bounds__(256) void cvtT_kernel(bf16t* __restrict__ hT, const void* __restrict__ x, const int* __restrict__ flag){
    int sb=blockIdx.x, t=threadIdx.x; int f=*flag;
    for(int i=t;i<CP_;i+=256){
        int c=i/P_, p=i-c*P_;
        float v=ldin(x,(long)sb*CP_+i,f);
        hT[(size_t)sb*CP_+(size_t)p*C_+c]=__float2bfloat16(v);
    }
}

// ---------- fold w_lin @ w_msg[:, :C] into W2 (f32), edge bias into b2l/b2r ----------
__global__ __launch_bounds__(128) void prep_msg_kernel(float* __restrict__ W2, float* __restrict__ b2l, float* __restrict__ b2r,
        const void* __restrict__ wlin, const void* __restrict__ wmsg, const void* __restrict__ bmsg, const int* __restrict__ flag){
    int d=blockIdx.x, c=threadIdx.x; int f=*flag;
    float acc=0.f;
    for(int o2=0;o2<C_;o2++) acc += ldin(wlin,(long)d*C_+o2,f)*ldin(wmsg,(long)o2*(C_+1)+c,f);
    W2[d*C_+c]=acc;
    if(c<2){
        float e=(c==0)?1.f:-1.f; float a=0.f;
        for(int o2=0;o2<C_;o2++) a += ldin(wlin,(long)d*C_+o2,f)*(ldin(bmsg,o2,f)+e*ldin(wmsg,(long)o2*(C_+1)+C_,f));
        if(c==0) b2l[d]=a; else b2r[d]=a;
    }
}

// ---------- 1x1 weight [oc][128ic] -> tiled bf16 [icb(4)][oc(128)][32] ----------
template<int RAW>
__global__ void prep_w1t(bf16t* __restrict__ dst, const void* __restrict__ src, const int* __restrict__ flag){
    int idx=blockIdx.x*blockDim.x+threadIdx.x;
    if(idx>=16384) return;
    int r=idx&31, oc=(idx>>5)&127, icb=idx>>12;
    float v = RAW? ldin(src,(long)oc*C_+icb*32+r,*flag) : ((const float*)src)[(long)oc*C_+icb*32+r];
    dst[idx]=__float2bfloat16(v);
}

// ---------- 3x3 weight [oc][256ic][3][3] -> tiled bf16 [tap][icb(8)][oc][32] ----------
__global__ void prep_w3t(bf16t* __restrict__ dst, const void* __restrict__ src, const int* __restrict__ flag, int OC){
    int idx=blockIdx.x*blockDim.x+threadIdx.x;
    int tot=OC*2304;
    if(idx>=tot) return;
    int r=idx&31; int rest=idx>>5; int oc=rest%OC; int g2=rest/OC; int icb=g2&7, tap=g2>>3;
    float v=ldin(src,((long)(oc*256+icb*32+r))*9+tap,*flag);
    dst[idx]=__float2bfloat16(v);
}

// ---------- gamma/beta [c][p] -> transposed f32 [p][c] ----------
__global__ void prep_gbt(float* __restrict__ gamT, float* __restrict__ betT,
                         const void* __restrict__ gam, const void* __restrict__ bet, const int* __restrict__ flag){
    int idx=blockIdx.x*blockDim.x+threadIdx.x;
    if(idx>=CP_) return;
    int c=idx/P_, p=idx-c*P_; int f=*flag;
    gamT[p*C_+c]=ldin(gam,idx,f);
    betT[p*C_+c]=ldin(bet,idx,f);
}

// ---------- w_gate [c][k] -> transposed f32 [k][c]; b_gate -> f32 ----------
__global__ void prep_wgt(float* __restrict__ wgT, float* __restrict__ bg2,
                         const void* __restrict__ wg, const void* __restrict__ bg, const int* __restrict__ flag){
    int idx=blockIdx.x*blockDim.x+threadIdx.x;
    int f=*flag;
    if(idx<16384){ int k=idx>>7, c=idx&127; wgT[idx]=ldin(wg,(long)c*C_+k,f); }
    if(idx<128) bg2[idx]=ldin(bg,idx,f);
}

// ---------- 128(M) x 128(N) x 128(K) GEMM tile for 8 waves (2 ocr x 4 pcr) ----------
__device__ __forceinline__ void gemm_tile24(f32x4 (&acc)[4][2],
    const bf16t* __restrict__ Wt, const bf16t* __restrict__ Bsrc,
    int ocr,int pcr,int l15,int kg)
{
    #pragma unroll
    for(int i=0;i<4;i++){
        #pragma unroll
        for(int j=0;j<2;j++) acc[i][j]=(f32x4){0.f,0.f,0.f,0.f};
    }
    #pragma unroll
    for(int kc=0;kc<4;kc++){
        bf16x8 a[4],b[2];
        #pragma unroll
        for(int mt=0;mt<4;mt++) a[mt]=*(const bf16x8*)(Wt+((size_t)(kc*C_+ocr*64+mt*16+l15))*32+kg*8);
        #pragma unroll
        for(int nt=0;nt<2;nt++) b[nt]=*(const bf16x8*)(Bsrc+(size_t)(pcr*32+nt*16+l15)*136+kc*32+kg*8);
        #pragma unroll
        for(int mt=0;mt<4;mt++){
            #pragma unroll
            for(int nt=0;nt<2;nt++)
                acc[mt][nt]=__builtin_amdgcn_mfma_f32_16x16x32_bf16(a[mt],b[nt],acc[mt][nt],0,0,0);
        }
    }
}

// ---------- fused qkv + intra attention per (s,b), 512 threads ----------
// comb = w*(alpha * softmax(qk^T*scale) v + h)
__global__ __launch_bounds__(512) void qkv_attn(
    bf16t* __restrict__ comb, const bf16t* __restrict__ hT,
    const bf16t* __restrict__ WqT, const bf16t* __restrict__ WkT, const bf16t* __restrict__ WvT,
    const float* __restrict__ bq, const float* __restrict__ bk, const float* __restrict__ bv,
    const float* __restrict__ alphap, const float* __restrict__ wp)
{
    __shared__ bf16t L[3*128*136];
    bf16t* Lh=L; bf16t* Lq=L+128*136; bf16t* Lk=L+2*128*136;
    bf16t* Lv=Lk; bf16t* LP=Lq;     // overlays after QK
    int sb=blockIdx.x, t=threadIdx.x, lane=t&63, w=t>>6;
    int l15=lane&15, kg=lane>>4;
    {
        const bf16t* hp=hT+(size_t)sb*CP_;
        bf16x8 z;
        #pragma unroll
        for(int e=0;e<8;e++) z[e]=0;
        for(int i=t;i<2048;i+=512){
            int r=i>>4, cc=(i&15)*8;
            bf16x8 v=(r<P_)? *(const bf16x8*)(hp+(size_t)r*C_+cc):z;
            *(bf16x8*)(Lh+r*136+cc)=v;
        }
    }
    __syncthreads();
    int ocr=w>>2, pcr=w&3;
    f32x4 acc[4][2];
    gemm_tile24(acc,WqT,Lh,ocr,pcr,l15,kg);
    #pragma unroll
    for(int mt=0;mt<4;mt++){
        int oc0=ocr*64+mt*16+kg*4;
        #pragma unroll
        for(int nt=0;nt<2;nt++){
            int p=pcr*32+nt*16+l15;
            us4 pk;
            #pragma unroll
            for(int r=0;r<4;r++) pk[r]=f2bu(acc[mt][nt][r]+bq[oc0+r]);
            *(us4*)(Lq+p*136+oc0)=pk;
        }
    }
    gemm_tile24(acc,WkT,Lh,ocr,pcr,l15,kg);
    #pragma unroll
    for(int mt=0;mt<4;mt++){
        int oc0=ocr*64+mt*16+kg*4;
        #pragma unroll
        for(int nt=0;nt<2;nt++){
            int p=pcr*32+nt*16+l15;
            us4 pk;
            #pragma unroll
            for(int r=0;r<4;r++) pk[r]=f2bu(acc[mt][nt][r]+bk[oc0+r]);
            *(us4*)(Lk+p*136+oc0)=pk;
        }
    }
    __syncthreads();
    // QK^T: rows m0..m0+15
    int m0=w*16;
    f32x4 s[8];
    #pragma unroll
    for(int nt=0;nt<8;nt++) s[nt]=(f32x4){0.f,0.f,0.f,0.f};
    #pragma unroll
    for(int kc=0;kc<4;kc++){
        bf16x8 a=*(const bf16x8*)(Lq+(size_t)(m0+l15)*136+kc*32+kg*8);
        #pragma unroll
        for(int nt=0;nt<8;nt++){
            bf16x8 b=*(const bf16x8*)(Lk+(size_t)(nt*16+l15)*136+kc*32+kg*8);
            s[nt]=__builtin_amdgcn_mfma_f32_16x16x32_bf16(a,b,s[nt],0,0,0);
        }
    }
    const float scale=0.08838834764831845f;
    #pragma unroll
    for(int nt=0;nt<8;nt++){
        #pragma unroll
        for(int r=0;r<4;r++) s[nt][r]*=scale;
    }
    if(l15>=9){
        #pragma unroll
        for(int r=0;r<4;r++) s[7][r]=-3.0e38f;
    }
    #pragma unroll
    for(int r=0;r<4;r++){
        float mx=s[0][r];
        #pragma unroll
        for(int nt=1;nt<8;nt++) mx=fmaxf(mx,s[nt][r]);
        #pragma unroll
        for(int o=1;o<16;o<<=1) mx=fmaxf(mx,__shfl_xor(mx,o));
        float sm=0.f;
        #pragma unroll
        for(int nt=0;nt<8;nt++){ float e=__expf(s[nt][r]-mx); s[nt][r]=e; sm+=e; }
        #pragma unroll
        for(int o=1;o<16;o<<=1) sm+=__shfl_xor(sm,o);
        float rs=1.f/sm;
        #pragma unroll
        for(int nt=0;nt<8;nt++) s[nt][r]*=rs;
    }
    __syncthreads();   // all waves done reading Lq(q), Lk(k)
    // v GEMM into Lv (over Lk); P into LP (over Lq, own rows)
    gemm_tile24(acc,WvT,Lh,ocr,pcr,l15,kg);
    #pragma unroll
    for(int mt=0;mt<4;mt++){
        int oc0=ocr*64+mt*16+kg*4;
        #pragma unroll
        for(int nt=0;nt<2;nt++){
            int p=pcr*32+nt*16+l15;
            #pragma unroll
            for(int r=0;r<4;r++)
                Lv[(oc0+r)*136+p]=__float2bfloat16(p<P_? acc[mt][nt][r]+bv[oc0+r] : 0.f);
        }
    }
    #pragma unroll
    for(int r=0;r<4;r++){
        int pr=m0+kg*4+r;
        #pragma unroll
        for(int nt=0;nt<8;nt++) LP[pr*136+nt*16+l15]=__float2bfloat16(s[nt][r]);
    }
    __syncthreads();
    // PV
    f32x4 o[8];
    #pragma unroll
    for(int nt=0;nt<8;nt++) o[nt]=(f32x4){0.f,0.f,0.f,0.f};
    #pragma unroll
    for(int jc=0;jc<4;jc++){
        bf16x8 a=*(const bf16x8*)(Lv+(size_t)(m0+l15)*136+jc*32+kg*8);
        #pragma unroll
        for(int nt=0;nt<8;nt++){
            bf16x8 b=*(const bf16x8*)(LP+(size_t)(nt*16+l15)*136+jc*32+kg*8);
            o[nt]=__builtin_amdgcn_mfma_f32_16x16x32_bf16(a,b,o[nt],0,0,0);
        }
    }
    float al=*alphap, wv=*wp;
    int c0=m0+kg*4;
    bf16t* ob=comb+(size_t)sb*CP_;
    #pragma unroll
    for(int nt=0;nt<8;nt++){
        int p=nt*16+l15;
        if(p>=P_) continue;
        us4 hv=*(const us4*)(Lh+p*136+c0);
        us4 pk;
        #pragma unroll
        for(int r=0;r<4;r++) pk[r]=f2bu(wv*(al*o[nt][r]+b2f(hv[r])));
        *(us4*)(ob+(size_t)p*C_+c0)=pk;
    }
}

// ---------- fused msg: yy=W2@h_shift; m=softmax(h yy^T) yy; gate; comb += (1-w)*m*g ----------
__global__ __launch_bounds__(512) void msg_all(
    bf16t* __restrict__ comb, const bf16t* __restrict__ hT,
    const bf16t* __restrict__ W2T, const float* __restrict__ b2e,
    const float* __restrict__ wgT, const float* __restrict__ bgf,
    const float* __restrict__ wp, int sb0, int shift)
{
    __shared__ bf16t L[3*128*136];
    bf16t* Lsh=L; bf16t* Lyy=L+128*136; bf16t* LyyV=L+2*128*136;
    bf16t* LP=Lsh;      // overlays after phase A
    int sb=sb0+blockIdx.x, t=threadIdx.x, lane=t&63, w=t>>6;
    int l15=lane&15, kg=lane>>4;
    {
        const bf16t* hp=hT+(size_t)(sb+shift)*CP_;
        bf16x8 z;
        #pragma unroll
        for(int e=0;e<8;e++) z[e]=0;
        for(int i=t;i<2048;i+=512){
            int r=i>>4, cc=(i&15)*8;
            bf16x8 v=(r<P_)? *(const bf16x8*)(hp+(size_t)r*C_+cc):z;
            *(bf16x8*)(Lsh+r*136+cc)=v;
        }
    }
    __syncthreads();
    int ocr=w>>2, pcr=w&3;
    f32x4 acc[4][2];
    gemm_tile24(acc,W2T,Lsh,ocr,pcr,l15,kg);
    #pragma unroll
    for(int mt=0;mt<4;mt++){
        int oc0=ocr*64+mt*16+kg*4;
        #pragma unroll
        for(int nt=0;nt<2;nt++){
            int p=pcr*32+nt*16+l15;
            us4 pk;
            #pragma unroll
            for(int r=0;r<4;r++){
                float v=acc[mt][nt][r]+b2e[oc0+r];
                pk[r]=f2bu(v);
                LyyV[(oc0+r)*136+p]=__float2bfloat16(p<P_? v : 0.f);
            }
            *(us4*)(Lyy+p*136+oc0)=pk;
        }
    }
    __syncthreads();
    // logits: A = own h rows from global, B = yy in LDS; no scale
    int m0=w*16;
    const bf16t* ap=hT+(size_t)sb*CP_;
    f32x4 s[8];
    #pragma unroll
    for(int nt=0;nt<8;nt++) s[nt]=(f32x4){0.f,0.f,0.f,0.f};
    #pragma unroll
    for(int kc=0;kc<4;kc++){
        bf16x8 a=*(const bf16x8*)(ap+(size_t)(m0+l15)*C_+kc*32+kg*8);
        #pragma unroll
        for(int nt=0;nt<8;nt++){
            bf16x8 b=*(const bf16x8*)(Lyy+(size_t)(nt*16+l15)*136+kc*32+kg*8);
            s[nt]=__builtin_amdgcn_mfma_f32_16x16x32_bf16(a,b,s[nt],0,0,0);
        }
    }
    if(l15>=9){
        #pragma unroll
        for(int r=0;r<4;r++) s[7][r]=-3.0e38f;
    }
    #pragma unroll
    for(int r=0;r<4;r++){
        float mx=s[0][r];
        #pragma unroll
        for(int nt=1;nt<8;nt++) mx=fmaxf(mx,s[nt][r]);
        #pragma unroll
        for(int o=1;o<16;o<<=1) mx=fmaxf(mx,__shfl_xor(mx,o));
        float sm=0.f;
        #pragma unroll
        for(int nt=0;nt<8;nt++){ float e=__expf(s[nt][r]-mx); s[nt][r]=e; sm+=e; }
        #pragma unroll
        for(int o=1;o<16;o<<=1) sm+=__shfl_xor(sm,o);
        float rs=1.f/sm;
        #pragma unroll
        for(int nt=0;nt<8;nt++) s[nt][r]*=rs;
    }
    #pragma unroll
    for(int r=0;r<4;r++){
        int pr=m0+kg*4+r;
        #pragma unroll
        for(int nt=0;nt<8;nt++) LP[pr*136+nt*16+l15]=__float2bfloat16(s[nt][r]);
    }
    __syncthreads();
    // PV: m[c][p]
    f32x4 o[8];
    #pragma unroll
    for(int nt=0;nt<8;nt++) o[nt]=(f32x4){0.f,0.f,0.f,0.f};
    #pragma unroll
    for(int jc=0;jc<4;jc++){
        bf16x8 a=*(const bf16x8*)(LyyV+(size_t)(m0+l15)*136+jc*32+kg*8);
        #pragma unroll
        for(int nt=0;nt<8;nt++){
            bf16x8 b=*(const bf16x8*)(LP+(size_t)(nt*16+l15)*136+jc*32+kg*8);
            o[nt]=__builtin_amdgcn_mfma_f32_16x16x32_bf16(a,b,o[nt],0,0,0);
        }
    }
    // gate: mean over p, then matvec + sigmoid
    float* fl=(float*)Lyy;     // Lyy free after QK
    int c0=m0+kg*4;
    #pragma unroll
    for(int r=0;r<4;r++){
        float sm=0.f;
        #pragma unroll
        for(int nt=0;nt<8;nt++){ float v=o[nt][r]; if(nt==7&&l15>8) v=0.f; sm+=v; }
        sm+=__shfl_xor(sm,1); sm+=__shfl_xor(sm,2); sm+=__shfl_xor(sm,4); sm+=__shfl_xor(sm,8);
        if(l15==0) fl[c0+r]=sm*(1.f/121.f);
    }
    __syncthreads();
    if(t<C_){
        float a=bgf[t];
        #pragma unroll 8
        for(int k=0;k<C_;k++) a+=wgT[k*C_+t]*fl[k];
        fl[C_+t]=1.f/(1.f+__expf(-a));
    }
    __syncthreads();
    float w1m=1.f-*wp;
    float gg[4];
    #pragma unroll
    for(int r=0;r<4;r++) gg[r]=fl[C_+c0+r];
    bf16t* ob=comb+(size_t)sb*CP_;
    #pragma unroll
    for(int nt=0;nt<8;nt++){
        int p=nt*16+l15;
        if(p>=P_) continue;
        us4 bv=*(const us4*)(ob+(size_t)p*C_+c0);
        #pragma unroll
        for(int r=0;r<4;r++) bv[r]=f2bu(b2f(bv[r]) + w1m*o[nt][r]*gg[r]);
        *(us4*)(ob+(size_t)p*C_+c0)=bv;
    }
}

// ---------- 3x3 SAME conv (concat in0T|in1T) via MFMA, 4-buffer A-prefetch (dist 2) ----------
// MODE 1 (zr): ocb==0 -> o0 = sigmoid (Z); ocb==128 -> o1 = sigmoid * hT (RH)
// MODE 2 (hhat+LN): nh=(1-z)h+z*tanh+h staged to LDS, LayerNorm, write o0 = new hT
template<int MODE>
__global__ __launch_bounds__(256) void conv3_mfma(
    bf16t* __restrict__ o0, bf16t* __restrict__ o1,
    const bf16t* __restrict__ in0T, const bf16t* __restrict__ in1T,
    const bf16t* __restrict__ Wt, const float* __restrict__ bias,
    const bf16t* __restrict__ zT, const bf16t* __restrict__ hTb,
    const float* __restrict__ gamT, const float* __restrict__ betT)
{
    constexpr int OC=(MODE==1)?256:128;
    __shared__ bf16t lin[169*136];
    __shared__ float red[8];
    int sb=blockIdx.x, ocb=(MODE==1)? (int)blockIdx.y*128 : 0;
    int t=threadIdx.x, lane=t&63, w=t>>6;
    int ocr=w>>1, pcr=w&1, l15=lane&15, kg=lane>>4;
    int boff[4]; bool pv_[4];
    #pragma unroll
    for(int nt=0;nt<4;nt++){
        int p=pcr*64+nt*16+l15;
        pv_[nt]=(p<P_); int pc=pv_[nt]?p:(P_-1);
        boff[nt]=((pc/11)*13+(pc%11))*136+kg*8;
    }
    f32x4 acc[4][4];
    #pragma unroll
    for(int i=0;i<4;i++){
        #pragma unroll
        for(int j=0;j<4;j++) acc[i][j]=(f32x4){0.f,0.f,0.f,0.f};
    }
    int base_lane=(ocb+ocr*64+l15)*32+kg*8;
    bf16x8 a0[4],a1[4],a2[4],a3[4];
    auto LOADA=[&](bf16x8 (&dst)[4], int idx_){
        #pragma unroll
        for(int mt=0;mt<4;mt++) dst[mt]=*(const bf16x8*)(Wt+(size_t)idx_*(OC*32)+mt*512+base_lane);
    };
    int d=0;
    auto STEP=[&](bf16x8 (&aa)[4], int icb_){
        bf16x8 bb[4];
        #pragma unroll
        for(int nt=0;nt<4;nt++) bb[nt]=*(const bf16x8*)(lin+boff[nt]+d+icb_*32);
        __builtin_amdgcn_s_setprio(1);
        #pragma unroll
        for(int mt=0;mt<4;mt++){
            #pragma unroll
            for(int nt=0;nt<4;nt++)
                acc[mt][nt]=__builtin_amdgcn_mfma_f32_16x16x32_bf16(aa[mt],bb[nt],acc[mt][nt],0,0,0);
        }
        __builtin_amdgcn_s_setprio(0);
    };
    LOADA(a0,0); LOADA(a1,1);   // steps 0,1 in flight before staging
    // zero border pixels
    {
        bf16x8 z;
        #pragma unroll
        for(int e=0;e<8;e++) z[e]=0;
        for(int i=t;i<48*16;i+=256){
            int bi=i>>4, cc=(i&15)*8;
            int pix;
            if(bi<13) pix=bi;
            else if(bi<26) pix=156+(bi-13);
            else { int j2=bi-26; pix=(1+(j2>>1))*13+((j2&1)?12:0); }
            *(bf16x8*)(lin+pix*136+cc)=z;
        }
    }
    for(int hi=0;hi<2;++hi){
        __syncthreads();
        const bf16t* src=(hi? in1T:in0T)+(size_t)sb*CP_;
        for(int i=t;i<1936;i+=256){
            int p=i>>4, cc=(i&15)*8;
            int pix=(p/11+1)*13+(p%11)+1;
            *(bf16x8*)(lin+pix*136+cc)=*(const bf16x8*)(src+(size_t)p*C_+cc);
        }
        __syncthreads();
        int ib=hi*4;
        d=0; int colc=0;
        for(int tap=0;tap<9;++tap){
            int t2=tap*8+ib+2, t3=tap*8+ib+3;
            int n0,n1;
            if(tap<8){ n0=(tap+1)*8+ib; n1=n0+1; }
            else if(hi==0){ n0=4; n1=5; }
            else { n0=t2; n1=t3; }
            LOADA(a2,t2); STEP(a0,0);
            LOADA(a3,t3); STEP(a1,1);
            LOADA(a0,n0); STEP(a2,2);
            LOADA(a1,n1); STEP(a3,3);
            if(colc==2){ colc=0; d+=11*136; } else { colc++; d+=136; }
        }
    }
    if(MODE==1){
        #pragma unroll
        for(int mt=0;mt<4;mt++){
            int ocl=ocr*64+mt*16+kg*4;
            #pragma unroll
            for(int nt=0;nt<4;nt++){
                if(!pv_[nt]) continue;
                int p=pcr*64+nt*16+l15;
                size_t tb=(size_t)sb*CP_+(size_t)p*C_+ocl;
                us4 pk;
                if(ocb==0){
                    #pragma unroll
                    for(int r=0;r<4;r++){ float a=acc[mt][nt][r]+bias[ocl+r]; pk[r]=f2bu(1.f/(1.f+__expf(-a))); }
                    *(us4*)(o0+tb)=pk;
                }else{
                    us4 hv=*(const us4*)(hTb+tb);
                    #pragma unroll
                    for(int r=0;r<4;r++){ float a=acc[mt][nt][r]+bias[128+ocl+r]; float sg=1.f/(1.f+__expf(-a)); pk[r]=f2bu(sg*b2f(hv[r])); }
                    *(us4*)(o1+tb)=pk;
                }
            }
        }
    }else{
        __syncthreads();   // reuse lin for NH
        float ls=0.f, ls2=0.f;
        #pragma unroll
        for(int mt=0;mt<4;mt++){
            int ocl=ocr*64+mt*16+kg*4;
            #pragma unroll
            for(int nt=0;nt<4;nt++){
                if(!pv_[nt]) continue;
                int p=pcr*64+nt*16+l15;
                size_t tb=(size_t)sb*CP_+(size_t)p*C_+ocl;
                us4 hv=*(const us4*)(hTb+tb);
                us4 zv=*(const us4*)(zT+tb);
                us4 pk;
                #pragma unroll
                for(int r=0;r<4;r++){
                    float a=acc[mt][nt][r]+bias[ocl+r];
                    float ht=tanhf(a);
                    float z=b2f(zv[r]), h=b2f(hv[r]);
                    unsigned short u=f2bu((1.f-z)*h+z*ht+h);
                    pk[r]=u;
                    float nr=b2f(u); ls+=nr; ls2+=nr*nr;
                }
                *(us4*)((unsigned short*)lin + p*C_+ocl)=pk;
            }
        }
        #pragma unroll
        for(int o=32;o;o>>=1){ ls+=__shfl_xor(ls,o); ls2+=__shfl_xor(ls2,o); }
        if(lane==0){ red[w]=ls; red[4+w]=ls2; }
        __syncthreads();
        float Sx=red[0]+red[1]+red[2]+red[3];
        float Sx2=red[4]+red[5]+red[6]+red[7];
        float mu=Sx*(1.f/(float)CP_);
        float var=Sx2*(1.f/(float)CP_)-mu*mu;
        float rstd=rsqrtf(var+1e-5f);
        bf16t* ho=o0+(size_t)sb*CP_;
        for(int i=t;i<CP_;i+=256){
            float v=(ldb(lin+i)-mu)*rstd*gamT[i]+betT[i];
            ho[i]=__float2bfloat16(v);
        }
    }
}

// ---------- final: hT [p][c] -> natural [c][p] output ----------
__global__ __launch_bounds__(256) void finalT_kernel(void* __restrict__ fout, const bf16t* __restrict__ hT, const int* __restrict__ flag){
    __shared__ bf16t tl[CP_];
    int sb=blockIdx.x, t=threadIdx.x, f=*flag;
    for(int i=t;i<CP_;i+=256) tl[i]=hT[(size_t)sb*CP_+i];
    __syncthreads();
    for(int i=t;i<CP_;i+=256){
        int c=i/P_, p=i-c*P_;
        float v=ldb(tl+p*C_+c);
        size_t oi=(size_t)sb*CP_+i;
        if(f) ((float*)fout)[oi]=v;
        else  ((bf16t*)fout)[oi]=__float2bfloat16(v);
    }
}

extern "C" void kernel_launch(void* const* d_in, const int* in_sizes, int n_in,
                              void* d_out, int out_size, void* d_ws, size_t ws_size,
                              hipStream_t stream) {
    (void)in_sizes; (void)n_in; (void)out_size;
    char* base=(char*)d_ws;
    size_t off=0;
    auto alloc=[&](size_t bytes){ void* p=base+off; off+=(bytes+255)&~(size_t)255; return p; };
    bf16t* b1=(bf16t*)alloc((size_t)NEl*2+8192);          // hT
    bf16t* b2=(bf16t*)alloc((size_t)NEl*2+8192);          // comb
    bf16t* b3=(bf16t*)alloc((size_t)NEl*2+8192);          // RH
    bf16t* b4=(bf16t*)d_out;                              // Z / final
    bf16t* wqT=(bf16t*)alloc(16384*2);
    bf16t* wkT=(bf16t*)alloc(16384*2);
    bf16t* wvT=(bf16t*)alloc(16384*2);
    bf16t* w2T=(bf16t*)alloc(16384*2);
    bf16t* wzrT=(bf16t*)alloc((size_t)589824*2);
    bf16t* whT =(bf16t*)alloc((size_t)294912*2);
    float* W2f=(float*)alloc(16384*4);
    float* b2l=(float*)alloc(128*4); float* b2r=(float*)alloc(128*4);
    float* bqf=(float*)alloc(128*4); float* bkf=(float*)alloc(128*4); float* bvf=(float*)alloc(128*4);
    float* bzrf=(float*)alloc(256*4); float* bhf=(float*)alloc(128*4);
    float* gamT=(float*)alloc(15488*4); float* betT=(float*)alloc(15488*4);
    float* wgTf=(float*)alloc(16384*4); float* bgf2=(float*)alloc(128*4);
    float* alphaf=(float*)alloc(4); float* weightf=(float*)alloc(4);
    int* flag=(int*)alloc(4);
    if(ws_size<off) return;  // ~100MB needed

    detect_kernel<<<1,64,0,stream>>>((const unsigned short*)d_in[0],flag);
    cvtT_kernel<<<SBn,256,0,stream>>>(b1,d_in[0],flag);
    prep_w1t<1><<<64,256,0,stream>>>(wqT,d_in[1],flag);
    cvt_kernel<<<1,128,0,stream>>>(bqf,d_in[2],128,flag);
    prep_w1t<1><<<64,256,0,stream>>>(wkT,d_in[3],flag);
    cvt_kernel<<<1,128,0,stream>>>(bkf,d_in[4],128,flag);
    prep_w1t<1><<<64,256,0,stream>>>(wvT,d_in[5],flag);
    cvt_kernel<<<1,128,0,stream>>>(bvf,d_in[6],128,flag);
    cvt_kernel<<<1,64,0,stream>>>(alphaf,d_in[7],1,flag);
    prep_msg_kernel<<<C_,C_,0,stream>>>(W2f,b2l,b2r,d_in[10],d_in[8],d_in[9],flag);
    prep_w1t<0><<<64,256,0,stream>>>(w2T,W2f,flag);
    cvt_kernel<<<1,64,0,stream>>>(weightf,d_in[11],1,flag);
    prep_wgt<<<64,256,0,stream>>>(wgTf,bgf2,d_in[12],d_in[13],flag);
    prep_w3t<<<(256*2304+255)/256,256,0,stream>>>(wzrT,d_in[14],flag,256);
    cvt_kernel<<<1,256,0,stream>>>(bzrf,d_in[15],256,flag);
    prep_w3t<<<(128*2304+255)/256,256,0,stream>>>(whT,d_in[16],flag,128);
    cvt_kernel<<<1,128,0,stream>>>(bhf,d_in[17],128,flag);
    prep_gbt<<<(CP_+255)/256,256,0,stream>>>(gamT,betT,d_in[18],d_in[19],flag);

    for(int it=0; it<3; ++it){
        // intra: comb(b2) = w*(alpha*attn(h) + h)
        qkv_attn<<<SBn,512,0,stream>>>(b2,b1,wqT,wkT,wvT,bqf,bkf,bvf,alphaf,weightf);
        // left message (sb in [64,1024)): comb += (1-w)*m*g
        msg_all<<<SBn-B_,512,0,stream>>>(b2,b1,w2T,b2l,wgTf,bgf2,weightf,B_,-B_);
        // right message (sb in [0,960))
        msg_all<<<SBn-B_,512,0,stream>>>(b2,b1,w2T,b2r,wgTf,bgf2,weightf,0,B_);
        // GRU: zr([comb|h]) -> Z->b4, RH->b3 ; hhat([comb|RH]) + LN -> new hT (b1)
        conv3_mfma<1><<<dim3(SBn,2),256,0,stream>>>(b4,b3,b2,b1,wzrT,bzrf,nullptr,b1,nullptr,nullptr);
        conv3_mfma<2><<<dim3(SBn,1),256,0,stream>>>(b1,nullptr,b2,b3,whT,bhf,b4,b1,gamT,betT);
    }
    finalT_kernel<<<SBn,256,0,stream>>>(d_out,b1,flag);
}

// Round 7
// 1521.487 us; speedup vs baseline: 14.2922x; 1.0344x over previous
//
#include <hip/hip_runtime.h>
#include <hip/hip_bf16.h>

// GraphProcessor: S=16,B=64,C=128,H=W=11,P=121, 3 iterations.
// Transposed [sb][p][128ch] bf16 storage; MFMA everywhere; deep fusion.
#define S_   16
#define B_   64
#define SBn  1024
#define C_   128
#define P_   121
#define CP_  15488
static const long NEl = 15859712L; // SBn*CP_

typedef __hip_bfloat16 bf16t;
typedef __attribute__((ext_vector_type(8))) short bf16x8;
typedef __attribute__((ext_vector_type(4))) float f32x4;
typedef __attribute__((ext_vector_type(4))) unsigned short us4;

__device__ __forceinline__ float ldb(const bf16t* p){ return __bfloat162float(*p); }
__device__ __forceinline__ float b2f(unsigned short u){ unsigned x=((unsigned)u)<<16; float f; __builtin_memcpy(&f,&x,4); return f; }
__device__ __forceinline__ unsigned short f2bu(float v){ __hip_bfloat16 b=__float2bfloat16(v); unsigned short u; __builtin_memcpy(&u,&b,2); return u; }
__device__ __forceinline__ float ldin(const void* s, long i, int f){
    return f ? ((const float*)s)[i] : b2f(((const unsigned short*)s)[i]);
}

// ---------- dtype detect: flag=1 if inputs are f32, 0 if bf16 ----------
__global__ void detect_kernel(const unsigned short* __restrict__ x, int* __restrict__ flag){
    if(blockIdx.x==0 && threadIdx.x==0){
        int crazy=0;
        for(int i=0;i<512;i++){
            unsigned e=(x[i]>>7)&0xFF;
            if(e!=0 && (e<64 || e>191)) crazy++;
        }
        *flag=(crazy>40)?1:0;
    }
}

// ---------- raw input -> f32 ----------
__global__ void cvt_kernel(float* __restrict__ dst, const void* __restrict__ src, long n, const int* __restrict__ flag){
    long i=(long)blockIdx.x*blockDim.x+threadIdx.x;
    long st=(long)gridDim.x*blockDim.x;
    int f=*flag;
    for(;i<n;i+=st) dst[i]=ldin(src,i,f);
}

// ---------- x [sb][c][p] -> hT [sb][p][c] bf16 ----------
__global__ __launch_bounds__(256) void cvtT_kernel(bf16t* __restrict__ hT, const void* __restrict__ x, const int* __restrict__ flag){
    int sb=blockIdx.x, t=threadIdx.x; int f=*flag;
    for(int i=t;i<CP_;i+=256){
        int c=i/P_, p=i-c*P_;
        float v=ldin(x,(long)sb*CP_+i,f);
        hT[(size_t)sb*CP_+(size_t)p*C_+c]=__float2bfloat16(v);
    }
}

// ---------- fold w_lin @ w_msg[:, :C] into W2 (f32), edge bias into b2l/b2r ----------
__global__ __launch_bounds__(128) void prep_msg_kernel(float* __restrict__ W2, float* __restrict__ b2l, float* __restrict__ b2r,
        const void* __restrict__ wlin, const void* __restrict__ wmsg, const void* __restrict__ bmsg, const int* __restrict__ flag){
    int d=blockIdx.x, c=threadIdx.x; int f=*flag;
    float acc=0.f;
    for(int o2=0;o2<C_;o2++) acc += ldin(wlin,(long)d*C_+o2,f)*ldin(wmsg,(long)o2*(C_+1)+c,f);
    W2[d*C_+c]=acc;
    if(c<2){
        float e=(c==0)?1.f:-1.f; float a=0.f;
        for(int o2=0;o2<C_;o2++) a += ldin(wlin,(long)d*C_+o2,f)*(ldin(bmsg,o2,f)+e*ldin(wmsg,(long)o2*(C_+1)+C_,f));
        if(c==0) b2l[d]=a; else b2r[d]=a;
    }
}

// ---------- 1x1 weight [oc][128ic] -> tiled bf16 [icb(4)][oc(128)][32] ----------
template<int RAW>
__global__ void prep_w1t(bf16t* __restrict__ dst, const void* __restrict__ src, const int* __restrict__ flag){
    int idx=blockIdx.x*blockDim.x+threadIdx.x;
    if(idx>=16384) return;
    int r=idx&31, oc=(idx>>5)&127, icb=idx>>12;
    float v = RAW? ldin(src,(long)oc*C_+icb*32+r,*flag) : ((const float*)src)[(long)oc*C_+icb*32+r];
    dst[idx]=__float2bfloat16(v);
}

// ---------- 3x3 weight [oc][256ic][3][3] -> tiled bf16 [tap][icb(8)][oc][32] ----------
__global__ void prep_w3t(bf16t* __restrict__ dst, const void* __restrict__ src, const int* __restrict__ flag, int OC){
    int idx=blockIdx.x*blockDim.x+threadIdx.x;
    int tot=OC*2304;
    if(idx>=tot) return;
    int r=idx&31; int rest=idx>>5; int oc=rest%OC; int g2=rest/OC; int icb=g2&7, tap=g2>>3;
    float v=ldin(src,((long)(oc*256+icb*32+r))*9+tap,*flag);
    dst[idx]=__float2bfloat16(v);
}

// ---------- gamma/beta [c][p] -> transposed f32 [p][c] ----------
__global__ void prep_gbt(float* __restrict__ gamT, float* __restrict__ betT,
                         const void* __restrict__ gam, const void* __restrict__ bet, const int* __restrict__ flag){
    int idx=blockIdx.x*blockDim.x+threadIdx.x;
    if(idx>=CP_) return;
    int c=idx/P_, p=idx-c*P_; int f=*flag;
    gamT[p*C_+c]=ldin(gam,idx,f);
    betT[p*C_+c]=ldin(bet,idx,f);
}

// ---------- w_gate [c][k] -> transposed f32 [k][c]; b_gate -> f32 ----------
__global__ void prep_wgt(float* __restrict__ wgT, float* __restrict__ bg2,
                         const void* __restrict__ wg, const void* __restrict__ bg, const int* __restrict__ flag){
    int idx=blockIdx.x*blockDim.x+threadIdx.x;
    int f=*flag;
    if(idx<16384){ int k=idx>>7, c=idx&127; wgT[idx]=ldin(wg,(long)c*C_+k,f); }
    if(idx<128) bg2[idx]=ldin(bg,idx,f);
}

// ---------- 128x128x128 GEMM tile, 8 waves (2 ocr x 4 pcr), B from GLOBAL (stride 128) ----------
__device__ __forceinline__ void gemm24g(f32x4 (&acc)[4][2],
    const bf16t* __restrict__ Wt, const bf16t* __restrict__ hsrc,
    int ocr,int pcr,int l15,int kg)
{
    #pragma unroll
    for(int i=0;i<4;i++){
        #pragma unroll
        for(int j=0;j<2;j++) acc[i][j]=(f32x4){0.f,0.f,0.f,0.f};
    }
    #pragma unroll
    for(int kc=0;kc<4;kc++){
        bf16x8 a[4],b[2];
        #pragma unroll
        for(int mt=0;mt<4;mt++) a[mt]=*(const bf16x8*)(Wt+((size_t)(kc*C_+ocr*64+mt*16+l15))*32+kg*8);
        #pragma unroll
        for(int nt=0;nt<2;nt++) b[nt]=*(const bf16x8*)(hsrc+(size_t)(pcr*32+nt*16+l15)*C_+kc*32+kg*8);
        #pragma unroll
        for(int mt=0;mt<4;mt++){
            #pragma unroll
            for(int nt=0;nt<2;nt++)
                acc[mt][nt]=__builtin_amdgcn_mfma_f32_16x16x32_bf16(a[mt],b[nt],acc[mt][nt],0,0,0);
        }
    }
}

// ---------- fused qkv + intra attention per (s,b), 512 threads, 2 LDS buffers ----------
// comb = w*(alpha * softmax(qk^T*scale) v + h)
__global__ __launch_bounds__(512) void qkv_attn(
    bf16t* __restrict__ comb, const bf16t* __restrict__ hT,
    const bf16t* __restrict__ WqT, const bf16t* __restrict__ WkT, const bf16t* __restrict__ WvT,
    const float* __restrict__ bq, const float* __restrict__ bk, const float* __restrict__ bv,
    const float* __restrict__ alphap, const float* __restrict__ wp)
{
    __shared__ bf16t LA[128*136];   // q, then v (natural)
    __shared__ bf16t LB[128*136];   // k, then P
    int sb=blockIdx.x, t=threadIdx.x, lane=t&63, w=t>>6;
    int l15=lane&15, kg=lane>>4;
    const bf16t* hp=hT+(size_t)sb*CP_;
    int ocr=w>>2, pcr=w&3;
    f32x4 acc[4][2];
    // q -> LA [p][c]
    gemm24g(acc,WqT,hp,ocr,pcr,l15,kg);
    #pragma unroll
    for(int mt=0;mt<4;mt++){
        int oc0=ocr*64+mt*16+kg*4;
        #pragma unroll
        for(int nt=0;nt<2;nt++){
            int p=pcr*32+nt*16+l15;
            us4 pk;
            #pragma unroll
            for(int r=0;r<4;r++) pk[r]=f2bu(acc[mt][nt][r]+bq[oc0+r]);
            *(us4*)(LA+p*136+oc0)=pk;
        }
    }
    // k -> LB [p][c]
    gemm24g(acc,WkT,hp,ocr,pcr,l15,kg);
    #pragma unroll
    for(int mt=0;mt<4;mt++){
        int oc0=ocr*64+mt*16+kg*4;
        #pragma unroll
        for(int nt=0;nt<2;nt++){
            int p=pcr*32+nt*16+l15;
            us4 pk;
            #pragma unroll
            for(int r=0;r<4;r++) pk[r]=f2bu(acc[mt][nt][r]+bk[oc0+r]);
            *(us4*)(LB+p*136+oc0)=pk;
        }
    }
    __syncthreads();
    // QK^T: wave owns rows m0..m0+15 (p = m0+kg*4+r), cols j = nt*16+l15
    int m0=w*16;
    f32x4 s[8];
    #pragma unroll
    for(int nt=0;nt<8;nt++) s[nt]=(f32x4){0.f,0.f,0.f,0.f};
    #pragma unroll
    for(int kc=0;kc<4;kc++){
        bf16x8 a=*(const bf16x8*)(LA+(size_t)(m0+l15)*136+kc*32+kg*8);
        #pragma unroll
        for(int nt=0;nt<8;nt++){
            bf16x8 b=*(const bf16x8*)(LB+(size_t)(nt*16+l15)*136+kc*32+kg*8);
            s[nt]=__builtin_amdgcn_mfma_f32_16x16x32_bf16(a,b,s[nt],0,0,0);
        }
    }
    const float scale=0.08838834764831845f;
    #pragma unroll
    for(int nt=0;nt<8;nt++){
        #pragma unroll
        for(int r=0;r<4;r++) s[nt][r]*=scale;
    }
    if(l15>=9){
        #pragma unroll
        for(int r=0;r<4;r++) s[7][r]=-3.0e38f;
    }
    #pragma unroll
    for(int r=0;r<4;r++){
        float mx=s[0][r];
        #pragma unroll
        for(int nt=1;nt<8;nt++) mx=fmaxf(mx,s[nt][r]);
        #pragma unroll
        for(int o=1;o<16;o<<=1) mx=fmaxf(mx,__shfl_xor(mx,o));
        float sm=0.f;
        #pragma unroll
        for(int nt=0;nt<8;nt++){ float e=__expf(s[nt][r]-mx); s[nt][r]=e; sm+=e; }
        #pragma unroll
        for(int o=1;o<16;o<<=1) sm+=__shfl_xor(sm,o);
        float rs=1.f/sm;
        #pragma unroll
        for(int nt=0;nt<8;nt++) s[nt][r]*=rs;
    }
    __syncthreads();   // everyone done reading q/k
    // v -> LA natural [c][p] (pad cols zeroed); P -> LB [p][j]
    gemm24g(acc,WvT,hp,ocr,pcr,l15,kg);
    #pragma unroll
    for(int mt=0;mt<4;mt++){
        int oc0=ocr*64+mt*16+kg*4;
        #pragma unroll
        for(int nt=0;nt<2;nt++){
            int p=pcr*32+nt*16+l15;
            #pragma unroll
            for(int r=0;r<4;r++)
                LA[(oc0+r)*136+p]=__float2bfloat16(p<P_? acc[mt][nt][r]+bv[oc0+r] : 0.f);
        }
    }
    #pragma unroll
    for(int r=0;r<4;r++){
        int pr=m0+kg*4+r;
        #pragma unroll
        for(int nt=0;nt<8;nt++) LB[pr*136+nt*16+l15]=__float2bfloat16(s[nt][r]);
    }
    __syncthreads();
    // PV: wave owns c rows m0..m0+15
    f32x4 o[8];
    #pragma unroll
    for(int nt=0;nt<8;nt++) o[nt]=(f32x4){0.f,0.f,0.f,0.f};
    #pragma unroll
    for(int jc=0;jc<4;jc++){
        bf16x8 a=*(const bf16x8*)(LA+(size_t)(m0+l15)*136+jc*32+kg*8);
        #pragma unroll
        for(int nt=0;nt<8;nt++){
            bf16x8 b=*(const bf16x8*)(LB+(size_t)(nt*16+l15)*136+jc*32+kg*8);
            o[nt]=__builtin_amdgcn_mfma_f32_16x16x32_bf16(a,b,o[nt],0,0,0);
        }
    }
    float al=*alphap, wv=*wp;
    int c0=m0+kg*4;
    bf16t* ob=comb+(size_t)sb*CP_;
    #pragma unroll
    for(int nt=0;nt<8;nt++){
        int p=nt*16+l15;
        if(p>=P_) continue;
        us4 hv=*(const us4*)(hp+(size_t)p*C_+c0);
        us4 pk;
        #pragma unroll
        for(int r=0;r<4;r++) pk[r]=f2bu(wv*(al*o[nt][r]+b2f(hv[r])));
        *(us4*)(ob+(size_t)p*C_+c0)=pk;
    }
}

// ---------- fused msg: yy=W2@h_shift; m=softmax(h yy^T) yy; gate; comb += (1-w)*m*g ----------
__global__ __launch_bounds__(512) void msg_all(
    bf16t* __restrict__ comb, const bf16t* __restrict__ hT,
    const bf16t* __restrict__ W2T, const float* __restrict__ b2e,
    const float* __restrict__ wgT, const float* __restrict__ bgf,
    const float* __restrict__ wp, int sb0, int shift)
{
    __shared__ bf16t LA[128*136];   // yyT [p][c], then P
    __shared__ bf16t LB[128*136];   // yyN [c][p]
    __shared__ float fl[256];
    int sb=sb0+blockIdx.x, t=threadIdx.x, lane=t&63, w=t>>6;
    int l15=lane&15, kg=lane>>4;
    const bf16t* hsp=hT+(size_t)(sb+shift)*CP_;
    int ocr=w>>2, pcr=w&3;
    f32x4 acc[4][2];
    gemm24g(acc,W2T,hsp,ocr,pcr,l15,kg);
    #pragma unroll
    for(int mt=0;mt<4;mt++){
        int oc0=ocr*64+mt*16+kg*4;
        #pragma unroll
        for(int nt=0;nt<2;nt++){
            int p=pcr*32+nt*16+l15;
            us4 pk;
            #pragma unroll
            for(int r=0;r<4;r++){
                float v=acc[mt][nt][r]+b2e[oc0+r];
                pk[r]=f2bu(v);
                LB[(oc0+r)*136+p]=__float2bfloat16(p<P_? v : 0.f);
            }
            *(us4*)(LA+p*136+oc0)=pk;
        }
    }
    __syncthreads();
    // logits: A = own h rows from global, B = yyT(LA); no scale
    int m0=w*16;
    const bf16t* ap=hT+(size_t)sb*CP_;
    f32x4 s[8];
    #pragma unroll
    for(int nt=0;nt<8;nt++) s[nt]=(f32x4){0.f,0.f,0.f,0.f};
    #pragma unroll
    for(int kc=0;kc<4;kc++){
        bf16x8 a=*(const bf16x8*)(ap+(size_t)(m0+l15)*C_+kc*32+kg*8);
        #pragma unroll
        for(int nt=0;nt<8;nt++){
            bf16x8 b=*(const bf16x8*)(LA+(size_t)(nt*16+l15)*136+kc*32+kg*8);
            s[nt]=__builtin_amdgcn_mfma_f32_16x16x32_bf16(a,b,s[nt],0,0,0);
        }
    }
    if(l15>=9){
        #pragma unroll
        for(int r=0;r<4;r++) s[7][r]=-3.0e38f;
    }
    #pragma unroll
    for(int r=0;r<4;r++){
        float mx=s[0][r];
        #pragma unroll
        for(int nt=1;nt<8;nt++) mx=fmaxf(mx,s[nt][r]);
        #pragma unroll
        for(int o=1;o<16;o<<=1) mx=fmaxf(mx,__shfl_xor(mx,o));
        float sm=0.f;
        #pragma unroll
        for(int nt=0;nt<8;nt++){ float e=__expf(s[nt][r]-mx); s[nt][r]=e; sm+=e; }
        #pragma unroll
        for(int o=1;o<16;o<<=1) sm+=__shfl_xor(sm,o);
        float rs=1.f/sm;
        #pragma unroll
        for(int nt=0;nt<8;nt++) s[nt][r]*=rs;
    }
    __syncthreads();   // everyone done reading yyT
    #pragma unroll
    for(int r=0;r<4;r++){
        int pr=m0+kg*4+r;
        #pragma unroll
        for(int nt=0;nt<8;nt++) LA[pr*136+nt*16+l15]=__float2bfloat16(s[nt][r]);
    }
    __syncthreads();
    // PV: m[c][p], A=yyN(LB), B=P(LA)
    f32x4 o[8];
    #pragma unroll
    for(int nt=0;nt<8;nt++) o[nt]=(f32x4){0.f,0.f,0.f,0.f};
    #pragma unroll
    for(int jc=0;jc<4;jc++){
        bf16x8 a=*(const bf16x8*)(LB+(size_t)(m0+l15)*136+jc*32+kg*8);
        #pragma unroll
        for(int nt=0;nt<8;nt++){
            bf16x8 b=*(const bf16x8*)(LA+(size_t)(nt*16+l15)*136+jc*32+kg*8);
            o[nt]=__builtin_amdgcn_mfma_f32_16x16x32_bf16(a,b,o[nt],0,0,0);
        }
    }
    // gate: mean over p, then matvec + sigmoid
    int c0=m0+kg*4;
    #pragma unroll
    for(int r=0;r<4;r++){
        float sm=0.f;
        #pragma unroll
        for(int nt=0;nt<8;nt++){ float v=o[nt][r]; if(nt==7&&l15>8) v=0.f; sm+=v; }
        sm+=__shfl_xor(sm,1); sm+=__shfl_xor(sm,2); sm+=__shfl_xor(sm,4); sm+=__shfl_xor(sm,8);
        if(l15==0) fl[c0+r]=sm*(1.f/121.f);
    }
    __syncthreads();
    if(t<C_){
        float a=bgf[t];
        #pragma unroll 8
        for(int k=0;k<C_;k++) a+=wgT[k*C_+t]*fl[k];
        fl[C_+t]=1.f/(1.f+__expf(-a));
    }
    __syncthreads();
    float w1m=1.f-*wp;
    float gg[4];
    #pragma unroll
    for(int r=0;r<4;r++) gg[r]=fl[C_+c0+r];
    bf16t* ob=comb+(size_t)sb*CP_;
    #pragma unroll
    for(int nt=0;nt<8;nt++){
        int p=nt*16+l15;
        if(p>=P_) continue;
        us4 bv=*(const us4*)(ob+(size_t)p*C_+c0);
        #pragma unroll
        for(int r=0;r<4;r++) bv[r]=f2bu(b2f(bv[r]) + w1m*o[nt][r]*gg[r]);
        *(us4*)(ob+(size_t)p*C_+c0)=bv;
    }
}

// ---------- 3x3 SAME conv via MFMA: 64-ch staging (4 stages x 18 steps), ring-4 A-prefetch ----------
// MODE 1 (zr): ocb==0 -> o0 = sigmoid (Z); ocb==128 -> o1 = sigmoid * hT (RH)
// MODE 2 (hhat+LN): nh staged to LDS, LayerNorm, write o0 = new hT
#define LOADA3(bidx, widx) { \
    _Pragma("unroll") \
    for(int mt=0;mt<4;mt++) abuf[bidx][mt]=*(const bf16x8*)(Wt+(size_t)(widx)*(OC*32)+mt*512+base_lane); }
#define STEP3(bidx, doff) { \
    bf16x8 bb[4]; \
    _Pragma("unroll") \
    for(int nt=0;nt<4;nt++) bb[nt]=*(const bf16x8*)(lin+boff[nt]+(doff)); \
    __builtin_amdgcn_s_setprio(1); \
    _Pragma("unroll") \
    for(int mt=0;mt<4;mt++){ \
        _Pragma("unroll") \
        for(int nt=0;nt<4;nt++) \
            acc[mt][nt]=__builtin_amdgcn_mfma_f32_16x16x32_bf16(abuf[bidx][mt],bb[nt],acc[mt][nt],0,0,0); } \
    __builtin_amdgcn_s_setprio(0); }

template<int MODE>
__global__ __launch_bounds__(256) void conv3_mfma(
    bf16t* __restrict__ o0, bf16t* __restrict__ o1,
    const bf16t* __restrict__ in0T, const bf16t* __restrict__ in1T,
    const bf16t* __restrict__ Wt, const float* __restrict__ bias,
    const bf16t* __restrict__ zT, const bf16t* __restrict__ hTb,
    const float* __restrict__ gamT, const float* __restrict__ betT)
{
    constexpr int OC=(MODE==1)?256:128;
    constexpr int LSZ=(MODE==2)?15488:12176;
    __shared__ bf16t lin[LSZ];
    __shared__ float red[8];
    int sb=blockIdx.x, ocb=(MODE==1)? (int)blockIdx.y*128 : 0;
    int t=threadIdx.x, lane=t&63, w=t>>6;
    int ocr=w>>1, pcr=w&1, l15=lane&15, kg=lane>>4;
    int boff[4]; bool pv_[4];
    #pragma unroll
    for(int nt=0;nt<4;nt++){
        int p=pcr*64+nt*16+l15;
        pv_[nt]=(p<P_); int pc=pv_[nt]?p:(P_-1);
        boff[nt]=((pc/11)*13+(pc%11))*72+kg*8;
    }
    f32x4 acc[4][4];
    #pragma unroll
    for(int i=0;i<4;i++){
        #pragma unroll
        for(int j=0;j<4;j++) acc[i][j]=(f32x4){0.f,0.f,0.f,0.f};
    }
    int base_lane=(ocb+ocr*64+l15)*32+kg*8;
    bf16x8 abuf[4][4];
    // prologue: first 4 steps' weights in flight   (widx(s)=tap*8+stage*2+l)
    LOADA3(0,0); LOADA3(1,1); LOADA3(2,8); LOADA3(3,9);
    // zero border pixels (48) for 64-ch stride-72 tile
    {
        bf16x8 z;
        #pragma unroll
        for(int e=0;e<8;e++) z[e]=0;
        for(int i=t;i<384;i+=256){
            int bi=i>>3, cc=(i&7)*8;
            int pix;
            if(bi<13) pix=bi;
            else if(bi<26) pix=156+(bi-13);
            else { int j2=bi-26; pix=(1+(j2>>1))*13+((j2&1)?12:0); }
            *(bf16x8*)(lin+pix*72+cc)=z;
        }
    }
    #pragma unroll
    for(int st=0; st<4; ++st){
        __syncthreads();
        {
            const bf16t* src=((st<2)? in0T:in1T)+(size_t)sb*CP_+(st&1)*64;
            for(int i=t;i<968;i+=256){
                int p=i>>3, cc=(i&7)*8;
                int pix=(p/11+1)*13+(p%11)+1;
                *(bf16x8*)(lin+pix*72+cc)=*(const bf16x8*)(src+(size_t)p*C_+cc);
            }
        }
        __syncthreads();
        #pragma unroll
        for(int k=0;k<18;k++){
            int s=st*18+k;
            int tap=k>>1, l=k&1;
            int doff=((tap/3)*13+(tap%3))*72+l*32;
            STEP3(s&3, doff);
            if(s<68){
                int s4=s+4, st4=s4/18, k4=s4-st4*18, tap4=k4>>1, l4=k4&1;
                LOADA3(s&3, tap4*8+st4*2+l4);
            }
        }
    }
    if(MODE==1){
        #pragma unroll
        for(int mt=0;mt<4;mt++){
            int ocl=ocr*64+mt*16+kg*4;
            #pragma unroll
            for(int nt=0;nt<4;nt++){
                if(!pv_[nt]) continue;
                int p=pcr*64+nt*16+l15;
                size_t tb=(size_t)sb*CP_+(size_t)p*C_+ocl;
                us4 pk;
                if(ocb==0){
                    #pragma unroll
                    for(int r=0;r<4;r++){ float a=acc[mt][nt][r]+bias[ocl+r]; pk[r]=f2bu(1.f/(1.f+__expf(-a))); }
                    *(us4*)(o0+tb)=pk;
                }else{
                    us4 hv=*(const us4*)(hTb+tb);
                    #pragma unroll
                    for(int r=0;r<4;r++){ float a=acc[mt][nt][r]+bias[128+ocl+r]; float sg=1.f/(1.f+__expf(-a)); pk[r]=f2bu(sg*b2f(hv[r])); }
                    *(us4*)(o1+tb)=pk;
                }
            }
        }
    }else{
        __syncthreads();   // reuse lin for NH
        float ls=0.f, ls2=0.f;
        #pragma unroll
        for(int mt=0;mt<4;mt++){
            int ocl=ocr*64+mt*16+kg*4;
            #pragma unroll
            for(int nt=0;nt<4;nt++){
                if(!pv_[nt]) continue;
                int p=pcr*64+nt*16+l15;
                size_t tb=(size_t)sb*CP_+(size_t)p*C_+ocl;
                us4 hv=*(const us4*)(hTb+tb);
                us4 zv=*(const us4*)(zT+tb);
                us4 pk;
                #pragma unroll
                for(int r=0;r<4;r++){
                    float a=acc[mt][nt][r]+bias[ocl+r];
                    float ht=tanhf(a);
                    float z=b2f(zv[r]), h=b2f(hv[r]);
                    unsigned short u=f2bu((1.f-z)*h+z*ht+h);
                    pk[r]=u;
                    float nr=b2f(u); ls+=nr; ls2+=nr*nr;
                }
                *(us4*)((unsigned short*)lin + p*C_+ocl)=pk;
            }
        }
        #pragma unroll
        for(int o=32;o;o>>=1){ ls+=__shfl_xor(ls,o); ls2+=__shfl_xor(ls2,o); }
        if(lane==0){ red[w]=ls; red[4+w]=ls2; }
        __syncthreads();
        float Sx=red[0]+red[1]+red[2]+red[3];
        float Sx2=red[4]+red[5]+red[6]+red[7];
        float mu=Sx*(1.f/(float)CP_);
        float var=Sx2*(1.f/(float)CP_)-mu*mu;
        float rstd=rsqrtf(var+1e-5f);
        bf16t* ho=o0+(size_t)sb*CP_;
        for(int i=t;i<CP_;i+=256){
            float v=(ldb(lin+i)-mu)*rstd*gamT[i]+betT[i];
            ho[i]=__float2bfloat16(v);
        }
    }
}

// ---------- final: hT [p][c] -> natural [c][p] output ----------
__global__ __launch_bounds__(256) void finalT_kernel(void* __restrict__ fout, const bf16t* __restrict__ hT, const int* __restrict__ flag){
    __shared__ bf16t tl[CP_];
    int sb=blockIdx.x, t=threadIdx.x, f=*flag;
    for(int i=t;i<CP_;i+=256) tl[i]=hT[(size_t)sb*CP_+i];
    __syncthreads();
    for(int i=t;i<CP_;i+=256){
        int c=i/P_, p=i-c*P_;
        float v=ldb(tl+p*C_+c);
        size_t oi=(size_t)sb*CP_+i;
        if(f) ((float*)fout)[oi]=v;
        else  ((bf16t*)fout)[oi]=__float2bfloat16(v);
    }
}

extern "C" void kernel_launch(void* const* d_in, const int* in_sizes, int n_in,
                              void* d_out, int out_size, void* d_ws, size_t ws_size,
                              hipStream_t stream) {
    (void)in_sizes; (void)n_in; (void)out_size;
    char* base=(char*)d_ws;
    size_t off=0;
    auto alloc=[&](size_t bytes){ void* p=base+off; off+=(bytes+255)&~(size_t)255; return p; };
    bf16t* b1=(bf16t*)alloc((size_t)NEl*2+8192);          // hT
    bf16t* b2=(bf16t*)alloc((size_t)NEl*2+8192);          // comb
    bf16t* b3=(bf16t*)alloc((size_t)NEl*2+8192);          // RH
    bf16t* b4=(bf16t*)d_out;                              // Z / final
    bf16t* wqT=(bf16t*)alloc(16384*2);
    bf16t* wkT=(bf16t*)alloc(16384*2);
    bf16t* wvT=(bf16t*)alloc(16384*2);
    bf16t* w2T=(bf16t*)alloc(16384*2);
    bf16t* wzrT=(bf16t*)alloc((size_t)589824*2);
    bf16t* whT =(bf16t*)alloc((size_t)294912*2);
    float* W2f=(float*)alloc(16384*4);
    float* b2l=(float*)alloc(128*4); float* b2r=(float*)alloc(128*4);
    float* bqf=(float*)alloc(128*4); float* bkf=(float*)alloc(128*4); float* bvf=(float*)alloc(128*4);
    float* bzrf=(float*)alloc(256*4); float* bhf=(float*)alloc(128*4);
    float* gamT=(float*)alloc(15488*4); float* betT=(float*)alloc(15488*4);
    float* wgTf=(float*)alloc(16384*4); float* bgf2=(float*)alloc(128*4);
    float* alphaf=(float*)alloc(4); float* weightf=(float*)alloc(4);
    int* flag=(int*)alloc(4);
    if(ws_size<off) return;  // ~100MB needed

    detect_kernel<<<1,64,0,stream>>>((const unsigned short*)d_in[0],flag);
    cvtT_kernel<<<SBn,256,0,stream>>>(b1,d_in[0],flag);
    prep_w1t<1><<<64,256,0,stream>>>(wqT,d_in[1],flag);
    cvt_kernel<<<1,128,0,stream>>>(bqf,d_in[2],128,flag);
    prep_w1t<1><<<64,256,0,stream>>>(wkT,d_in[3],flag);
    cvt_kernel<<<1,128,0,stream>>>(bkf,d_in[4],128,flag);
    prep_w1t<1><<<64,256,0,stream>>>(wvT,d_in[5],flag);
    cvt_kernel<<<1,128,0,stream>>>(bvf,d_in[6],128,flag);
    cvt_kernel<<<1,64,0,stream>>>(alphaf,d_in[7],1,flag);
    prep_msg_kernel<<<C_,C_,0,stream>>>(W2f,b2l,b2r,d_in[10],d_in[8],d_in[9],flag);
    prep_w1t<0><<<64,256,0,stream>>>(w2T,W2f,flag);
    cvt_kernel<<<1,64,0,stream>>>(weightf,d_in[11],1,flag);
    prep_wgt<<<64,256,0,stream>>>(wgTf,bgf2,d_in[12],d_in[13],flag);
    prep_w3t<<<(256*2304+255)/256,256,0,stream>>>(wzrT,d_in[14],flag,256);
    cvt_kernel<<<1,256,0,stream>>>(bzrf,d_in[15],256,flag);
    prep_w3t<<<(128*2304+255)/256,256,0,stream>>>(whT,d_in[16],flag,128);
    cvt_kernel<<<1,128,0,stream>>>(bhf,d_in[17],128,flag);
    prep_gbt<<<(CP_+255)/256,256,0,stream>>>(gamT,betT,d_in[18],d_in[19],flag);

    for(int it=0; it<3; ++it){
        // intra: comb(b2) = w*(alpha*attn(h) + h)
        qkv_attn<<<SBn,512,0,stream>>>(b2,b1,wqT,wkT,wvT,bqf,bkf,bvf,alphaf,weightf);
        // left message (sb in [64,1024)): comb += (1-w)*m*g
        msg_all<<<SBn-B_,512,0,stream>>>(b2,b1,w2T,b2l,wgTf,bgf2,weightf,B_,-B_);
        // right message (sb in [0,960))
        msg_all<<<SBn-B_,512,0,stream>>>(b2,b1,w2T,b2r,wgTf,bgf2,weightf,0,B_);
        // GRU: zr([comb|h]) -> Z->b4, RH->b3 ; hhat([comb|RH]) + LN -> new hT (b1)
        conv3_mfma<1><<<dim3(SBn,2),256,0,stream>>>(b4,b3,b2,b1,wzrT,bzrf,nullptr,b1,nullptr,nullptr);
        conv3_mfma<2><<<dim3(SBn,1),256,0,stream>>>(b1,nullptr,b2,b3,whT,bhf,b4,b1,gamT,betT);
    }
    finalT_kernel<<<SBn,256,0,stream>>>(d_out,b1,flag);
}

// Round 9
// 1449.828 us; speedup vs baseline: 14.9986x; 1.0494x over previous
//
#include <hip/hip_runtime.h>
#include <hip/hip_bf16.h>

// GraphProcessor: S=16,B=64,C=128,H=W=11,P=121, 3 iterations.
// Transposed [sb][p][128ch] bf16 storage; MFMA everywhere; deep fusion.
// conv3: double-buffered LDS + reg-staged B (T14 async-STAGE split).
#define S_   16
#define B_   64
#define SBn  1024
#define C_   128
#define P_   121
#define CP_  15488
static const long NEl = 15859712L; // SBn*CP_

typedef __hip_bfloat16 bf16t;
typedef __attribute__((ext_vector_type(8))) short bf16x8;
typedef __attribute__((ext_vector_type(4))) float f32x4;
typedef __attribute__((ext_vector_type(4))) unsigned short us4;

__device__ __forceinline__ float ldb(const bf16t* p){ return __bfloat162float(*p); }
__device__ __forceinline__ float b2f(unsigned short u){ unsigned x=((unsigned)u)<<16; float f; __builtin_memcpy(&f,&x,4); return f; }
__device__ __forceinline__ unsigned short f2bu(float v){ __hip_bfloat16 b=__float2bfloat16(v); unsigned short u; __builtin_memcpy(&u,&b,2); return u; }
__device__ __forceinline__ float ldin(const void* s, long i, int f){
    return f ? ((const float*)s)[i] : b2f(((const unsigned short*)s)[i]);
}

// ---------- dtype detect: flag=1 if inputs are f32, 0 if bf16 ----------
__global__ void detect_kernel(const unsigned short* __restrict__ x, int* __restrict__ flag){
    if(blockIdx.x==0 && threadIdx.x==0){
        int crazy=0;
        for(int i=0;i<512;i++){
            unsigned e=(x[i]>>7)&0xFF;
            if(e!=0 && (e<64 || e>191)) crazy++;
        }
        *flag=(crazy>40)?1:0;
    }
}

// ---------- raw input -> f32 ----------
__global__ void cvt_kernel(float* __restrict__ dst, const void* __restrict__ src, long n, const int* __restrict__ flag){
    long i=(long)blockIdx.x*blockDim.x+threadIdx.x;
    long st=(long)gridDim.x*blockDim.x;
    int f=*flag;
    for(;i<n;i+=st) dst[i]=ldin(src,i,f);
}

// ---------- x [sb][c][p] -> hT [sb][p][c] bf16 ----------
__global__ __launch_bounds__(256) void cvtT_kernel(bf16t* __restrict__ hT, const void* __restrict__ x, const int* __restrict__ flag){
    int sb=blockIdx.x, t=threadIdx.x; int f=*flag;
    for(int i=t;i<CP_;i+=256){
        int c=i/P_, p=i-c*P_;
        float v=ldin(x,(long)sb*CP_+i,f);
        hT[(size_t)sb*CP_+(size_t)p*C_+c]=__float2bfloat16(v);
    }
}

// ---------- fold w_lin @ w_msg[:, :C] into W2 (f32), edge bias into b2l/b2r ----------
__global__ __launch_bounds__(128) void prep_msg_kernel(float* __restrict__ W2, float* __restrict__ b2l, float* __restrict__ b2r,
        const void* __restrict__ wlin, const void* __restrict__ wmsg, const void* __restrict__ bmsg, const int* __restrict__ flag){
    int d=blockIdx.x, c=threadIdx.x; int f=*flag;
    float acc=0.f;
    for(int o2=0;o2<C_;o2++) acc += ldin(wlin,(long)d*C_+o2,f)*ldin(wmsg,(long)o2*(C_+1)+c,f);
    W2[d*C_+c]=acc;
    if(c<2){
        float e=(c==0)?1.f:-1.f; float a=0.f;
        for(int o2=0;o2<C_;o2++) a += ldin(wlin,(long)d*C_+o2,f)*(ldin(bmsg,o2,f)+e*ldin(wmsg,(long)o2*(C_+1)+C_,f));
        if(c==0) b2l[d]=a; else b2r[d]=a;
    }
}

// ---------- 1x1 weight [oc][128ic] -> tiled bf16 [icb(4)][oc(128)][32] ----------
template<int RAW>
__global__ void prep_w1t(bf16t* __restrict__ dst, const void* __restrict__ src, const int* __restrict__ flag){
    int idx=blockIdx.x*blockDim.x+threadIdx.x;
    if(idx>=16384) return;
    int r=idx&31, oc=(idx>>5)&127, icb=idx>>12;
    float v = RAW? ldin(src,(long)oc*C_+icb*32+r,*flag) : ((const float*)src)[(long)oc*C_+icb*32+r];
    dst[idx]=__float2bfloat16(v);
}

// ---------- 3x3 weight [oc][256ic][3][3] -> tiled bf16 [tap][icb(8)][oc][32] ----------
__global__ void prep_w3t(bf16t* __restrict__ dst, const void* __restrict__ src, const int* __restrict__ flag, int OC){
    int idx=blockIdx.x*blockDim.x+threadIdx.x;
    int tot=OC*2304;
    if(idx>=tot) return;
    int r=idx&31; int rest=idx>>5; int oc=rest%OC; int g2=rest/OC; int icb=g2&7, tap=g2>>3;
    float v=ldin(src,((long)(oc*256+icb*32+r))*9+tap,*flag);
    dst[idx]=__float2bfloat16(v);
}

// ---------- gamma/beta [c][p] -> transposed f32 [p][c] ----------
__global__ void prep_gbt(float* __restrict__ gamT, float* __restrict__ betT,
                         const void* __restrict__ gam, const void* __restrict__ bet, const int* __restrict__ flag){
    int idx=blockIdx.x*blockDim.x+threadIdx.x;
    if(idx>=CP_) return;
    int c=idx/P_, p=idx-c*P_; int f=*flag;
    gamT[p*C_+c]=ldin(gam,idx,f);
    betT[p*C_+c]=ldin(bet,idx,f);
}

// ---------- w_gate [c][k] -> transposed f32 [k][c]; b_gate -> f32 ----------
__global__ void prep_wgt(float* __restrict__ wgT, float* __restrict__ bg2,
                         const void* __restrict__ wg, const void* __restrict__ bg, const int* __restrict__ flag){
    int idx=blockIdx.x*blockDim.x+threadIdx.x;
    int f=*flag;
    if(idx<16384){ int k=idx>>7, c=idx&127; wgT[idx]=ldin(wg,(long)c*C_+k,f); }
    if(idx<128) bg2[idx]=ldin(bg,idx,f);
}

// ---------- 128x128x128 GEMM tile, 8 waves (2 ocr x 4 pcr), B from registers ----------
__device__ __forceinline__ void gemm24r(f32x4 (&acc)[4][2],
    const bf16t* __restrict__ Wt, const bf16x8 (&hreg)[4][2],
    int ocr,int l15,int kg)
{
    #pragma unroll
    for(int i=0;i<4;i++){
        #pragma unroll
        for(int j=0;j<2;j++) acc[i][j]=(f32x4){0.f,0.f,0.f,0.f};
    }
    #pragma unroll
    for(int kc=0;kc<4;kc++){
        bf16x8 a[4];
        #pragma unroll
        for(int mt=0;mt<4;mt++) a[mt]=*(const bf16x8*)(Wt+((size_t)(kc*C_+ocr*64+mt*16+l15))*32+kg*8);
        #pragma unroll
        for(int mt=0;mt<4;mt++){
            #pragma unroll
            for(int nt=0;nt<2;nt++)
                acc[mt][nt]=__builtin_amdgcn_mfma_f32_16x16x32_bf16(a[mt],hreg[kc][nt],acc[mt][nt],0,0,0);
        }
    }
}

// ---------- fused qkv + intra attention per (s,b), 512 threads, 2 LDS buffers ----------
// comb = w*(alpha * softmax(qk^T*scale) v + h)
__global__ __launch_bounds__(512) void qkv_attn(
    bf16t* __restrict__ comb, const bf16t* __restrict__ hT,
    const bf16t* __restrict__ WqT, const bf16t* __restrict__ WkT, const bf16t* __restrict__ WvT,
    const float* __restrict__ bq, const float* __restrict__ bk, const float* __restrict__ bv,
    const float* __restrict__ alphap, const float* __restrict__ wp)
{
    __shared__ bf16t LA[128*136];   // q, then v (natural)
    __shared__ bf16t LB[128*136];   // k, then P
    int sb=blockIdx.x, t=threadIdx.x, lane=t&63, w=t>>6;
    int l15=lane&15, kg=lane>>4;
    const bf16t* hp=hT+(size_t)sb*CP_;
    int ocr=w>>2, pcr=w&3;
    // hoist h B-fragments once, reuse for q/k/v GEMMs
    bf16x8 hreg[4][2];
    #pragma unroll
    for(int kc=0;kc<4;kc++){
        #pragma unroll
        for(int nt=0;nt<2;nt++)
            hreg[kc][nt]=*(const bf16x8*)(hp+(size_t)(pcr*32+nt*16+l15)*C_+kc*32+kg*8);
    }
    f32x4 acc[4][2];
    // q -> LA [p][c]
    gemm24r(acc,WqT,hreg,ocr,l15,kg);
    #pragma unroll
    for(int mt=0;mt<4;mt++){
        int oc0=ocr*64+mt*16+kg*4;
        #pragma unroll
        for(int nt=0;nt<2;nt++){
            int p=pcr*32+nt*16+l15;
            us4 pk;
            #pragma unroll
            for(int r=0;r<4;r++) pk[r]=f2bu(acc[mt][nt][r]+bq[oc0+r]);
            *(us4*)(LA+p*136+oc0)=pk;
        }
    }
    // k -> LB [p][c]
    gemm24r(acc,WkT,hreg,ocr,l15,kg);
    #pragma unroll
    for(int mt=0;mt<4;mt++){
        int oc0=ocr*64+mt*16+kg*4;
        #pragma unroll
        for(int nt=0;nt<2;nt++){
            int p=pcr*32+nt*16+l15;
            us4 pk;
            #pragma unroll
            for(int r=0;r<4;r++) pk[r]=f2bu(acc[mt][nt][r]+bk[oc0+r]);
            *(us4*)(LB+p*136+oc0)=pk;
        }
    }
    __syncthreads();
    // QK^T: wave owns rows m0..m0+15 (p = m0+kg*4+r), cols j = nt*16+l15
    int m0=w*16;
    f32x4 s[8];
    #pragma unroll
    for(int nt=0;nt<8;nt++) s[nt]=(f32x4){0.f,0.f,0.f,0.f};
    #pragma unroll
    for(int kc=0;kc<4;kc++){
        bf16x8 a=*(const bf16x8*)(LA+(size_t)(m0+l15)*136+kc*32+kg*8);
        #pragma unroll
        for(int nt=0;nt<8;nt++){
            bf16x8 b=*(const bf16x8*)(LB+(size_t)(nt*16+l15)*136+kc*32+kg*8);
            s[nt]=__builtin_amdgcn_mfma_f32_16x16x32_bf16(a,b,s[nt],0,0,0);
        }
    }
    const float scale=0.08838834764831845f;
    #pragma unroll
    for(int nt=0;nt<8;nt++){
        #pragma unroll
        for(int r=0;r<4;r++) s[nt][r]*=scale;
    }
    if(l15>=9){
        #pragma unroll
        for(int r=0;r<4;r++) s[7][r]=-3.0e38f;
    }
    #pragma unroll
    for(int r=0;r<4;r++){
        float mx=s[0][r];
        #pragma unroll
        for(int nt=1;nt<8;nt++) mx=fmaxf(mx,s[nt][r]);
        #pragma unroll
        for(int o=1;o<16;o<<=1) mx=fmaxf(mx,__shfl_xor(mx,o));
        float sm=0.f;
        #pragma unroll
        for(int nt=0;nt<8;nt++){ float e=__expf(s[nt][r]-mx); s[nt][r]=e; sm+=e; }
        #pragma unroll
        for(int o=1;o<16;o<<=1) sm+=__shfl_xor(sm,o);
        float rs=1.f/sm;
        #pragma unroll
        for(int nt=0;nt<8;nt++) s[nt][r]*=rs;
    }
    __syncthreads();   // everyone done reading q/k
    // v -> LA natural [c][p] (pad cols zeroed); P -> LB [p][j]
    gemm24r(acc,WvT,hreg,ocr,l15,kg);
    #pragma unroll
    for(int mt=0;mt<4;mt++){
        int oc0=ocr*64+mt*16+kg*4;
        #pragma unroll
        for(int nt=0;nt<2;nt++){
            int p=pcr*32+nt*16+l15;
            #pragma unroll
            for(int r=0;r<4;r++)
                LA[(oc0+r)*136+p]=__float2bfloat16(p<P_? acc[mt][nt][r]+bv[oc0+r] : 0.f);
        }
    }
    #pragma unroll
    for(int r=0;r<4;r++){
        int pr=m0+kg*4+r;
        #pragma unroll
        for(int nt=0;nt<8;nt++) LB[pr*136+nt*16+l15]=__float2bfloat16(s[nt][r]);
    }
    __syncthreads();
    // PV: wave owns c rows m0..m0+15
    f32x4 o[8];
    #pragma unroll
    for(int nt=0;nt<8;nt++) o[nt]=(f32x4){0.f,0.f,0.f,0.f};
    #pragma unroll
    for(int jc=0;jc<4;jc++){
        bf16x8 a=*(const bf16x8*)(LA+(size_t)(m0+l15)*136+jc*32+kg*8);
        #pragma unroll
        for(int nt=0;nt<8;nt++){
            bf16x8 b=*(const bf16x8*)(LB+(size_t)(nt*16+l15)*136+jc*32+kg*8);
            o[nt]=__builtin_amdgcn_mfma_f32_16x16x32_bf16(a,b,o[nt],0,0,0);
        }
    }
    float al=*alphap, wv=*wp;
    int c0=m0+kg*4;
    bf16t* ob=comb+(size_t)sb*CP_;
    #pragma unroll
    for(int nt=0;nt<8;nt++){
        int p=nt*16+l15;
        if(p>=P_) continue;
        us4 hv=*(const us4*)(hp+(size_t)p*C_+c0);
        us4 pk;
        #pragma unroll
        for(int r=0;r<4;r++) pk[r]=f2bu(wv*(al*o[nt][r]+b2f(hv[r])));
        *(us4*)(ob+(size_t)p*C_+c0)=pk;
    }
}

// ---------- fused msg: yy=W2@h_shift; m=softmax(h yy^T) yy; gate; comb += (1-w)*m*g ----------
__global__ __launch_bounds__(512) void msg_all(
    bf16t* __restrict__ comb, const bf16t* __restrict__ hT,
    const bf16t* __restrict__ W2T, const float* __restrict__ b2e,
    const float* __restrict__ wgT, const float* __restrict__ bgf,
    const float* __restrict__ wp, int sb0, int shift)
{
    __shared__ bf16t LA[128*136];   // yyT [p][c], then P
    __shared__ bf16t LB[128*136];   // yyN [c][p]
    __shared__ float fl[256];
    int sb=sb0+blockIdx.x, t=threadIdx.x, lane=t&63, w=t>>6;
    int l15=lane&15, kg=lane>>4;
    const bf16t* hsp=hT+(size_t)(sb+shift)*CP_;
    int ocr=w>>2, pcr=w&3;
    bf16x8 hreg[4][2];
    #pragma unroll
    for(int kc=0;kc<4;kc++){
        #pragma unroll
        for(int nt=0;nt<2;nt++)
            hreg[kc][nt]=*(const bf16x8*)(hsp+(size_t)(pcr*32+nt*16+l15)*C_+kc*32+kg*8);
    }
    f32x4 acc[4][2];
    gemm24r(acc,W2T,hreg,ocr,l15,kg);
    #pragma unroll
    for(int mt=0;mt<4;mt++){
        int oc0=ocr*64+mt*16+kg*4;
        #pragma unroll
        for(int nt=0;nt<2;nt++){
            int p=pcr*32+nt*16+l15;
            us4 pk;
            #pragma unroll
            for(int r=0;r<4;r++){
                float v=acc[mt][nt][r]+b2e[oc0+r];
                pk[r]=f2bu(v);
                LB[(oc0+r)*136+p]=__float2bfloat16(p<P_? v : 0.f);
            }
            *(us4*)(LA+p*136+oc0)=pk;
        }
    }
    __syncthreads();
    // logits: A = own h rows from global, B = yyT(LA); no scale
    int m0=w*16;
    const bf16t* ap=hT+(size_t)sb*CP_;
    f32x4 s[8];
    #pragma unroll
    for(int nt=0;nt<8;nt++) s[nt]=(f32x4){0.f,0.f,0.f,0.f};
    #pragma unroll
    for(int kc=0;kc<4;kc++){
        bf16x8 a=*(const bf16x8*)(ap+(size_t)(m0+l15)*C_+kc*32+kg*8);
        #pragma unroll
        for(int nt=0;nt<8;nt++){
            bf16x8 b=*(const bf16x8*)(LA+(size_t)(nt*16+l15)*136+kc*32+kg*8);
            s[nt]=__builtin_amdgcn_mfma_f32_16x16x32_bf16(a,b,s[nt],0,0,0);
        }
    }
    if(l15>=9){
        #pragma unroll
        for(int r=0;r<4;r++) s[7][r]=-3.0e38f;
    }
    #pragma unroll
    for(int r=0;r<4;r++){
        float mx=s[0][r];
        #pragma unroll
        for(int nt=1;nt<8;nt++) mx=fmaxf(mx,s[nt][r]);
        #pragma unroll
        for(int o=1;o<16;o<<=1) mx=fmaxf(mx,__shfl_xor(mx,o));
        float sm=0.f;
        #pragma unroll
        for(int nt=0;nt<8;nt++){ float e=__expf(s[nt][r]-mx); s[nt][r]=e; sm+=e; }
        #pragma unroll
        for(int o=1;o<16;o<<=1) sm+=__shfl_xor(sm,o);
        float rs=1.f/sm;
        #pragma unroll
        for(int nt=0;nt<8;nt++) s[nt][r]*=rs;
    }
    __syncthreads();   // everyone done reading yyT
    #pragma unroll
    for(int r=0;r<4;r++){
        int pr=m0+kg*4+r;
        #pragma unroll
        for(int nt=0;nt<8;nt++) LA[pr*136+nt*16+l15]=__float2bfloat16(s[nt][r]);
    }
    __syncthreads();
    // PV: m[c][p], A=yyN(LB), B=P(LA)
    f32x4 o[8];
    #pragma unroll
    for(int nt=0;nt<8;nt++) o[nt]=(f32x4){0.f,0.f,0.f,0.f};
    #pragma unroll
    for(int jc=0;jc<4;jc++){
        bf16x8 a=*(const bf16x8*)(LB+(size_t)(m0+l15)*136+jc*32+kg*8);
        #pragma unroll
        for(int nt=0;nt<8;nt++){
            bf16x8 b=*(const bf16x8*)(LA+(size_t)(nt*16+l15)*136+jc*32+kg*8);
            o[nt]=__builtin_amdgcn_mfma_f32_16x16x32_bf16(a,b,o[nt],0,0,0);
        }
    }
    // gate: mean over p, then matvec + sigmoid
    int c0=m0+kg*4;
    #pragma unroll
    for(int r=0;r<4;r++){
        float sm=0.f;
        #pragma unroll
        for(int nt=0;nt<8;nt++){ float v=o[nt][r]; if(nt==7&&l15>8) v=0.f; sm+=v; }
        sm+=__shfl_xor(sm,1); sm+=__shfl_xor(sm,2); sm+=__shfl_xor(sm,4); sm+=__shfl_xor(sm,8);
        if(l15==0) fl[c0+r]=sm*(1.f/121.f);
    }
    __syncthreads();
    if(t<C_){
        float a=bgf[t];
        #pragma unroll 8
        for(int k=0;k<C_;k++) a+=wgT[k*C_+t]*fl[k];
        fl[C_+t]=1.f/(1.f+__expf(-a));
    }
    __syncthreads();
    float w1m=1.f-*wp;
    float gg[4];
    #pragma unroll
    for(int r=0;r<4;r++) gg[r]=fl[C_+c0+r];
    bf16t* ob=comb+(size_t)sb*CP_;
    #pragma unroll
    for(int nt=0;nt<8;nt++){
        int p=nt*16+l15;
        if(p>=P_) continue;
        us4 bv=*(const us4*)(ob+(size_t)p*C_+c0);
        #pragma unroll
        for(int r=0;r<4;r++) bv[r]=f2bu(b2f(bv[r]) + w1m*o[nt][r]*gg[r]);
        *(us4*)(ob+(size_t)p*C_+c0)=bv;
    }
}

// ---------- 3x3 SAME conv via MFMA: dbuf LDS + reg-staged B + ring-4 A-prefetch ----------
// MODE 1 (zr): ocb==0 -> o0 = sigmoid (Z); ocb==128 -> o1 = sigmoid * hT (RH)
// MODE 2 (hhat+LN): nh staged to LDS, LayerNorm, write o0 = new hT
#define LOADA3(bidx, widx) { \
    _Pragma("unroll") \
    for(int mt=0;mt<4;mt++) abuf[bidx][mt]=*(const bf16x8*)(Wt+(size_t)(widx)*(OC*32)+mt*512+base_lane); }
#define STEP3(lbase, bidx, doff) { \
    bf16x8 bb[4]; \
    _Pragma("unroll") \
    for(int nt=0;nt<4;nt++) bb[nt]=*(const bf16x8*)((lbase)+boff[nt]+(doff)); \
    __builtin_amdgcn_s_setprio(1); \
    _Pragma("unroll") \
    for(int mt=0;mt<4;mt++){ \
        _Pragma("unroll") \
        for(int nt=0;nt<4;nt++) \
            acc[mt][nt]=__builtin_amdgcn_mfma_f32_16x16x32_bf16(abuf[bidx][mt],bb[nt],acc[mt][nt],0,0,0); } \
    __builtin_amdgcn_s_setprio(0); }
#define SLOAD3(stg) { \
    const bf16t* ssrc=(((stg)<2)? in0T:in1T)+(size_t)sb*CP_+((stg)&1)*64; \
    sreg[0]=*(const bf16x8*)(ssrc+(size_t)(t>>3)*C_+(t&7)*8); \
    sreg[1]=*(const bf16x8*)(ssrc+(size_t)((t+256)>>3)*C_+(t&7)*8); \
    if(sv2) sreg[2]=*(const bf16x8*)(ssrc+(size_t)((t+512)>>3)*C_+(t&7)*8); \
    if(sv3) sreg[3]=*(const bf16x8*)(ssrc+(size_t)((t+768)>>3)*C_+(t&7)*8); }
#define SWRITE3(lbase) { \
    *(bf16x8*)((lbase)+spix0*72+(t&7)*8)=sreg[0]; \
    *(bf16x8*)((lbase)+spix1*72+(t&7)*8)=sreg[1]; \
    if(sv2) *(bf16x8*)((lbase)+spix2*72+(t&7)*8)=sreg[2]; \
    if(sv3) *(bf16x8*)((lbase)+spix3*72+(t&7)*8)=sreg[3]; }

template<int MODE>
__global__ __launch_bounds__(256) void conv3_mfma(
    bf16t* __restrict__ o0, bf16t* __restrict__ o1,
    const bf16t* __restrict__ in0T, const bf16t* __restrict__ in1T,
    const bf16t* __restrict__ Wt, const float* __restrict__ bias,
    const bf16t* __restrict__ zT, const bf16t* __restrict__ hTb,
    const float* __restrict__ gamT, const float* __restrict__ betT)
{
    constexpr int OC=(MODE==1)?256:128;
    __shared__ bf16t lin[2*12176];
    __shared__ float red[8];
    int sb=blockIdx.x, ocb=(MODE==1)? (int)blockIdx.y*128 : 0;
    int t=threadIdx.x, lane=t&63, w=t>>6;
    int ocr=w>>1, pcr=w&1, l15=lane&15, kg=lane>>4;
    int boff[4]; bool pv_[4];
    #pragma unroll
    for(int nt=0;nt<4;nt++){
        int p=pcr*64+nt*16+l15;
        pv_[nt]=(p<P_); int pc=pv_[nt]?p:(P_-1);
        boff[nt]=((pc/11)*13+(pc%11))*72+kg*8;
    }
    f32x4 acc[4][4];
    #pragma unroll
    for(int i=0;i<4;i++){
        #pragma unroll
        for(int j=0;j<4;j++) acc[i][j]=(f32x4){0.f,0.f,0.f,0.f};
    }
    int base_lane=(ocb+ocr*64+l15)*32+kg*8;
    bf16x8 abuf[4][4];
    bf16x8 sreg[4];
    // staging geometry (static per thread): 968 chunks of 8 bf16 per stage
    bool sv2=((t+512)<968), sv3=((t+768)<968);
    int sp0=t>>3, sp1=(t+256)>>3, sp2=(t+512)>>3, sp3=(t+768)>>3;
    if(sp2>120) sp2=120;
    if(sp3>120) sp3=120;
    int spix0=(sp0/11+1)*13+(sp0%11)+1;
    int spix1=(sp1/11+1)*13+(sp1%11)+1;
    int spix2=(sp2/11+1)*13+(sp2%11)+1;
    int spix3=(sp3/11+1)*13+(sp3%11)+1;
    // prologue: A-ring first 4 steps, B stage 0
    LOADA3(0,0); LOADA3(1,1); LOADA3(2,8); LOADA3(3,9);
    SLOAD3(0);
    // zero border pixels (48) in BOTH buffers
    {
        bf16x8 z;
        #pragma unroll
        for(int e=0;e<8;e++) z[e]=0;
        for(int i=t;i<768;i+=256){
            int half=i>=384; int i2=i-half*384;
            int bi=i2>>3, cc=(i2&7)*8;
            int pix;
            if(bi<13) pix=bi;
            else if(bi<26) pix=156+(bi-13);
            else { int j2=bi-26; pix=(1+(j2>>1))*13+((j2&1)?12:0); }
            *(bf16x8*)(lin+half*12176+pix*72+cc)=z;
        }
    }
    SWRITE3(lin);          // stage 0 -> buf0 (compiler inserts vmcnt wait)
    __syncthreads();
    #pragma unroll
    for(int st=0; st<4; ++st){
        if(st<3) SLOAD3(st+1);          // issue next stage's loads before compute
        bf16t* lbase=lin+(st&1)*12176;
        #pragma unroll
        for(int k=0;k<18;k++){
            int s=st*18+k;
            int tap=k>>1, l=k&1;
            int doff=((tap/3)*13+(tap%3))*72+l*32;
            STEP3(lbase, s&3, doff);
            if(s<68){
                int s4=s+4, st4=s4/18, k4=s4-st4*18, tap4=k4>>1, l4=k4&1;
                LOADA3(s&3, tap4*8+st4*2+l4);
            }
        }
        if(st<3){ SWRITE3(lin+((st+1)&1)*12176); }
        __syncthreads();
    }
    if(MODE==1){
        #pragma unroll
        for(int mt=0;mt<4;mt++){
            int ocl=ocr*64+mt*16+kg*4;
            #pragma unroll
            for(int nt=0;nt<4;nt++){
                if(!pv_[nt]) continue;
                int p=pcr*64+nt*16+l15;
                size_t tb=(size_t)sb*CP_+(size_t)p*C_+ocl;
                us4 pk;
                if(ocb==0){
                    #pragma unroll
                    for(int r=0;r<4;r++){ float a=acc[mt][nt][r]+bias[ocl+r]; pk[r]=f2bu(1.f/(1.f+__expf(-a))); }
                    *(us4*)(o0+tb)=pk;
                }else{
                    us4 hv=*(const us4*)(hTb+tb);
                    #pragma unroll
                    for(int r=0;r<4;r++){ float a=acc[mt][nt][r]+bias[128+ocl+r]; float sg=1.f/(1.f+__expf(-a)); pk[r]=f2bu(sg*b2f(hv[r])); }
                    *(us4*)(o1+tb)=pk;
                }
            }
        }
    }else{
        // reuse lin (both buffers, contiguous) for NH tile [p][c]
        float ls=0.f, ls2=0.f;
        #pragma unroll
        for(int mt=0;mt<4;mt++){
            int ocl=ocr*64+mt*16+kg*4;
            #pragma unroll
            for(int nt=0;nt<4;nt++){
                if(!pv_[nt]) continue;
                int p=pcr*64+nt*16+l15;
                size_t tb=(size_t)sb*CP_+(size_t)p*C_+ocl;
                us4 hv=*(const us4*)(hTb+tb);
                us4 zv=*(const us4*)(zT+tb);
                us4 pk;
                #pragma unroll
                for(int r=0;r<4;r++){
                    float a=acc[mt][nt][r]+bias[ocl+r];
                    float ht=tanhf(a);
                    float z=b2f(zv[r]), h=b2f(hv[r]);
                    unsigned short u=f2bu((1.f-z)*h+z*ht+h);
                    pk[r]=u;
                    float nr=b2f(u); ls+=nr; ls2+=nr*nr;
                }
                *(us4*)((unsigned short*)lin + p*C_+ocl)=pk;
            }
        }
        #pragma unroll
        for(int o=32;o;o>>=1){ ls+=__shfl_xor(ls,o); ls2+=__shfl_xor(ls2,o); }
        if(lane==0){ red[w]=ls; red[4+w]=ls2; }
        __syncthreads();
        float Sx=red[0]+red[1]+red[2]+red[3];
        float Sx2=red[4]+red[5]+red[6]+red[7];
        float mu=Sx*(1.f/(float)CP_);
        float var=Sx2*(1.f/(float)CP_)-mu*mu;
        float rstd=rsqrtf(var+1e-5f);
        bf16t* ho=o0+(size_t)sb*CP_;
        for(int i=t;i<CP_;i+=256){
            float v=(ldb(lin+i)-mu)*rstd*gamT[i]+betT[i];
            ho[i]=__float2bfloat16(v);
        }
    }
}

// ---------- final: hT [p][c] -> natural [c][p] output ----------
__global__ __launch_bounds__(256) void finalT_kernel(void* __restrict__ fout, const bf16t* __restrict__ hT, const int* __restrict__ flag){
    __shared__ bf16t tl[CP_];
    int sb=blockIdx.x, t=threadIdx.x, f=*flag;
    for(int i=t;i<CP_;i+=256) tl[i]=hT[(size_t)sb*CP_+i];
    __syncthreads();
    for(int i=t;i<CP_;i+=256){
        int c=i/P_, p=i-c*P_;
        float v=ldb(tl+p*C_+c);
        size_t oi=(size_t)sb*CP_+i;
        if(f) ((float*)fout)[oi]=v;
        else  ((bf16t*)fout)[oi]=__float2bfloat16(v);
    }
}

extern "C" void kernel_launch(void* const* d_in, const int* in_sizes, int n_in,
                              void* d_out, int out_size, void* d_ws, size_t ws_size,
                              hipStream_t stream) {
    (void)in_sizes; (void)n_in; (void)out_size;
    char* base=(char*)d_ws;
    size_t off=0;
    auto alloc=[&](size_t bytes){ void* p=base+off; off+=(bytes+255)&~(size_t)255; return p; };
    bf16t* b1=(bf16t*)alloc((size_t)NEl*2+8192);          // hT
    bf16t* b2=(bf16t*)alloc((size_t)NEl*2+8192);          // comb
    bf16t* b3=(bf16t*)alloc((size_t)NEl*2+8192);          // RH
    bf16t* b4=(bf16t*)d_out;                              // Z / final
    bf16t* wqT=(bf16t*)alloc(16384*2);
    bf16t* wkT=(bf16t*)alloc(16384*2);
    bf16t* wvT=(bf16t*)alloc(16384*2);
    bf16t* w2T=(bf16t*)alloc(16384*2);
    bf16t* wzrT=(bf16t*)alloc((size_t)589824*2);
    bf16t* whT =(bf16t*)alloc((size_t)294912*2);
    float* W2f=(float*)alloc(16384*4);
    float* b2l=(float*)alloc(128*4); float* b2r=(float*)alloc(128*4);
    float* bqf=(float*)alloc(128*4); float* bkf=(float*)alloc(128*4); float* bvf=(float*)alloc(128*4);
    float* bzrf=(float*)alloc(256*4); float* bhf=(float*)alloc(128*4);
    float* gamT=(float*)alloc(15488*4); float* betT=(float*)alloc(15488*4);
    float* wgTf=(float*)alloc(16384*4); float* bgf2=(float*)alloc(128*4);
    float* alphaf=(float*)alloc(4); float* weightf=(float*)alloc(4);
    int* flag=(int*)alloc(4);
    if(ws_size<off) return;  // ~100MB needed

    detect_kernel<<<1,64,0,stream>>>((const unsigned short*)d_in[0],flag);
    cvtT_kernel<<<SBn,256,0,stream>>>(b1,d_in[0],flag);
    prep_w1t<1><<<64,256,0,stream>>>(wqT,d_in[1],flag);
    cvt_kernel<<<1,128,0,stream>>>(bqf,d_in[2],128,flag);
    prep_w1t<1><<<64,256,0,stream>>>(wkT,d_in[3],flag);
    cvt_kernel<<<1,128,0,stream>>>(bkf,d_in[4],128,flag);
    prep_w1t<1><<<64,256,0,stream>>>(wvT,d_in[5],flag);
    cvt_kernel<<<1,128,0,stream>>>(bvf,d_in[6],128,flag);
    cvt_kernel<<<1,64,0,stream>>>(alphaf,d_in[7],1,flag);
    prep_msg_kernel<<<C_,C_,0,stream>>>(W2f,b2l,b2r,d_in[10],d_in[8],d_in[9],flag);
    prep_w1t<0><<<64,256,0,stream>>>(w2T,W2f,flag);
    cvt_kernel<<<1,64,0,stream>>>(weightf,d_in[11],1,flag);
    prep_wgt<<<64,256,0,stream>>>(wgTf,bgf2,d_in[12],d_in[13],flag);
    prep_w3t<<<(256*2304+255)/256,256,0,stream>>>(wzrT,d_in[14],flag,256);
    cvt_kernel<<<1,256,0,stream>>>(bzrf,d_in[15],256,flag);
    prep_w3t<<<(128*2304+255)/256,256,0,stream>>>(whT,d_in[16],flag,128);
    cvt_kernel<<<1,128,0,stream>>>(bhf,d_in[17],128,flag);
    prep_gbt<<<(CP_+255)/256,256,0,stream>>>(gamT,betT,d_in[18],d_in[19],flag);

    for(int it=0; it<3; ++it){
        // intra: comb(b2) = w*(alpha*attn(h) + h)
        qkv_attn<<<SBn,512,0,stream>>>(b2,b1,wqT,wkT,wvT,bqf,bkf,bvf,alphaf,weightf);
        // left message (sb in [64,1024)): comb += (1-w)*m*g
        msg_all<<<SBn-B_,512,0,stream>>>(b2,b1,w2T,b2l,wgTf,bgf2,weightf,B_,-B_);
        // right message (sb in [0,960))
        msg_all<<<SBn-B_,512,0,stream>>>(b2,b1,w2T,b2r,wgTf,bgf2,weightf,0,B_);
        // GRU: zr([comb|h]) -> Z->b4, RH->b3 ; hhat([comb|RH]) + LN -> new hT (b1)
        conv3_mfma<1><<<dim3(SBn,2),256,0,stream>>>(b4,b3,b2,b1,wzrT,bzrf,nullptr,b1,nullptr,nullptr);
        conv3_mfma<2><<<dim3(SBn,1),256,0,stream>>>(b1,nullptr,b2,b3,whT,bhf,b4,b1,gamT,betT);
    }
    finalT_kernel<<<SBn,256,0,stream>>>(d_out,b1,flag);
}

// Round 10
// 1424.361 us; speedup vs baseline: 15.2668x; 1.0179x over previous
//
#include <hip/hip_runtime.h>
#include <hip/hip_bf16.h>

// GraphProcessor: S=16,B=64,C=128,H=W=11,P=121, 3 iterations.
// Transposed [sb][p][128ch] bf16 storage; MFMA everywhere; deep fusion.
// zr conv: 512-thr merged-ocb block, dbuf LDS + reg-staged B.
#define S_   16
#define B_   64
#define SBn  1024
#define C_   128
#define P_   121
#define CP_  15488
static const long NEl = 15859712L; // SBn*CP_

typedef __hip_bfloat16 bf16t;
typedef __attribute__((ext_vector_type(8))) short bf16x8;
typedef __attribute__((ext_vector_type(4))) float f32x4;
typedef __attribute__((ext_vector_type(4))) unsigned short us4;

__device__ __forceinline__ float ldb(const bf16t* p){ return __bfloat162float(*p); }
__device__ __forceinline__ float b2f(unsigned short u){ unsigned x=((unsigned)u)<<16; float f; __builtin_memcpy(&f,&x,4); return f; }
__device__ __forceinline__ unsigned short f2bu(float v){ __hip_bfloat16 b=__float2bfloat16(v); unsigned short u; __builtin_memcpy(&u,&b,2); return u; }
__device__ __forceinline__ float ldin(const void* s, long i, int f){
    return f ? ((const float*)s)[i] : b2f(((const unsigned short*)s)[i]);
}

// ---------- dtype detect: flag=1 if inputs are f32, 0 if bf16 ----------
__global__ void detect_kernel(const unsigned short* __restrict__ x, int* __restrict__ flag){
    if(blockIdx.x==0 && threadIdx.x==0){
        int crazy=0;
        for(int i=0;i<512;i++){
            unsigned e=(x[i]>>7)&0xFF;
            if(e!=0 && (e<64 || e>191)) crazy++;
        }
        *flag=(crazy>40)?1:0;
    }
}

// ---------- raw input -> f32 ----------
__global__ void cvt_kernel(float* __restrict__ dst, const void* __restrict__ src, long n, const int* __restrict__ flag){
    long i=(long)blockIdx.x*blockDim.x+threadIdx.x;
    long st=(long)gridDim.x*blockDim.x;
    int f=*flag;
    for(;i<n;i+=st) dst[i]=ldin(src,i,f);
}

// ---------- x [sb][c][p] -> hT [sb][p][c] bf16, LDS-tiled (coalesced both sides) ----------
__global__ __launch_bounds__(256) void cvtT_kernel(bf16t* __restrict__ hT, const void* __restrict__ x, const int* __restrict__ flag){
    __shared__ bf16t tl[CP_];   // [c][p]
    int sb=blockIdx.x, t=threadIdx.x; int f=*flag;
    for(int i=t;i<CP_;i+=256)
        tl[i]=__float2bfloat16(ldin(x,(long)sb*CP_+i,f));
    __syncthreads();
    bf16t* ho=hT+(size_t)sb*CP_;
    for(int j=t;j<CP_;j+=256){
        int p=j>>7, c=j&127;
        ho[j]=tl[c*P_+p];
    }
}

// ---------- fold w_lin @ w_msg[:, :C] into W2 (f32), edge bias into b2l/b2r ----------
__global__ __launch_bounds__(128) void prep_msg_kernel(float* __restrict__ W2, float* __restrict__ b2l, float* __restrict__ b2r,
        const void* __restrict__ wlin, const void* __restrict__ wmsg, const void* __restrict__ bmsg, const int* __restrict__ flag){
    int d=blockIdx.x, c=threadIdx.x; int f=*flag;
    float acc=0.f;
    for(int o2=0;o2<C_;o2++) acc += ldin(wlin,(long)d*C_+o2,f)*ldin(wmsg,(long)o2*(C_+1)+c,f);
    W2[d*C_+c]=acc;
    if(c<2){
        float e=(c==0)?1.f:-1.f; float a=0.f;
        for(int o2=0;o2<C_;o2++) a += ldin(wlin,(long)d*C_+o2,f)*(ldin(bmsg,o2,f)+e*ldin(wmsg,(long)o2*(C_+1)+C_,f));
        if(c==0) b2l[d]=a; else b2r[d]=a;
    }
}

// ---------- 1x1 weight [oc][128ic] -> tiled bf16 [icb(4)][oc(128)][32] ----------
template<int RAW>
__global__ void prep_w1t(bf16t* __restrict__ dst, const void* __restrict__ src, const int* __restrict__ flag){
    int idx=blockIdx.x*blockDim.x+threadIdx.x;
    if(idx>=16384) return;
    int r=idx&31, oc=(idx>>5)&127, icb=idx>>12;
    float v = RAW? ldin(src,(long)oc*C_+icb*32+r,*flag) : ((const float*)src)[(long)oc*C_+icb*32+r];
    dst[idx]=__float2bfloat16(v);
}

// ---------- 3x3 weight [oc][256ic][3][3] -> tiled bf16 [tap][icb(8)][oc][32] ----------
__global__ void prep_w3t(bf16t* __restrict__ dst, const void* __restrict__ src, const int* __restrict__ flag, int OC){
    int idx=blockIdx.x*blockDim.x+threadIdx.x;
    int tot=OC*2304;
    if(idx>=tot) return;
    int r=idx&31; int rest=idx>>5; int oc=rest%OC; int g2=rest/OC; int icb=g2&7, tap=g2>>3;
    float v=ldin(src,((long)(oc*256+icb*32+r))*9+tap,*flag);
    dst[idx]=__float2bfloat16(v);
}

// ---------- gamma/beta [c][p] -> transposed f32 [p][c] ----------
__global__ void prep_gbt(float* __restrict__ gamT, float* __restrict__ betT,
                         const void* __restrict__ gam, const void* __restrict__ bet, const int* __restrict__ flag){
    int idx=blockIdx.x*blockDim.x+threadIdx.x;
    if(idx>=CP_) return;
    int c=idx/P_, p=idx-c*P_; int f=*flag;
    gamT[p*C_+c]=ldin(gam,idx,f);
    betT[p*C_+c]=ldin(bet,idx,f);
}

// ---------- w_gate [c][k] -> transposed f32 [k][c]; b_gate -> f32 ----------
__global__ void prep_wgt(float* __restrict__ wgT, float* __restrict__ bg2,
                         const void* __restrict__ wg, const void* __restrict__ bg, const int* __restrict__ flag){
    int idx=blockIdx.x*blockDim.x+threadIdx.x;
    int f=*flag;
    if(idx<16384){ int k=idx>>7, c=idx&127; wgT[idx]=ldin(wg,(long)c*C_+k,f); }
    if(idx<128) bg2[idx]=ldin(bg,idx,f);
}

// ---------- 128x128x128 GEMM tile, 8 waves (2 ocr x 4 pcr), B from registers ----------
__device__ __forceinline__ void gemm24r(f32x4 (&acc)[4][2],
    const bf16t* __restrict__ Wt, const bf16x8 (&hreg)[4][2],
    int ocr,int l15,int kg)
{
    #pragma unroll
    for(int i=0;i<4;i++){
        #pragma unroll
        for(int j=0;j<2;j++) acc[i][j]=(f32x4){0.f,0.f,0.f,0.f};
    }
    #pragma unroll
    for(int kc=0;kc<4;kc++){
        bf16x8 a[4];
        #pragma unroll
        for(int mt=0;mt<4;mt++) a[mt]=*(const bf16x8*)(Wt+((size_t)(kc*C_+ocr*64+mt*16+l15))*32+kg*8);
        #pragma unroll
        for(int mt=0;mt<4;mt++){
            #pragma unroll
            for(int nt=0;nt<2;nt++)
                acc[mt][nt]=__builtin_amdgcn_mfma_f32_16x16x32_bf16(a[mt],hreg[kc][nt],acc[mt][nt],0,0,0);
        }
    }
}

// ---------- fused qkv + intra attention per (s,b), 512 threads, 2 LDS buffers ----------
// comb = w*(alpha * softmax(qk^T*scale) v + h)
__global__ __launch_bounds__(512) void qkv_attn(
    bf16t* __restrict__ comb, const bf16t* __restrict__ hT,
    const bf16t* __restrict__ WqT, const bf16t* __restrict__ WkT, const bf16t* __restrict__ WvT,
    const float* __restrict__ bq, const float* __restrict__ bk, const float* __restrict__ bv,
    const float* __restrict__ alphap, const float* __restrict__ wp)
{
    __shared__ bf16t LA[128*136];   // q, then v (natural)
    __shared__ bf16t LB[128*136];   // k, then P
    int sb=blockIdx.x, t=threadIdx.x, lane=t&63, w=t>>6;
    int l15=lane&15, kg=lane>>4;
    const bf16t* hp=hT+(size_t)sb*CP_;
    int ocr=w>>2, pcr=w&3;
    // hoist h B-fragments once, reuse for q/k/v GEMMs
    bf16x8 hreg[4][2];
    #pragma unroll
    for(int kc=0;kc<4;kc++){
        #pragma unroll
        for(int nt=0;nt<2;nt++)
            hreg[kc][nt]=*(const bf16x8*)(hp+(size_t)(pcr*32+nt*16+l15)*C_+kc*32+kg*8);
    }
    f32x4 acc[4][2];
    // q -> LA [p][c]
    gemm24r(acc,WqT,hreg,ocr,l15,kg);
    #pragma unroll
    for(int mt=0;mt<4;mt++){
        int oc0=ocr*64+mt*16+kg*4;
        #pragma unroll
        for(int nt=0;nt<2;nt++){
            int p=pcr*32+nt*16+l15;
            us4 pk;
            #pragma unroll
            for(int r=0;r<4;r++) pk[r]=f2bu(acc[mt][nt][r]+bq[oc0+r]);
            *(us4*)(LA+p*136+oc0)=pk;
        }
    }
    // k -> LB [p][c]
    gemm24r(acc,WkT,hreg,ocr,l15,kg);
    #pragma unroll
    for(int mt=0;mt<4;mt++){
        int oc0=ocr*64+mt*16+kg*4;
        #pragma unroll
        for(int nt=0;nt<2;nt++){
            int p=pcr*32+nt*16+l15;
            us4 pk;
            #pragma unroll
            for(int r=0;r<4;r++) pk[r]=f2bu(acc[mt][nt][r]+bk[oc0+r]);
            *(us4*)(LB+p*136+oc0)=pk;
        }
    }
    __syncthreads();
    // QK^T: wave owns rows m0..m0+15 (p = m0+kg*4+r), cols j = nt*16+l15
    int m0=w*16;
    f32x4 s[8];
    #pragma unroll
    for(int nt=0;nt<8;nt++) s[nt]=(f32x4){0.f,0.f,0.f,0.f};
    #pragma unroll
    for(int kc=0;kc<4;kc++){
        bf16x8 a=*(const bf16x8*)(LA+(size_t)(m0+l15)*136+kc*32+kg*8);
        #pragma unroll
        for(int nt=0;nt<8;nt++){
            bf16x8 b=*(const bf16x8*)(LB+(size_t)(nt*16+l15)*136+kc*32+kg*8);
            s[nt]=__builtin_amdgcn_mfma_f32_16x16x32_bf16(a,b,s[nt],0,0,0);
        }
    }
    const float scale=0.08838834764831845f;
    #pragma unroll
    for(int nt=0;nt<8;nt++){
        #pragma unroll
        for(int r=0;r<4;r++) s[nt][r]*=scale;
    }
    if(l15>=9){
        #pragma unroll
        for(int r=0;r<4;r++) s[7][r]=-3.0e38f;
    }
    #pragma unroll
    for(int r=0;r<4;r++){
        float mx=s[0][r];
        #pragma unroll
        for(int nt=1;nt<8;nt++) mx=fmaxf(mx,s[nt][r]);
        #pragma unroll
        for(int o=1;o<16;o<<=1) mx=fmaxf(mx,__shfl_xor(mx,o));
        float sm=0.f;
        #pragma unroll
        for(int nt=0;nt<8;nt++){ float e=__expf(s[nt][r]-mx); s[nt][r]=e; sm+=e; }
        #pragma unroll
        for(int o=1;o<16;o<<=1) sm+=__shfl_xor(sm,o);
        float rs=1.f/sm;
        #pragma unroll
        for(int nt=0;nt<8;nt++) s[nt][r]*=rs;
    }
    __syncthreads();   // everyone done reading q/k
    // v -> LA natural [c][p] (pad cols zeroed); P -> LB [p][j]
    gemm24r(acc,WvT,hreg,ocr,l15,kg);
    #pragma unroll
    for(int mt=0;mt<4;mt++){
        int oc0=ocr*64+mt*16+kg*4;
        #pragma unroll
        for(int nt=0;nt<2;nt++){
            int p=pcr*32+nt*16+l15;
            #pragma unroll
            for(int r=0;r<4;r++)
                LA[(oc0+r)*136+p]=__float2bfloat16(p<P_? acc[mt][nt][r]+bv[oc0+r] : 0.f);
        }
    }
    #pragma unroll
    for(int r=0;r<4;r++){
        int pr=m0+kg*4+r;
        #pragma unroll
        for(int nt=0;nt<8;nt++) LB[pr*136+nt*16+l15]=__float2bfloat16(s[nt][r]);
    }
    __syncthreads();
    // PV: wave owns c rows m0..m0+15
    f32x4 o[8];
    #pragma unroll
    for(int nt=0;nt<8;nt++) o[nt]=(f32x4){0.f,0.f,0.f,0.f};
    #pragma unroll
    for(int jc=0;jc<4;jc++){
        bf16x8 a=*(const bf16x8*)(LA+(size_t)(m0+l15)*136+jc*32+kg*8);
        #pragma unroll
        for(int nt=0;nt<8;nt++){
            bf16x8 b=*(const bf16x8*)(LB+(size_t)(nt*16+l15)*136+jc*32+kg*8);
            o[nt]=__builtin_amdgcn_mfma_f32_16x16x32_bf16(a,b,o[nt],0,0,0);
        }
    }
    float al=*alphap, wv=*wp;
    int c0=m0+kg*4;
    bf16t* ob=comb+(size_t)sb*CP_;
    #pragma unroll
    for(int nt=0;nt<8;nt++){
        int p=nt*16+l15;
        if(p>=P_) continue;
        us4 hv=*(const us4*)(hp+(size_t)p*C_+c0);
        us4 pk;
        #pragma unroll
        for(int r=0;r<4;r++) pk[r]=f2bu(wv*(al*o[nt][r]+b2f(hv[r])));
        *(us4*)(ob+(size_t)p*C_+c0)=pk;
    }
}

// ---------- fused msg: yy=W2@h_shift; m=softmax(h yy^T) yy; gate; comb += (1-w)*m*g ----------
__global__ __launch_bounds__(512) void msg_all(
    bf16t* __restrict__ comb, const bf16t* __restrict__ hT,
    const bf16t* __restrict__ W2T, const float* __restrict__ b2e,
    const float* __restrict__ wgT, const float* __restrict__ bgf,
    const float* __restrict__ wp, int sb0, int shift)
{
    __shared__ bf16t LA[128*136];   // yyT [p][c], then P
    __shared__ bf16t LB[128*136];   // yyN [c][p]
    __shared__ float fl[256];
    int sb=sb0+blockIdx.x, t=threadIdx.x, lane=t&63, w=t>>6;
    int l15=lane&15, kg=lane>>4;
    const bf16t* hsp=hT+(size_t)(sb+shift)*CP_;
    int ocr=w>>2, pcr=w&3;
    bf16x8 hreg[4][2];
    #pragma unroll
    for(int kc=0;kc<4;kc++){
        #pragma unroll
        for(int nt=0;nt<2;nt++)
            hreg[kc][nt]=*(const bf16x8*)(hsp+(size_t)(pcr*32+nt*16+l15)*C_+kc*32+kg*8);
    }
    f32x4 acc[4][2];
    gemm24r(acc,W2T,hreg,ocr,l15,kg);
    #pragma unroll
    for(int mt=0;mt<4;mt++){
        int oc0=ocr*64+mt*16+kg*4;
        #pragma unroll
        for(int nt=0;nt<2;nt++){
            int p=pcr*32+nt*16+l15;
            us4 pk;
            #pragma unroll
            for(int r=0;r<4;r++){
                float v=acc[mt][nt][r]+b2e[oc0+r];
                pk[r]=f2bu(v);
                LB[(oc0+r)*136+p]=__float2bfloat16(p<P_? v : 0.f);
            }
            *(us4*)(LA+p*136+oc0)=pk;
        }
    }
    __syncthreads();
    // logits: A = own h rows from global, B = yyT(LA); no scale
    int m0=w*16;
    const bf16t* ap=hT+(size_t)sb*CP_;
    f32x4 s[8];
    #pragma unroll
    for(int nt=0;nt<8;nt++) s[nt]=(f32x4){0.f,0.f,0.f,0.f};
    #pragma unroll
    for(int kc=0;kc<4;kc++){
        bf16x8 a=*(const bf16x8*)(ap+(size_t)(m0+l15)*C_+kc*32+kg*8);
        #pragma unroll
        for(int nt=0;nt<8;nt++){
            bf16x8 b=*(const bf16x8*)(LA+(size_t)(nt*16+l15)*136+kc*32+kg*8);
            s[nt]=__builtin_amdgcn_mfma_f32_16x16x32_bf16(a,b,s[nt],0,0,0);
        }
    }
    if(l15>=9){
        #pragma unroll
        for(int r=0;r<4;r++) s[7][r]=-3.0e38f;
    }
    #pragma unroll
    for(int r=0;r<4;r++){
        float mx=s[0][r];
        #pragma unroll
        for(int nt=1;nt<8;nt++) mx=fmaxf(mx,s[nt][r]);
        #pragma unroll
        for(int o=1;o<16;o<<=1) mx=fmaxf(mx,__shfl_xor(mx,o));
        float sm=0.f;
        #pragma unroll
        for(int nt=0;nt<8;nt++){ float e=__expf(s[nt][r]-mx); s[nt][r]=e; sm+=e; }
        #pragma unroll
        for(int o=1;o<16;o<<=1) sm+=__shfl_xor(sm,o);
        float rs=1.f/sm;
        #pragma unroll
        for(int nt=0;nt<8;nt++) s[nt][r]*=rs;
    }
    __syncthreads();   // everyone done reading yyT
    #pragma unroll
    for(int r=0;r<4;r++){
        int pr=m0+kg*4+r;
        #pragma unroll
        for(int nt=0;nt<8;nt++) LA[pr*136+nt*16+l15]=__float2bfloat16(s[nt][r]);
    }
    __syncthreads();
    // PV: m[c][p], A=yyN(LB), B=P(LA)
    f32x4 o[8];
    #pragma unroll
    for(int nt=0;nt<8;nt++) o[nt]=(f32x4){0.f,0.f,0.f,0.f};
    #pragma unroll
    for(int jc=0;jc<4;jc++){
        bf16x8 a=*(const bf16x8*)(LB+(size_t)(m0+l15)*136+jc*32+kg*8);
        #pragma unroll
        for(int nt=0;nt<8;nt++){
            bf16x8 b=*(const bf16x8*)(LA+(size_t)(nt*16+l15)*136+jc*32+kg*8);
            o[nt]=__builtin_amdgcn_mfma_f32_16x16x32_bf16(a,b,o[nt],0,0,0);
        }
    }
    // gate: mean over p, then matvec + sigmoid
    int c0=m0+kg*4;
    #pragma unroll
    for(int r=0;r<4;r++){
        float sm=0.f;
        #pragma unroll
        for(int nt=0;nt<8;nt++){ float v=o[nt][r]; if(nt==7&&l15>8) v=0.f; sm+=v; }
        sm+=__shfl_xor(sm,1); sm+=__shfl_xor(sm,2); sm+=__shfl_xor(sm,4); sm+=__shfl_xor(sm,8);
        if(l15==0) fl[c0+r]=sm*(1.f/121.f);
    }
    __syncthreads();
    if(t<C_){
        float a=bgf[t];
        #pragma unroll 8
        for(int k=0;k<C_;k++) a+=wgT[k*C_+t]*fl[k];
        fl[C_+t]=1.f/(1.f+__expf(-a));
    }
    __syncthreads();
    float w1m=1.f-*wp;
    float gg[4];
    #pragma unroll
    for(int r=0;r<4;r++) gg[r]=fl[C_+c0+r];
    bf16t* ob=comb+(size_t)sb*CP_;
    #pragma unroll
    for(int nt=0;nt<8;nt++){
        int p=nt*16+l15;
        if(p>=P_) continue;
        us4 bv=*(const us4*)(ob+(size_t)p*C_+c0);
        #pragma unroll
        for(int r=0;r<4;r++) bv[r]=f2bu(b2f(bv[r]) + w1m*o[nt][r]*gg[r]);
        *(us4*)(ob+(size_t)p*C_+c0)=bv;
    }
}

// ---------- shared MFMA-step macros for 3x3 convs ----------
#define LOADA3(bidx, widx) { \
    _Pragma("unroll") \
    for(int mt=0;mt<4;mt++) abuf[bidx][mt]=*(const bf16x8*)(Wt+(size_t)(widx)*(OC*32)+mt*512+base_lane); }
#define STEP3(lbase, bidx, doff) { \
    bf16x8 bb[4]; \
    _Pragma("unroll") \
    for(int nt=0;nt<4;nt++) bb[nt]=*(const bf16x8*)((lbase)+boff[nt]+(doff)); \
    __builtin_amdgcn_s_setprio(1); \
    _Pragma("unroll") \
    for(int mt=0;mt<4;mt++){ \
        _Pragma("unroll") \
        for(int nt=0;nt<4;nt++) \
            acc[mt][nt]=__builtin_amdgcn_mfma_f32_16x16x32_bf16(abuf[bidx][mt],bb[nt],acc[mt][nt],0,0,0); } \
    __builtin_amdgcn_s_setprio(0); }

// ---------- zr conv: 512 threads, waves 0-3 -> Z (ocb 0), waves 4-7 -> RH (ocb 128) ----------
#define SLOADZ(stg) { \
    const bf16t* ssrc=(((stg)<2)? in0T:in1T)+(size_t)sb*CP_+((stg)&1)*64; \
    sreg[0]=*(const bf16x8*)(ssrc+(size_t)sp0*C_+(t&7)*8); \
    if(sv1) sreg[1]=*(const bf16x8*)(ssrc+(size_t)sp1*C_+(t&7)*8); }
#define SWRITEZ(lbase) { \
    *(bf16x8*)((lbase)+spix0*72+(t&7)*8)=sreg[0]; \
    if(sv1) *(bf16x8*)((lbase)+spix1*72+(t&7)*8)=sreg[1]; }

__global__ __launch_bounds__(512) void conv3_zr(
    bf16t* __restrict__ o0, bf16t* __restrict__ o1,
    const bf16t* __restrict__ in0T, const bf16t* __restrict__ in1T,
    const bf16t* __restrict__ Wt, const float* __restrict__ bias,
    const bf16t* __restrict__ hTb)
{
    constexpr int OC=256;
    __shared__ bf16t lin[2*12176];
    int sb=blockIdx.x;
    int t=threadIdx.x, lane=t&63, w=t>>6;
    int ocb=(w>=4)?128:0; int w2=w&3;
    int ocr=w2>>1, pcr=w2&1, l15=lane&15, kg=lane>>4;
    int boff[4]; bool pv_[4];
    #pragma unroll
    for(int nt=0;nt<4;nt++){
        int p=pcr*64+nt*16+l15;
        pv_[nt]=(p<P_); int pc=pv_[nt]?p:(P_-1);
        boff[nt]=((pc/11)*13+(pc%11))*72+kg*8;
    }
    f32x4 acc[4][4];
    #pragma unroll
    for(int i=0;i<4;i++){
        #pragma unroll
        for(int j=0;j<4;j++) acc[i][j]=(f32x4){0.f,0.f,0.f,0.f};
    }
    int base_lane=(ocb+ocr*64+l15)*32+kg*8;
    bf16x8 abuf[4][4];
    bf16x8 sreg[2];
    // staging: 968 chunks of 8 bf16 per stage, 512 threads -> <=2 chunks each
    bool sv1=((t+512)<968);
    int sp0=t>>3, sp1=(t+512)>>3;
    if(sp1>120) sp1=120;
    int spix0=(sp0/11+1)*13+(sp0%11)+1;
    int spix1=(sp1/11+1)*13+(sp1%11)+1;
    // prologue: A-ring first 4 steps, B stage 0
    LOADA3(0,0); LOADA3(1,1); LOADA3(2,8); LOADA3(3,9);
    SLOADZ(0);
    // zero border pixels (48) in BOTH buffers: 768 chunks
    {
        bf16x8 z;
        #pragma unroll
        for(int e=0;e<8;e++) z[e]=0;
        for(int i=t;i<768;i+=512){
            int half=i>=384; int i2=i-half*384;
            int bi=i2>>3, cc=(i2&7)*8;
            int pix;
            if(bi<13) pix=bi;
            else if(bi<26) pix=156+(bi-13);
            else { int j2=bi-26; pix=(1+(j2>>1))*13+((j2&1)?12:0); }
            *(bf16x8*)(lin+half*12176+pix*72+cc)=z;
        }
    }
    SWRITEZ(lin);
    __syncthreads();
    #pragma unroll
    for(int st=0; st<4; ++st){
        if(st<3) SLOADZ(st+1);
        bf16t* lbase=lin+(st&1)*12176;
        #pragma unroll
        for(int k=0;k<18;k++){
            int s=st*18+k;
            int tap=k>>1, l=k&1;
            int doff=((tap/3)*13+(tap%3))*72+l*32;
            STEP3(lbase, s&3, doff);
            if(s<68){
                int s4=s+4, st4=s4/18, k4=s4-st4*18, tap4=k4>>1, l4=k4&1;
                LOADA3(s&3, tap4*8+st4*2+l4);
            }
        }
        if(st<3){ SWRITEZ(lin+((st+1)&1)*12176); }
        __syncthreads();
    }
    #pragma unroll
    for(int mt=0;mt<4;mt++){
        int ocl=ocr*64+mt*16+kg*4;
        #pragma unroll
        for(int nt=0;nt<4;nt++){
            if(!pv_[nt]) continue;
            int p=pcr*64+nt*16+l15;
            size_t tb=(size_t)sb*CP_+(size_t)p*C_+ocl;
            us4 pk;
            if(ocb==0){
                #pragma unroll
                for(int r=0;r<4;r++){ float a=acc[mt][nt][r]+bias[ocl+r]; pk[r]=f2bu(1.f/(1.f+__expf(-a))); }
                *(us4*)(o0+tb)=pk;
            }else{
                us4 hv=*(const us4*)(hTb+tb);
                #pragma unroll
                for(int r=0;r<4;r++){ float a=acc[mt][nt][r]+bias[128+ocl+r]; float sg=1.f/(1.f+__expf(-a)); pk[r]=f2bu(sg*b2f(hv[r])); }
                *(us4*)(o1+tb)=pk;
            }
        }
    }
}

// ---------- hhat conv + GRU-combine + LayerNorm: 256 threads (round-9 structure) ----------
#define SLOADH(stg) { \
    const bf16t* ssrc=(((stg)<2)? in0T:in1T)+(size_t)sb*CP_+((stg)&1)*64; \
    sreg[0]=*(const bf16x8*)(ssrc+(size_t)(t>>3)*C_+(t&7)*8); \
    sreg[1]=*(const bf16x8*)(ssrc+(size_t)((t+256)>>3)*C_+(t&7)*8); \
    if(sv2) sreg[2]=*(const bf16x8*)(ssrc+(size_t)sp2*C_+(t&7)*8); \
    if(sv3) sreg[3]=*(const bf16x8*)(ssrc+(size_t)sp3*C_+(t&7)*8); }
#define SWRITEH(lbase) { \
    *(bf16x8*)((lbase)+spix0*72+(t&7)*8)=sreg[0]; \
    *(bf16x8*)((lbase)+spix1*72+(t&7)*8)=sreg[1]; \
    if(sv2) *(bf16x8*)((lbase)+spix2*72+(t&7)*8)=sreg[2]; \
    if(sv3) *(bf16x8*)((lbase)+spix3*72+(t&7)*8)=sreg[3]; }

__global__ __launch_bounds__(256) void conv3_hh(
    bf16t* __restrict__ o0,
    const bf16t* __restrict__ in0T, const bf16t* __restrict__ in1T,
    const bf16t* __restrict__ Wt, const float* __restrict__ bias,
    const bf16t* __restrict__ zT, const bf16t* __restrict__ hTb,
    const float* __restrict__ gamT, const float* __restrict__ betT)
{
    constexpr int OC=128;
    __shared__ bf16t lin[2*12176];
    __shared__ float red[8];
    int sb=blockIdx.x;
    int t=threadIdx.x, lane=t&63, w=t>>6;
    int ocr=w>>1, pcr=w&1, l15=lane&15, kg=lane>>4;
    int boff[4]; bool pv_[4];
    #pragma unroll
    for(int nt=0;nt<4;nt++){
        int p=pcr*64+nt*16+l15;
        pv_[nt]=(p<P_); int pc=pv_[nt]?p:(P_-1);
        boff[nt]=((pc/11)*13+(pc%11))*72+kg*8;
    }
    f32x4 acc[4][4];
    #pragma unroll
    for(int i=0;i<4;i++){
        #pragma unroll
        for(int j=0;j<4;j++) acc[i][j]=(f32x4){0.f,0.f,0.f,0.f};
    }
    int base_lane=(ocr*64+l15)*32+kg*8;
    bf16x8 abuf[4][4];
    bf16x8 sreg[4];
    bool sv2=((t+512)<968), sv3=((t+768)<968);
    int sp0=t>>3, sp1=(t+256)>>3, sp2=(t+512)>>3, sp3=(t+768)>>3;
    if(sp2>120) sp2=120;
    if(sp3>120) sp3=120;
    int spix0=(sp0/11+1)*13+(sp0%11)+1;
    int spix1=(sp1/11+1)*13+(sp1%11)+1;
    int spix2=(sp2/11+1)*13+(sp2%11)+1;
    int spix3=(sp3/11+1)*13+(sp3%11)+1;
    LOADA3(0,0); LOADA3(1,1); LOADA3(2,8); LOADA3(3,9);
    SLOADH(0);
    {
        bf16x8 z;
        #pragma unroll
        for(int e=0;e<8;e++) z[e]=0;
        for(int i=t;i<768;i+=256){
            int half=i>=384; int i2=i-half*384;
            int bi=i2>>3, cc=(i2&7)*8;
            int pix;
            if(bi<13) pix=bi;
            else if(bi<26) pix=156+(bi-13);
            else { int j2=bi-26; pix=(1+(j2>>1))*13+((j2&1)?12:0); }
            *(bf16x8*)(lin+half*12176+pix*72+cc)=z;
        }
    }
    SWRITEH(lin);
    __syncthreads();
    #pragma unroll
    for(int st=0; st<4; ++st){
        if(st<3) SLOADH(st+1);
        bf16t* lbase=lin+(st&1)*12176;
        #pragma unroll
        for(int k=0;k<18;k++){
            int s=st*18+k;
            int tap=k>>1, l=k&1;
            int doff=((tap/3)*13+(tap%3))*72+l*32;
            STEP3(lbase, s&3, doff);
            if(s<68){
                int s4=s+4, st4=s4/18, k4=s4-st4*18, tap4=k4>>1, l4=k4&1;
                LOADA3(s&3, tap4*8+st4*2+l4);
            }
        }
        if(st<3){ SWRITEH(lin+((st+1)&1)*12176); }
        __syncthreads();
    }
    // GRU combine -> NH in LDS [p][c], LayerNorm, write new hT
    float ls=0.f, ls2=0.f;
    #pragma unroll
    for(int mt=0;mt<4;mt++){
        int ocl=ocr*64+mt*16+kg*4;
        #pragma unroll
        for(int nt=0;nt<4;nt++){
            if(!pv_[nt]) continue;
            int p=pcr*64+nt*16+l15;
            size_t tb=(size_t)sb*CP_+(size_t)p*C_+ocl;
            us4 hv=*(const us4*)(hTb+tb);
            us4 zv=*(const us4*)(zT+tb);
            us4 pk;
            #pragma unroll
            for(int r=0;r<4;r++){
                float a=acc[mt][nt][r]+bias[ocl+r];
                float ht=tanhf(a);
                float z=b2f(zv[r]), h=b2f(hv[r]);
                unsigned short u=f2bu((1.f-z)*h+z*ht+h);
                pk[r]=u;
                float nr=b2f(u); ls+=nr; ls2+=nr*nr;
            }
            *(us4*)((unsigned short*)lin + p*C_+ocl)=pk;
        }
    }
    #pragma unroll
    for(int o=32;o;o>>=1){ ls+=__shfl_xor(ls,o); ls2+=__shfl_xor(ls2,o); }
    if(lane==0){ red[w]=ls; red[4+w]=ls2; }
    __syncthreads();
    float Sx=red[0]+red[1]+red[2]+red[3];
    float Sx2=red[4]+red[5]+red[6]+red[7];
    float mu=Sx*(1.f/(float)CP_);
    float var=Sx2*(1.f/(float)CP_)-mu*mu;
    float rstd=rsqrtf(var+1e-5f);
    bf16t* ho=o0+(size_t)sb*CP_;
    for(int i=t;i<CP_;i+=256){
        float v=(ldb(lin+i)-mu)*rstd*gamT[i]+betT[i];
        ho[i]=__float2bfloat16(v);
    }
}

// ---------- final: hT [p][c] -> natural [c][p] output ----------
__global__ __launch_bounds__(256) void finalT_kernel(void* __restrict__ fout, const bf16t* __restrict__ hT, const int* __restrict__ flag){
    __shared__ bf16t tl[CP_];
    int sb=blockIdx.x, t=threadIdx.x, f=*flag;
    for(int i=t;i<CP_;i+=256) tl[i]=hT[(size_t)sb*CP_+i];
    __syncthreads();
    for(int i=t;i<CP_;i+=256){
        int c=i/P_, p=i-c*P_;
        float v=ldb(tl+p*C_+c);
        size_t oi=(size_t)sb*CP_+i;
        if(f) ((float*)fout)[oi]=v;
        else  ((bf16t*)fout)[oi]=__float2bfloat16(v);
    }
}

extern "C" void kernel_launch(void* const* d_in, const int* in_sizes, int n_in,
                              void* d_out, int out_size, void* d_ws, size_t ws_size,
                              hipStream_t stream) {
    (void)in_sizes; (void)n_in; (void)out_size;
    char* base=(char*)d_ws;
    size_t off=0;
    auto alloc=[&](size_t bytes){ void* p=base+off; off+=(bytes+255)&~(size_t)255; return p; };
    bf16t* b1=(bf16t*)alloc((size_t)NEl*2+8192);          // hT
    bf16t* b2=(bf16t*)alloc((size_t)NEl*2+8192);          // comb
    bf16t* b3=(bf16t*)alloc((size_t)NEl*2+8192);          // RH
    bf16t* b4=(bf16t*)d_out;                              // Z / final
    bf16t* wqT=(bf16t*)alloc(16384*2);
    bf16t* wkT=(bf16t*)alloc(16384*2);
    bf16t* wvT=(bf16t*)alloc(16384*2);
    bf16t* w2T=(bf16t*)alloc(16384*2);
    bf16t* wzrT=(bf16t*)alloc((size_t)589824*2);
    bf16t* whT =(bf16t*)alloc((size_t)294912*2);
    float* W2f=(float*)alloc(16384*4);
    float* b2l=(float*)alloc(128*4); float* b2r=(float*)alloc(128*4);
    float* bqf=(float*)alloc(128*4); float* bkf=(float*)alloc(128*4); float* bvf=(float*)alloc(128*4);
    float* bzrf=(float*)alloc(256*4); float* bhf=(float*)alloc(128*4);
    float* gamT=(float*)alloc(15488*4); float* betT=(float*)alloc(15488*4);
    float* wgTf=(float*)alloc(16384*4); float* bgf2=(float*)alloc(128*4);
    float* alphaf=(float*)alloc(4); float* weightf=(float*)alloc(4);
    int* flag=(int*)alloc(4);
    if(ws_size<off) return;  // ~100MB needed

    detect_kernel<<<1,64,0,stream>>>((const unsigned short*)d_in[0],flag);
    cvtT_kernel<<<SBn,256,0,stream>>>(b1,d_in[0],flag);
    prep_w1t<1><<<64,256,0,stream>>>(wqT,d_in[1],flag);
    cvt_kernel<<<1,128,0,stream>>>(bqf,d_in[2],128,flag);
    prep_w1t<1><<<64,256,0,stream>>>(wkT,d_in[3],flag);
    cvt_kernel<<<1,128,0,stream>>>(bkf,d_in[4],128,flag);
    prep_w1t<1><<<64,256,0,stream>>>(wvT,d_in[5],flag);
    cvt_kernel<<<1,128,0,stream>>>(bvf,d_in[6],128,flag);
    cvt_kernel<<<1,64,0,stream>>>(alphaf,d_in[7],1,flag);
    prep_msg_kernel<<<C_,C_,0,stream>>>(W2f,b2l,b2r,d_in[10],d_in[8],d_in[9],flag);
    prep_w1t<0><<<64,256,0,stream>>>(w2T,W2f,flag);
    cvt_kernel<<<1,64,0,stream>>>(weightf,d_in[11],1,flag);
    prep_wgt<<<64,256,0,stream>>>(wgTf,bgf2,d_in[12],d_in[13],flag);
    prep_w3t<<<(256*2304+255)/256,256,0,stream>>>(wzrT,d_in[14],flag,256);
    cvt_kernel<<<1,256,0,stream>>>(bzrf,d_in[15],256,flag);
    prep_w3t<<<(128*2304+255)/256,256,0,stream>>>(whT,d_in[16],flag,128);
    cvt_kernel<<<1,128,0,stream>>>(bhf,d_in[17],128,flag);
    prep_gbt<<<(CP_+255)/256,256,0,stream>>>(gamT,betT,d_in[18],d_in[19],flag);

    for(int it=0; it<3; ++it){
        // intra: comb(b2) = w*(alpha*attn(h) + h)
        qkv_attn<<<SBn,512,0,stream>>>(b2,b1,wqT,wkT,wvT,bqf,bkf,bvf,alphaf,weightf);
        // left message (sb in [64,1024)): comb += (1-w)*m*g
        msg_all<<<SBn-B_,512,0,stream>>>(b2,b1,w2T,b2l,wgTf,bgf2,weightf,B_,-B_);
        // right message (sb in [0,960))
        msg_all<<<SBn-B_,512,0,stream>>>(b2,b1,w2T,b2r,wgTf,bgf2,weightf,0,B_);
        // GRU: zr([comb|h]) -> Z->b4, RH->b3 (single 512-thr block per sb)
        conv3_zr<<<SBn,512,0,stream>>>(b4,b3,b2,b1,wzrT,bzrf,b1);
        // hhat([comb|RH]) + GRU combine + LN -> new hT (b1)
        conv3_hh<<<SBn,256,0,stream>>>(b1,b2,b3,whT,bhf,b4,b1,gamT,betT);
    }
    finalT_kernel<<<SBn,256,0,stream>>>(d_out,b1,flag);
}

// Round 11
// 1420.408 us; speedup vs baseline: 15.3093x; 1.0028x over previous
//
#include <hip/hip_runtime.h>
#include <hip/hip_bf16.h>

// GraphProcessor: S=16,B=64,C=128,H=W=11,P=121, 3 iterations.
// Transposed [sb][p][128ch] bf16 storage; MFMA everywhere; deep fusion.
// attn_all: intra + left-msg + right-msg fused, comb written once.
#define S_   16
#define B_   64
#define SBn  1024
#define C_   128
#define P_   121
#define CP_  15488
static const long NEl = 15859712L; // SBn*CP_

typedef __hip_bfloat16 bf16t;
typedef __attribute__((ext_vector_type(8))) short bf16x8;
typedef __attribute__((ext_vector_type(4))) float f32x4;
typedef __attribute__((ext_vector_type(4))) unsigned short us4;

__device__ __forceinline__ float ldb(const bf16t* p){ return __bfloat162float(*p); }
__device__ __forceinline__ float b2f(unsigned short u){ unsigned x=((unsigned)u)<<16; float f; __builtin_memcpy(&f,&x,4); return f; }
__device__ __forceinline__ unsigned short f2bu(float v){ __hip_bfloat16 b=__float2bfloat16(v); unsigned short u; __builtin_memcpy(&u,&b,2); return u; }
__device__ __forceinline__ float ldin(const void* s, long i, int f){
    return f ? ((const float*)s)[i] : b2f(((const unsigned short*)s)[i]);
}

// ---------- dtype detect: flag=1 if inputs are f32, 0 if bf16 ----------
__global__ void detect_kernel(const unsigned short* __restrict__ x, int* __restrict__ flag){
    if(blockIdx.x==0 && threadIdx.x==0){
        int crazy=0;
        for(int i=0;i<512;i++){
            unsigned e=(x[i]>>7)&0xFF;
            if(e!=0 && (e<64 || e>191)) crazy++;
        }
        *flag=(crazy>40)?1:0;
    }
}

// ---------- raw input -> f32 ----------
__global__ void cvt_kernel(float* __restrict__ dst, const void* __restrict__ src, long n, const int* __restrict__ flag){
    long i=(long)blockIdx.x*blockDim.x+threadIdx.x;
    long st=(long)gridDim.x*blockDim.x;
    int f=*flag;
    for(;i<n;i+=st) dst[i]=ldin(src,i,f);
}

// ---------- x [sb][c][p] -> hT [sb][p][c] bf16, LDS-tiled (coalesced both sides) ----------
__global__ __launch_bounds__(256) void cvtT_kernel(bf16t* __restrict__ hT, const void* __restrict__ x, const int* __restrict__ flag){
    __shared__ bf16t tl[CP_];   // [c][p]
    int sb=blockIdx.x, t=threadIdx.x; int f=*flag;
    for(int i=t;i<CP_;i+=256)
        tl[i]=__float2bfloat16(ldin(x,(long)sb*CP_+i,f));
    __syncthreads();
    bf16t* ho=hT+(size_t)sb*CP_;
    for(int j=t;j<CP_;j+=256){
        int p=j>>7, c=j&127;
        ho[j]=tl[c*P_+p];
    }
}

// ---------- fold w_lin @ w_msg[:, :C] into W2 (f32), edge bias into b2l/b2r ----------
__global__ __launch_bounds__(128) void prep_msg_kernel(float* __restrict__ W2, float* __restrict__ b2l, float* __restrict__ b2r,
        const void* __restrict__ wlin, const void* __restrict__ wmsg, const void* __restrict__ bmsg, const int* __restrict__ flag){
    int d=blockIdx.x, c=threadIdx.x; int f=*flag;
    float acc=0.f;
    for(int o2=0;o2<C_;o2++) acc += ldin(wlin,(long)d*C_+o2,f)*ldin(wmsg,(long)o2*(C_+1)+c,f);
    W2[d*C_+c]=acc;
    if(c<2){
        float e=(c==0)?1.f:-1.f; float a=0.f;
        for(int o2=0;o2<C_;o2++) a += ldin(wlin,(long)d*C_+o2,f)*(ldin(bmsg,o2,f)+e*ldin(wmsg,(long)o2*(C_+1)+C_,f));
        if(c==0) b2l[d]=a; else b2r[d]=a;
    }
}

// ---------- 1x1 weight [oc][128ic] -> tiled bf16 [icb(4)][oc(128)][32] ----------
template<int RAW>
__global__ void prep_w1t(bf16t* __restrict__ dst, const void* __restrict__ src, const int* __restrict__ flag){
    int idx=blockIdx.x*blockDim.x+threadIdx.x;
    if(idx>=16384) return;
    int r=idx&31, oc=(idx>>5)&127, icb=idx>>12;
    float v = RAW? ldin(src,(long)oc*C_+icb*32+r,*flag) : ((const float*)src)[(long)oc*C_+icb*32+r];
    dst[idx]=__float2bfloat16(v);
}

// ---------- 3x3 weight [oc][256ic][3][3] -> tiled bf16 [tap][icb(8)][oc][32] ----------
__global__ void prep_w3t(bf16t* __restrict__ dst, const void* __restrict__ src, const int* __restrict__ flag, int OC){
    int idx=blockIdx.x*blockDim.x+threadIdx.x;
    int tot=OC*2304;
    if(idx>=tot) return;
    int r=idx&31; int rest=idx>>5; int oc=rest%OC; int g2=rest/OC; int icb=g2&7, tap=g2>>3;
    float v=ldin(src,((long)(oc*256+icb*32+r))*9+tap,*flag);
    dst[idx]=__float2bfloat16(v);
}

// ---------- gamma/beta [c][p] -> transposed f32 [p][c] ----------
__global__ void prep_gbt(float* __restrict__ gamT, float* __restrict__ betT,
                         const void* __restrict__ gam, const void* __restrict__ bet, const int* __restrict__ flag){
    int idx=blockIdx.x*blockDim.x+threadIdx.x;
    if(idx>=CP_) return;
    int c=idx/P_, p=idx-c*P_; int f=*flag;
    gamT[p*C_+c]=ldin(gam,idx,f);
    betT[p*C_+c]=ldin(bet,idx,f);
}

// ---------- w_gate [c][k] -> transposed f32 [k][c]; b_gate -> f32 ----------
__global__ void prep_wgt(float* __restrict__ wgT, float* __restrict__ bg2,
                         const void* __restrict__ wg, const void* __restrict__ bg, const int* __restrict__ flag){
    int idx=blockIdx.x*blockDim.x+threadIdx.x;
    int f=*flag;
    if(idx<16384){ int k=idx>>7, c=idx&127; wgT[idx]=ldin(wg,(long)c*C_+k,f); }
    if(idx<128) bg2[idx]=ldin(bg,idx,f);
}

// ---------- 128x128x128 GEMM tile, 8 waves (2 ocr x 4 pcr), B from registers ----------
__device__ __forceinline__ void gemm24r(f32x4 (&acc)[4][2],
    const bf16t* __restrict__ Wt, const bf16x8 (&hreg)[4][2],
    int ocr,int l15,int kg)
{
    #pragma unroll
    for(int i=0;i<4;i++){
        #pragma unroll
        for(int j=0;j<2;j++) acc[i][j]=(f32x4){0.f,0.f,0.f,0.f};
    }
    #pragma unroll
    for(int kc=0;kc<4;kc++){
        bf16x8 a[4];
        #pragma unroll
        for(int mt=0;mt<4;mt++) a[mt]=*(const bf16x8*)(Wt+((size_t)(kc*C_+ocr*64+mt*16+l15))*32+kg*8);
        #pragma unroll
        for(int mt=0;mt<4;mt++){
            #pragma unroll
            for(int nt=0;nt<2;nt++)
                acc[mt][nt]=__builtin_amdgcn_mfma_f32_16x16x32_bf16(a[mt],hreg[kc][nt],acc[mt][nt],0,0,0);
        }
    }
}

// ---------- one message-direction phase: yy=W2@h_shift; m=softmax(h yy^T) yy; gate; res += (1-w)*m*g ----------
__device__ __forceinline__ void msg_phase(
    f32x4 (&res)[8], const bf16t* __restrict__ hT, int sb, int shift,
    const bf16t* __restrict__ W2T, const float* __restrict__ b2e,
    const float* __restrict__ wgT, const float* __restrict__ bgf, float w1m,
    const bf16x8 (&areg)[4],
    bf16t* LA, bf16t* LB, float* fl,
    int t,int w,int l15,int kg,int ocr,int pcr)
{
    __syncthreads();   // previous phase's LDS reads complete
    const bf16t* hsp=hT+(size_t)(sb+shift)*CP_;
    bf16x8 hregS[4][2];
    #pragma unroll
    for(int kc=0;kc<4;kc++){
        #pragma unroll
        for(int nt=0;nt<2;nt++)
            hregS[kc][nt]=*(const bf16x8*)(hsp+(size_t)(pcr*32+nt*16+l15)*C_+kc*32+kg*8);
    }
    f32x4 acc[4][2];
    gemm24r(acc,W2T,hregS,ocr,l15,kg);
    #pragma unroll
    for(int mt=0;mt<4;mt++){
        int oc0=ocr*64+mt*16+kg*4;
        #pragma unroll
        for(int nt=0;nt<2;nt++){
            int p=pcr*32+nt*16+l15;
            us4 pk;
            #pragma unroll
            for(int r=0;r<4;r++){
                float v=acc[mt][nt][r]+b2e[oc0+r];
                pk[r]=f2bu(v);
                LB[(oc0+r)*136+p]=__float2bfloat16(p<P_? v : 0.f);
            }
            *(us4*)(LA+p*136+oc0)=pk;
        }
    }
    __syncthreads();
    int m0=w*16;
    f32x4 s[8];
    #pragma unroll
    for(int nt=0;nt<8;nt++) s[nt]=(f32x4){0.f,0.f,0.f,0.f};
    #pragma unroll
    for(int kc=0;kc<4;kc++){
        #pragma unroll
        for(int nt=0;nt<8;nt++){
            bf16x8 b=*(const bf16x8*)(LA+(size_t)(nt*16+l15)*136+kc*32+kg*8);
            s[nt]=__builtin_amdgcn_mfma_f32_16x16x32_bf16(areg[kc],b,s[nt],0,0,0);
        }
    }
    if(l15>=9){
        #pragma unroll
        for(int r=0;r<4;r++) s[7][r]=-3.0e38f;
    }
    #pragma unroll
    for(int r=0;r<4;r++){
        float mx=s[0][r];
        #pragma unroll
        for(int nt=1;nt<8;nt++) mx=fmaxf(mx,s[nt][r]);
        #pragma unroll
        for(int o=1;o<16;o<<=1) mx=fmaxf(mx,__shfl_xor(mx,o));
        float sm=0.f;
        #pragma unroll
        for(int nt=0;nt<8;nt++){ float e=__expf(s[nt][r]-mx); s[nt][r]=e; sm+=e; }
        #pragma unroll
        for(int o=1;o<16;o<<=1) sm+=__shfl_xor(sm,o);
        float rs=1.f/sm;
        #pragma unroll
        for(int nt=0;nt<8;nt++) s[nt][r]*=rs;
    }
    __syncthreads();   // yyT reads done
    #pragma unroll
    for(int r=0;r<4;r++){
        int pr=m0+kg*4+r;
        #pragma unroll
        for(int nt=0;nt<8;nt++) LA[pr*136+nt*16+l15]=__float2bfloat16(s[nt][r]);
    }
    __syncthreads();
    f32x4 o[8];
    #pragma unroll
    for(int nt=0;nt<8;nt++) o[nt]=(f32x4){0.f,0.f,0.f,0.f};
    #pragma unroll
    for(int jc=0;jc<4;jc++){
        bf16x8 a=*(const bf16x8*)(LB+(size_t)(m0+l15)*136+jc*32+kg*8);
        #pragma unroll
        for(int nt=0;nt<8;nt++){
            bf16x8 b=*(const bf16x8*)(LA+(size_t)(nt*16+l15)*136+jc*32+kg*8);
            o[nt]=__builtin_amdgcn_mfma_f32_16x16x32_bf16(a,b,o[nt],0,0,0);
        }
    }
    int c0=m0+kg*4;
    #pragma unroll
    for(int r=0;r<4;r++){
        float sm=0.f;
        #pragma unroll
        for(int nt=0;nt<8;nt++){ float v=o[nt][r]; if(nt==7&&l15>8) v=0.f; sm+=v; }
        sm+=__shfl_xor(sm,1); sm+=__shfl_xor(sm,2); sm+=__shfl_xor(sm,4); sm+=__shfl_xor(sm,8);
        if(l15==0) fl[c0+r]=sm*(1.f/121.f);
    }
    __syncthreads();
    if(t<C_){
        float a=bgf[t];
        #pragma unroll 8
        for(int k=0;k<C_;k++) a+=wgT[k*C_+t]*fl[k];
        fl[C_+t]=1.f/(1.f+__expf(-a));
    }
    __syncthreads();
    float gg[4];
    #pragma unroll
    for(int r=0;r<4;r++) gg[r]=fl[C_+c0+r];
    #pragma unroll
    for(int nt=0;nt<8;nt++){
        #pragma unroll
        for(int r=0;r<4;r++) res[nt][r]+=w1m*o[nt][r]*gg[r];
    }
}

// ---------- fused intra + left-msg + right-msg per (s,b), 512 threads ----------
// comb = w*(alpha*attn(h)+h) + (1-w)*(m_l*g_l*maskL + m_r*g_r*maskR), written ONCE
__global__ __launch_bounds__(512) void attn_all(
    bf16t* __restrict__ comb, const bf16t* __restrict__ hT,
    const bf16t* __restrict__ WqT, const bf16t* __restrict__ WkT, const bf16t* __restrict__ WvT,
    const float* __restrict__ bq, const float* __restrict__ bk, const float* __restrict__ bv,
    const bf16t* __restrict__ W2T, const float* __restrict__ b2l, const float* __restrict__ b2r,
    const float* __restrict__ wgT, const float* __restrict__ bgf,
    const float* __restrict__ alphap, const float* __restrict__ wp)
{
    __shared__ bf16t LA[128*136];
    __shared__ bf16t LB[128*136];
    __shared__ float fl[256];
    int sb=blockIdx.x, t=threadIdx.x, lane=t&63, w=t>>6;
    int l15=lane&15, kg=lane>>4;
    const bf16t* hp=hT+(size_t)sb*CP_;
    int ocr=w>>2, pcr=w&3;
    int m0=w*16;
    // hoisted fragments: own-h B (q/k/v GEMMs) + own-h A (msg QK rows)
    bf16x8 hreg[4][2];
    #pragma unroll
    for(int kc=0;kc<4;kc++){
        #pragma unroll
        for(int nt=0;nt<2;nt++)
            hreg[kc][nt]=*(const bf16x8*)(hp+(size_t)(pcr*32+nt*16+l15)*C_+kc*32+kg*8);
    }
    bf16x8 areg[4];
    #pragma unroll
    for(int kc=0;kc<4;kc++)
        areg[kc]=*(const bf16x8*)(hp+(size_t)(m0+l15)*C_+kc*32+kg*8);

    f32x4 acc[4][2];
    // q -> LA [p][c]
    gemm24r(acc,WqT,hreg,ocr,l15,kg);
    #pragma unroll
    for(int mt=0;mt<4;mt++){
        int oc0=ocr*64+mt*16+kg*4;
        #pragma unroll
        for(int nt=0;nt<2;nt++){
            int p=pcr*32+nt*16+l15;
            us4 pk;
            #pragma unroll
            for(int r=0;r<4;r++) pk[r]=f2bu(acc[mt][nt][r]+bq[oc0+r]);
            *(us4*)(LA+p*136+oc0)=pk;
        }
    }
    // k -> LB [p][c]
    gemm24r(acc,WkT,hreg,ocr,l15,kg);
    #pragma unroll
    for(int mt=0;mt<4;mt++){
        int oc0=ocr*64+mt*16+kg*4;
        #pragma unroll
        for(int nt=0;nt<2;nt++){
            int p=pcr*32+nt*16+l15;
            us4 pk;
            #pragma unroll
            for(int r=0;r<4;r++) pk[r]=f2bu(acc[mt][nt][r]+bk[oc0+r]);
            *(us4*)(LB+p*136+oc0)=pk;
        }
    }
    __syncthreads();
    // QK^T
    f32x4 s[8];
    #pragma unroll
    for(int nt=0;nt<8;nt++) s[nt]=(f32x4){0.f,0.f,0.f,0.f};
    #pragma unroll
    for(int kc=0;kc<4;kc++){
        bf16x8 a=*(const bf16x8*)(LA+(size_t)(m0+l15)*136+kc*32+kg*8);
        #pragma unroll
        for(int nt=0;nt<8;nt++){
            bf16x8 b=*(const bf16x8*)(LB+(size_t)(nt*16+l15)*136+kc*32+kg*8);
            s[nt]=__builtin_amdgcn_mfma_f32_16x16x32_bf16(a,b,s[nt],0,0,0);
        }
    }
    const float scale=0.08838834764831845f;
    #pragma unroll
    for(int nt=0;nt<8;nt++){
        #pragma unroll
        for(int r=0;r<4;r++) s[nt][r]*=scale;
    }
    if(l15>=9){
        #pragma unroll
        for(int r=0;r<4;r++) s[7][r]=-3.0e38f;
    }
    #pragma unroll
    for(int r=0;r<4;r++){
        float mx=s[0][r];
        #pragma unroll
        for(int nt=1;nt<8;nt++) mx=fmaxf(mx,s[nt][r]);
        #pragma unroll
        for(int o=1;o<16;o<<=1) mx=fmaxf(mx,__shfl_xor(mx,o));
        float sm=0.f;
        #pragma unroll
        for(int nt=0;nt<8;nt++){ float e=__expf(s[nt][r]-mx); s[nt][r]=e; sm+=e; }
        #pragma unroll
        for(int o=1;o<16;o<<=1) sm+=__shfl_xor(sm,o);
        float rs=1.f/sm;
        #pragma unroll
        for(int nt=0;nt<8;nt++) s[nt][r]*=rs;
    }
    __syncthreads();   // q/k reads done
    // v -> LA natural [c][p]; P -> LB [p][j]
    gemm24r(acc,WvT,hreg,ocr,l15,kg);
    #pragma unroll
    for(int mt=0;mt<4;mt++){
        int oc0=ocr*64+mt*16+kg*4;
        #pragma unroll
        for(int nt=0;nt<2;nt++){
            int p=pcr*32+nt*16+l15;
            #pragma unroll
            for(int r=0;r<4;r++)
                LA[(oc0+r)*136+p]=__float2bfloat16(p<P_? acc[mt][nt][r]+bv[oc0+r] : 0.f);
        }
    }
    #pragma unroll
    for(int r=0;r<4;r++){
        int pr=m0+kg*4+r;
        #pragma unroll
        for(int nt=0;nt<8;nt++) LB[pr*136+nt*16+l15]=__float2bfloat16(s[nt][r]);
    }
    __syncthreads();
    // PV
    f32x4 res[8];
    #pragma unroll
    for(int nt=0;nt<8;nt++) res[nt]=(f32x4){0.f,0.f,0.f,0.f};
    #pragma unroll
    for(int jc=0;jc<4;jc++){
        bf16x8 a=*(const bf16x8*)(LA+(size_t)(m0+l15)*136+jc*32+kg*8);
        #pragma unroll
        for(int nt=0;nt<8;nt++){
            bf16x8 b=*(const bf16x8*)(LB+(size_t)(nt*16+l15)*136+jc*32+kg*8);
            res[nt]=__builtin_amdgcn_mfma_f32_16x16x32_bf16(a,b,res[nt],0,0,0);
        }
    }
    float al=*alphap, wv=*wp, w1m=1.f-wv;
    int c0=m0+kg*4;
    // res = w*(alpha*PV + h)
    #pragma unroll
    for(int nt=0;nt<8;nt++){
        int p=nt*16+l15;
        int pc=(p<P_)?p:(P_-1);
        us4 hv=*(const us4*)(hp+(size_t)pc*C_+c0);
        #pragma unroll
        for(int r=0;r<4;r++) res[nt][r]=wv*(al*res[nt][r]+b2f(hv[r]));
    }
    // message phases (block-uniform branches)
    if(sb>=B_)
        msg_phase(res,hT,sb,-B_,W2T,b2l,wgT,bgf,w1m,areg,LA,LB,fl,t,w,l15,kg,ocr,pcr);
    if(sb<SBn-B_)
        msg_phase(res,hT,sb, B_,W2T,b2r,wgT,bgf,w1m,areg,LA,LB,fl,t,w,l15,kg,ocr,pcr);
    // single comb write
    bf16t* ob=comb+(size_t)sb*CP_;
    #pragma unroll
    for(int nt=0;nt<8;nt++){
        int p=nt*16+l15;
        if(p>=P_) continue;
        us4 pk;
        #pragma unroll
        for(int r=0;r<4;r++) pk[r]=f2bu(res[nt][r]);
        *(us4*)(ob+(size_t)p*C_+c0)=pk;
    }
}

// ---------- shared MFMA-step macros for 3x3 convs ----------
#define LOADA3(bidx, widx) { \
    _Pragma("unroll") \
    for(int mt=0;mt<4;mt++) abuf[bidx][mt]=*(const bf16x8*)(Wt+(size_t)(widx)*(OC*32)+mt*512+base_lane); }
#define STEP3(lbase, bidx, doff) { \
    bf16x8 bb[4]; \
    _Pragma("unroll") \
    for(int nt=0;nt<4;nt++) bb[nt]=*(const bf16x8*)((lbase)+boff[nt]+(doff)); \
    __builtin_amdgcn_s_setprio(1); \
    _Pragma("unroll") \
    for(int mt=0;mt<4;mt++){ \
        _Pragma("unroll") \
        for(int nt=0;nt<4;nt++) \
            acc[mt][nt]=__builtin_amdgcn_mfma_f32_16x16x32_bf16(abuf[bidx][mt],bb[nt],acc[mt][nt],0,0,0); } \
    __builtin_amdgcn_s_setprio(0); }

// ---------- zr conv: 512 threads, waves 0-3 -> Z (ocb 0), waves 4-7 -> RH (ocb 128) ----------
#define SLOADZ(stg) { \
    const bf16t* ssrc=(((stg)<2)? in0T:in1T)+(size_t)sb*CP_+((stg)&1)*64; \
    sreg[0]=*(const bf16x8*)(ssrc+(size_t)sp0*C_+(t&7)*8); \
    if(sv1) sreg[1]=*(const bf16x8*)(ssrc+(size_t)sp1*C_+(t&7)*8); }
#define SWRITEZ(lbase) { \
    *(bf16x8*)((lbase)+spix0*72+(t&7)*8)=sreg[0]; \
    if(sv1) *(bf16x8*)((lbase)+spix1*72+(t&7)*8)=sreg[1]; }

__global__ __launch_bounds__(512) void conv3_zr(
    bf16t* __restrict__ o0, bf16t* __restrict__ o1,
    const bf16t* __restrict__ in0T, const bf16t* __restrict__ in1T,
    const bf16t* __restrict__ Wt, const float* __restrict__ bias,
    const bf16t* __restrict__ hTb)
{
    constexpr int OC=256;
    __shared__ bf16t lin[2*12176];
    int sb=blockIdx.x;
    int t=threadIdx.x, lane=t&63, w=t>>6;
    int ocb=(w>=4)?128:0; int w2=w&3;
    int ocr=w2>>1, pcr=w2&1, l15=lane&15, kg=lane>>4;
    int boff[4]; bool pv_[4];
    #pragma unroll
    for(int nt=0;nt<4;nt++){
        int p=pcr*64+nt*16+l15;
        pv_[nt]=(p<P_); int pc=pv_[nt]?p:(P_-1);
        boff[nt]=((pc/11)*13+(pc%11))*72+kg*8;
    }
    f32x4 acc[4][4];
    #pragma unroll
    for(int i=0;i<4;i++){
        #pragma unroll
        for(int j=0;j<4;j++) acc[i][j]=(f32x4){0.f,0.f,0.f,0.f};
    }
    int base_lane=(ocb+ocr*64+l15)*32+kg*8;
    bf16x8 abuf[4][4];
    bf16x8 sreg[2];
    bool sv1=((t+512)<968);
    int sp0=t>>3, sp1=(t+512)>>3;
    if(sp1>120) sp1=120;
    int spix0=(sp0/11+1)*13+(sp0%11)+1;
    int spix1=(sp1/11+1)*13+(sp1%11)+1;
    LOADA3(0,0); LOADA3(1,1); LOADA3(2,8); LOADA3(3,9);
    SLOADZ(0);
    {
        bf16x8 z;
        #pragma unroll
        for(int e=0;e<8;e++) z[e]=0;
        for(int i=t;i<768;i+=512){
            int half=i>=384; int i2=i-half*384;
            int bi=i2>>3, cc=(i2&7)*8;
            int pix;
            if(bi<13) pix=bi;
            else if(bi<26) pix=156+(bi-13);
            else { int j2=bi-26; pix=(1+(j2>>1))*13+((j2&1)?12:0); }
            *(bf16x8*)(lin+half*12176+pix*72+cc)=z;
        }
    }
    SWRITEZ(lin);
    __syncthreads();
    #pragma unroll
    for(int st=0; st<4; ++st){
        if(st<3) SLOADZ(st+1);
        bf16t* lbase=lin+(st&1)*12176;
        #pragma unroll
        for(int k=0;k<18;k++){
            int s=st*18+k;
            int tap=k>>1, l=k&1;
            int doff=((tap/3)*13+(tap%3))*72+l*32;
            STEP3(lbase, s&3, doff);
            if(s<68){
                int s4=s+4, st4=s4/18, k4=s4-st4*18, tap4=k4>>1, l4=k4&1;
                LOADA3(s&3, tap4*8+st4*2+l4);
            }
        }
        if(st<3){ SWRITEZ(lin+((st+1)&1)*12176); }
        __syncthreads();
    }
    #pragma unroll
    for(int mt=0;mt<4;mt++){
        int ocl=ocr*64+mt*16+kg*4;
        #pragma unroll
        for(int nt=0;nt<4;nt++){
            if(!pv_[nt]) continue;
            int p=pcr*64+nt*16+l15;
            size_t tb=(size_t)sb*CP_+(size_t)p*C_+ocl;
            us4 pk;
            if(ocb==0){
                #pragma unroll
                for(int r=0;r<4;r++){ float a=acc[mt][nt][r]+bias[ocl+r]; pk[r]=f2bu(1.f/(1.f+__expf(-a))); }
                *(us4*)(o0+tb)=pk;
            }else{
                us4 hv=*(const us4*)(hTb+tb);
                #pragma unroll
                for(int r=0;r<4;r++){ float a=acc[mt][nt][r]+bias[128+ocl+r]; float sg=1.f/(1.f+__expf(-a)); pk[r]=f2bu(sg*b2f(hv[r])); }
                *(us4*)(o1+tb)=pk;
            }
        }
    }
}

// ---------- hhat conv + GRU-combine + LayerNorm: 256 threads ----------
#define SLOADH(stg) { \
    const bf16t* ssrc=(((stg)<2)? in0T:in1T)+(size_t)sb*CP_+((stg)&1)*64; \
    sreg[0]=*(const bf16x8*)(ssrc+(size_t)(t>>3)*C_+(t&7)*8); \
    sreg[1]=*(const bf16x8*)(ssrc+(size_t)((t+256)>>3)*C_+(t&7)*8); \
    if(sv2) sreg[2]=*(const bf16x8*)(ssrc+(size_t)sp2*C_+(t&7)*8); \
    if(sv3) sreg[3]=*(const bf16x8*)(ssrc+(size_t)sp3*C_+(t&7)*8); }
#define SWRITEH(lbase) { \
    *(bf16x8*)((lbase)+spix0*72+(t&7)*8)=sreg[0]; \
    *(bf16x8*)((lbase)+spix1*72+(t&7)*8)=sreg[1]; \
    if(sv2) *(bf16x8*)((lbase)+spix2*72+(t&7)*8)=sreg[2]; \
    if(sv3) *(bf16x8*)((lbase)+spix3*72+(t&7)*8)=sreg[3]; }

__global__ __launch_bounds__(256) void conv3_hh(
    bf16t* __restrict__ o0,
    const bf16t* __restrict__ in0T, const bf16t* __restrict__ in1T,
    const bf16t* __restrict__ Wt, const float* __restrict__ bias,
    const bf16t* __restrict__ zT, const bf16t* __restrict__ hTb,
    const float* __restrict__ gamT, const float* __restrict__ betT)
{
    constexpr int OC=128;
    __shared__ bf16t lin[2*12176];
    __shared__ float red[8];
    int sb=blockIdx.x;
    int t=threadIdx.x, lane=t&63, w=t>>6;
    int ocr=w>>1, pcr=w&1, l15=lane&15, kg=lane>>4;
    int boff[4]; bool pv_[4];
    #pragma unroll
    for(int nt=0;nt<4;nt++){
        int p=pcr*64+nt*16+l15;
        pv_[nt]=(p<P_); int pc=pv_[nt]?p:(P_-1);
        boff[nt]=((pc/11)*13+(pc%11))*72+kg*8;
    }
    f32x4 acc[4][4];
    #pragma unroll
    for(int i=0;i<4;i++){
        #pragma unroll
        for(int j=0;j<4;j++) acc[i][j]=(f32x4){0.f,0.f,0.f,0.f};
    }
    int base_lane=(ocr*64+l15)*32+kg*8;
    bf16x8 abuf[4][4];
    bf16x8 sreg[4];
    bool sv2=((t+512)<968), sv3=((t+768)<968);
    int sp0=t>>3, sp1=(t+256)>>3, sp2=(t+512)>>3, sp3=(t+768)>>3;
    if(sp2>120) sp2=120;
    if(sp3>120) sp3=120;
    int spix0=(sp0/11+1)*13+(sp0%11)+1;
    int spix1=(sp1/11+1)*13+(sp1%11)+1;
    int spix2=(sp2/11+1)*13+(sp2%11)+1;
    int spix3=(sp3/11+1)*13+(sp3%11)+1;
    LOADA3(0,0); LOADA3(1,1); LOADA3(2,8); LOADA3(3,9);
    SLOADH(0);
    {
        bf16x8 z;
        #pragma unroll
        for(int e=0;e<8;e++) z[e]=0;
        for(int i=t;i<768;i+=256){
            int half=i>=384; int i2=i-half*384;
            int bi=i2>>3, cc=(i2&7)*8;
            int pix;
            if(bi<13) pix=bi;
            else if(bi<26) pix=156+(bi-13);
            else { int j2=bi-26; pix=(1+(j2>>1))*13+((j2&1)?12:0); }
            *(bf16x8*)(lin+half*12176+pix*72+cc)=z;
        }
    }
    SWRITEH(lin);
    __syncthreads();
    #pragma unroll
    for(int st=0; st<4; ++st){
        if(st<3) SLOADH(st+1);
        bf16t* lbase=lin+(st&1)*12176;
        #pragma unroll
        for(int k=0;k<18;k++){
            int s=st*18+k;
            int tap=k>>1, l=k&1;
            int doff=((tap/3)*13+(tap%3))*72+l*32;
            STEP3(lbase, s&3, doff);
            if(s<68){
                int s4=s+4, st4=s4/18, k4=s4-st4*18, tap4=k4>>1, l4=k4&1;
                LOADA3(s&3, tap4*8+st4*2+l4);
            }
        }
        if(st<3){ SWRITEH(lin+((st+1)&1)*12176); }
        __syncthreads();
    }
    float ls=0.f, ls2=0.f;
    #pragma unroll
    for(int mt=0;mt<4;mt++){
        int ocl=ocr*64+mt*16+kg*4;
        #pragma unroll
        for(int nt=0;nt<4;nt++){
            if(!pv_[nt]) continue;
            int p=pcr*64+nt*16+l15;
            size_t tb=(size_t)sb*CP_+(size_t)p*C_+ocl;
            us4 hv=*(const us4*)(hTb+tb);
            us4 zv=*(const us4*)(zT+tb);
            us4 pk;
            #pragma unroll
            for(int r=0;r<4;r++){
                float a=acc[mt][nt][r]+bias[ocl+r];
                float ht=tanhf(a);
                float z=b2f(zv[r]), h=b2f(hv[r]);
                unsigned short u=f2bu((1.f-z)*h+z*ht+h);
                pk[r]=u;
                float nr=b2f(u); ls+=nr; ls2+=nr*nr;
            }
            *(us4*)((unsigned short*)lin + p*C_+ocl)=pk;
        }
    }
    #pragma unroll
    for(int o=32;o;o>>=1){ ls+=__shfl_xor(ls,o); ls2+=__shfl_xor(ls2,o); }
    if(lane==0){ red[w]=ls; red[4+w]=ls2; }
    __syncthreads();
    float Sx=red[0]+red[1]+red[2]+red[3];
    float Sx2=red[4]+red[5]+red[6]+red[7];
    float mu=Sx*(1.f/(float)CP_);
    float var=Sx2*(1.f/(float)CP_)-mu*mu;
    float rstd=rsqrtf(var+1e-5f);
    bf16t* ho=o0+(size_t)sb*CP_;
    for(int i=t;i<CP_;i+=256){
        float v=(ldb(lin+i)-mu)*rstd*gamT[i]+betT[i];
        ho[i]=__float2bfloat16(v);
    }
}

// ---------- final: hT [p][c] -> natural [c][p] output ----------
__global__ __launch_bounds__(256) void finalT_kernel(void* __restrict__ fout, const bf16t* __restrict__ hT, const int* __restrict__ flag){
    __shared__ bf16t tl[CP_];
    int sb=blockIdx.x, t=threadIdx.x, f=*flag;
    for(int i=t;i<CP_;i+=256) tl[i]=hT[(size_t)sb*CP_+i];
    __syncthreads();
    for(int i=t;i<CP_;i+=256){
        int c=i/P_, p=i-c*P_;
        float v=ldb(tl+p*C_+c);
        size_t oi=(size_t)sb*CP_+i;
        if(f) ((float*)fout)[oi]=v;
        else  ((bf16t*)fout)[oi]=__float2bfloat16(v);
    }
}

extern "C" void kernel_launch(void* const* d_in, const int* in_sizes, int n_in,
                              void* d_out, int out_size, void* d_ws, size_t ws_size,
                              hipStream_t stream) {
    (void)in_sizes; (void)n_in; (void)out_size;
    char* base=(char*)d_ws;
    size_t off=0;
    auto alloc=[&](size_t bytes){ void* p=base+off; off+=(bytes+255)&~(size_t)255; return p; };
    bf16t* b1=(bf16t*)alloc((size_t)NEl*2+8192);          // hT
    bf16t* b2=(bf16t*)alloc((size_t)NEl*2+8192);          // comb
    bf16t* b3=(bf16t*)alloc((size_t)NEl*2+8192);          // RH
    bf16t* b4=(bf16t*)d_out;                              // Z / final
    bf16t* wqT=(bf16t*)alloc(16384*2);
    bf16t* wkT=(bf16t*)alloc(16384*2);
    bf16t* wvT=(bf16t*)alloc(16384*2);
    bf16t* w2T=(bf16t*)alloc(16384*2);
    bf16t* wzrT=(bf16t*)alloc((size_t)589824*2);
    bf16t* whT =(bf16t*)alloc((size_t)294912*2);
    float* W2f=(float*)alloc(16384*4);
    float* b2l=(float*)alloc(128*4); float* b2r=(float*)alloc(128*4);
    float* bqf=(float*)alloc(128*4); float* bkf=(float*)alloc(128*4); float* bvf=(float*)alloc(128*4);
    float* bzrf=(float*)alloc(256*4); float* bhf=(float*)alloc(128*4);
    float* gamT=(float*)alloc(15488*4); float* betT=(float*)alloc(15488*4);
    float* wgTf=(float*)alloc(16384*4); float* bgf2=(float*)alloc(128*4);
    float* alphaf=(float*)alloc(4); float* weightf=(float*)alloc(4);
    int* flag=(int*)alloc(4);
    if(ws_size<off) return;  // ~100MB needed

    detect_kernel<<<1,64,0,stream>>>((const unsigned short*)d_in[0],flag);
    cvtT_kernel<<<SBn,256,0,stream>>>(b1,d_in[0],flag);
    prep_w1t<1><<<64,256,0,stream>>>(wqT,d_in[1],flag);
    cvt_kernel<<<1,128,0,stream>>>(bqf,d_in[2],128,flag);
    prep_w1t<1><<<64,256,0,stream>>>(wkT,d_in[3],flag);
    cvt_kernel<<<1,128,0,stream>>>(bkf,d_in[4],128,flag);
    prep_w1t<1><<<64,256,0,stream>>>(wvT,d_in[5],flag);
    cvt_kernel<<<1,128,0,stream>>>(bvf,d_in[6],128,flag);
    cvt_kernel<<<1,64,0,stream>>>(alphaf,d_in[7],1,flag);
    prep_msg_kernel<<<C_,C_,0,stream>>>(W2f,b2l,b2r,d_in[10],d_in[8],d_in[9],flag);
    prep_w1t<0><<<64,256,0,stream>>>(w2T,W2f,flag);
    cvt_kernel<<<1,64,0,stream>>>(weightf,d_in[11],1,flag);
    prep_wgt<<<64,256,0,stream>>>(wgTf,bgf2,d_in[12],d_in[13],flag);
    prep_w3t<<<(256*2304+255)/256,256,0,stream>>>(wzrT,d_in[14],flag,256);
    cvt_kernel<<<1,256,0,stream>>>(bzrf,d_in[15],256,flag);
    prep_w3t<<<(128*2304+255)/256,256,0,stream>>>(whT,d_in[16],flag,128);
    cvt_kernel<<<1,128,0,stream>>>(bhf,d_in[17],128,flag);
    prep_gbt<<<(CP_+255)/256,256,0,stream>>>(gamT,betT,d_in[18],d_in[19],flag);

    for(int it=0; it<3; ++it){
        // comb(b2) = w*(alpha*attn(h)+h) + (1-w)*(msgL+msgR), one kernel, one write
        attn_all<<<SBn,512,0,stream>>>(b2,b1,wqT,wkT,wvT,bqf,bkf,bvf,
                                       w2T,b2l,b2r,wgTf,bgf2,alphaf,weightf);
        // GRU: zr([comb|h]) -> Z->b4, RH->b3
        conv3_zr<<<SBn,512,0,stream>>>(b4,b3,b2,b1,wzrT,bzrf,b1);
        // hhat([comb|RH]) + GRU combine + LN -> new hT (b1)
        conv3_hh<<<SBn,256,0,stream>>>(b1,b2,b3,whT,bhf,b4,b1,gamT,betT);
    }
    finalT_kernel<<<SBn,256,0,stream>>>(d_out,b1,flag);
}

// Round 12
// 1417.795 us; speedup vs baseline: 15.3375x; 1.0018x over previous
//
#include <hip/hip_runtime.h>
#include <hip/hip_bf16.h>

// GraphProcessor: S=16,B=64,C=128,H=W=11,P=121, 3 iterations.
// Transposed [sb][p][128ch] bf16 storage; MFMA everywhere; deep fusion.
// This round: LDS-staged coalesced epilogue stores (zr Z/RH, attn comb, hh LN).
#define S_   16
#define B_   64
#define SBn  1024
#define C_   128
#define P_   121
#define CP_  15488
static const long NEl = 15859712L; // SBn*CP_

typedef __hip_bfloat16 bf16t;
typedef __attribute__((ext_vector_type(8))) short bf16x8;
typedef __attribute__((ext_vector_type(4))) float f32x4;
typedef __attribute__((ext_vector_type(4))) unsigned short us4;

__device__ __forceinline__ float ldb(const bf16t* p){ return __bfloat162float(*p); }
__device__ __forceinline__ float b2f(unsigned short u){ unsigned x=((unsigned)u)<<16; float f; __builtin_memcpy(&f,&x,4); return f; }
__device__ __forceinline__ unsigned short f2bu(float v){ __hip_bfloat16 b=__float2bfloat16(v); unsigned short u; __builtin_memcpy(&u,&b,2); return u; }
__device__ __forceinline__ float ldin(const void* s, long i, int f){
    return f ? ((const float*)s)[i] : b2f(((const unsigned short*)s)[i]);
}

// ---------- dtype detect: flag=1 if inputs are f32, 0 if bf16 ----------
__global__ void detect_kernel(const unsigned short* __restrict__ x, int* __restrict__ flag){
    if(blockIdx.x==0 && threadIdx.x==0){
        int crazy=0;
        for(int i=0;i<512;i++){
            unsigned e=(x[i]>>7)&0xFF;
            if(e!=0 && (e<64 || e>191)) crazy++;
        }
        *flag=(crazy>40)?1:0;
    }
}

// ---------- raw input -> f32 ----------
__global__ void cvt_kernel(float* __restrict__ dst, const void* __restrict__ src, long n, const int* __restrict__ flag){
    long i=(long)blockIdx.x*blockDim.x+threadIdx.x;
    long st=(long)gridDim.x*blockDim.x;
    int f=*flag;
    for(;i<n;i+=st) dst[i]=ldin(src,i,f);
}

// ---------- x [sb][c][p] -> hT [sb][p][c] bf16, LDS-tiled (coalesced both sides) ----------
__global__ __launch_bounds__(256) void cvtT_kernel(bf16t* __restrict__ hT, const void* __restrict__ x, const int* __restrict__ flag){
    __shared__ bf16t tl[CP_];   // [c][p]
    int sb=blockIdx.x, t=threadIdx.x; int f=*flag;
    for(int i=t;i<CP_;i+=256)
        tl[i]=__float2bfloat16(ldin(x,(long)sb*CP_+i,f));
    __syncthreads();
    bf16t* ho=hT+(size_t)sb*CP_;
    for(int j=t;j<CP_;j+=256){
        int p=j>>7, c=j&127;
        ho[j]=tl[c*P_+p];
    }
}

// ---------- fold w_lin @ w_msg[:, :C] into W2 (f32), edge bias into b2l/b2r ----------
__global__ __launch_bounds__(128) void prep_msg_kernel(float* __restrict__ W2, float* __restrict__ b2l, float* __restrict__ b2r,
        const void* __restrict__ wlin, const void* __restrict__ wmsg, const void* __restrict__ bmsg, const int* __restrict__ flag){
    int d=blockIdx.x, c=threadIdx.x; int f=*flag;
    float acc=0.f;
    for(int o2=0;o2<C_;o2++) acc += ldin(wlin,(long)d*C_+o2,f)*ldin(wmsg,(long)o2*(C_+1)+c,f);
    W2[d*C_+c]=acc;
    if(c<2){
        float e=(c==0)?1.f:-1.f; float a=0.f;
        for(int o2=0;o2<C_;o2++) a += ldin(wlin,(long)d*C_+o2,f)*(ldin(bmsg,o2,f)+e*ldin(wmsg,(long)o2*(C_+1)+C_,f));
        if(c==0) b2l[d]=a; else b2r[d]=a;
    }
}

// ---------- 1x1 weight [oc][128ic] -> tiled bf16 [icb(4)][oc(128)][32] ----------
template<int RAW>
__global__ void prep_w1t(bf16t* __restrict__ dst, const void* __restrict__ src, const int* __restrict__ flag){
    int idx=blockIdx.x*blockDim.x+threadIdx.x;
    if(idx>=16384) return;
    int r=idx&31, oc=(idx>>5)&127, icb=idx>>12;
    float v = RAW? ldin(src,(long)oc*C_+icb*32+r,*flag) : ((const float*)src)[(long)oc*C_+icb*32+r];
    dst[idx]=__float2bfloat16(v);
}

// ---------- 3x3 weight [oc][256ic][3][3] -> tiled bf16 [tap][icb(8)][oc][32] ----------
__global__ void prep_w3t(bf16t* __restrict__ dst, const void* __restrict__ src, const int* __restrict__ flag, int OC){
    int idx=blockIdx.x*blockDim.x+threadIdx.x;
    int tot=OC*2304;
    if(idx>=tot) return;
    int r=idx&31; int rest=idx>>5; int oc=rest%OC; int g2=rest/OC; int icb=g2&7, tap=g2>>3;
    float v=ldin(src,((long)(oc*256+icb*32+r))*9+tap,*flag);
    dst[idx]=__float2bfloat16(v);
}

// ---------- gamma/beta [c][p] -> transposed f32 [p][c] ----------
__global__ void prep_gbt(float* __restrict__ gamT, float* __restrict__ betT,
                         const void* __restrict__ gam, const void* __restrict__ bet, const int* __restrict__ flag){
    int idx=blockIdx.x*blockDim.x+threadIdx.x;
    if(idx>=CP_) return;
    int c=idx/P_, p=idx-c*P_; int f=*flag;
    gamT[p*C_+c]=ldin(gam,idx,f);
    betT[p*C_+c]=ldin(bet,idx,f);
}

// ---------- w_gate [c][k] -> transposed f32 [k][c]; b_gate -> f32 ----------
__global__ void prep_wgt(float* __restrict__ wgT, float* __restrict__ bg2,
                         const void* __restrict__ wg, const void* __restrict__ bg, const int* __restrict__ flag){
    int idx=blockIdx.x*blockDim.x+threadIdx.x;
    int f=*flag;
    if(idx<16384){ int k=idx>>7, c=idx&127; wgT[idx]=ldin(wg,(long)c*C_+k,f); }
    if(idx<128) bg2[idx]=ldin(bg,idx,f);
}

// ---------- 128x128x128 GEMM tile, 8 waves (2 ocr x 4 pcr), B from registers ----------
__device__ __forceinline__ void gemm24r(f32x4 (&acc)[4][2],
    const bf16t* __restrict__ Wt, const bf16x8 (&hreg)[4][2],
    int ocr,int l15,int kg)
{
    #pragma unroll
    for(int i=0;i<4;i++){
        #pragma unroll
        for(int j=0;j<2;j++) acc[i][j]=(f32x4){0.f,0.f,0.f,0.f};
    }
    #pragma unroll
    for(int kc=0;kc<4;kc++){
        bf16x8 a[4];
        #pragma unroll
        for(int mt=0;mt<4;mt++) a[mt]=*(const bf16x8*)(Wt+((size_t)(kc*C_+ocr*64+mt*16+l15))*32+kg*8);
        #pragma unroll
        for(int mt=0;mt<4;mt++){
            #pragma unroll
            for(int nt=0;nt<2;nt++)
                acc[mt][nt]=__builtin_amdgcn_mfma_f32_16x16x32_bf16(a[mt],hreg[kc][nt],acc[mt][nt],0,0,0);
        }
    }
}

// ---------- one message-direction phase: yy=W2@h_shift; m=softmax(h yy^T) yy; gate; res += (1-w)*m*g ----------
__device__ __forceinline__ void msg_phase(
    f32x4 (&res)[8], const bf16t* __restrict__ hT, int sb, int shift,
    const bf16t* __restrict__ W2T, const float* __restrict__ b2e,
    const float* __restrict__ wgT, const float* __restrict__ bgf, float w1m,
    const bf16x8 (&areg)[4],
    bf16t* LA, bf16t* LB, float* fl,
    int t,int w,int l15,int kg,int ocr,int pcr)
{
    __syncthreads();   // previous phase's LDS reads complete
    const bf16t* hsp=hT+(size_t)(sb+shift)*CP_;
    bf16x8 hregS[4][2];
    #pragma unroll
    for(int kc=0;kc<4;kc++){
        #pragma unroll
        for(int nt=0;nt<2;nt++)
            hregS[kc][nt]=*(const bf16x8*)(hsp+(size_t)(pcr*32+nt*16+l15)*C_+kc*32+kg*8);
    }
    f32x4 acc[4][2];
    gemm24r(acc,W2T,hregS,ocr,l15,kg);
    #pragma unroll
    for(int mt=0;mt<4;mt++){
        int oc0=ocr*64+mt*16+kg*4;
        #pragma unroll
        for(int nt=0;nt<2;nt++){
            int p=pcr*32+nt*16+l15;
            us4 pk;
            #pragma unroll
            for(int r=0;r<4;r++){
                float v=acc[mt][nt][r]+b2e[oc0+r];
                pk[r]=f2bu(v);
                LB[(oc0+r)*136+p]=__float2bfloat16(p<P_? v : 0.f);
            }
            *(us4*)(LA+p*136+oc0)=pk;
        }
    }
    __syncthreads();
    int m0=w*16;
    f32x4 s[8];
    #pragma unroll
    for(int nt=0;nt<8;nt++) s[nt]=(f32x4){0.f,0.f,0.f,0.f};
    #pragma unroll
    for(int kc=0;kc<4;kc++){
        #pragma unroll
        for(int nt=0;nt<8;nt++){
            bf16x8 b=*(const bf16x8*)(LA+(size_t)(nt*16+l15)*136+kc*32+kg*8);
            s[nt]=__builtin_amdgcn_mfma_f32_16x16x32_bf16(areg[kc],b,s[nt],0,0,0);
        }
    }
    if(l15>=9){
        #pragma unroll
        for(int r=0;r<4;r++) s[7][r]=-3.0e38f;
    }
    #pragma unroll
    for(int r=0;r<4;r++){
        float mx=s[0][r];
        #pragma unroll
        for(int nt=1;nt<8;nt++) mx=fmaxf(mx,s[nt][r]);
        #pragma unroll
        for(int o=1;o<16;o<<=1) mx=fmaxf(mx,__shfl_xor(mx,o));
        float sm=0.f;
        #pragma unroll
        for(int nt=0;nt<8;nt++){ float e=__expf(s[nt][r]-mx); s[nt][r]=e; sm+=e; }
        #pragma unroll
        for(int o=1;o<16;o<<=1) sm+=__shfl_xor(sm,o);
        float rs=1.f/sm;
        #pragma unroll
        for(int nt=0;nt<8;nt++) s[nt][r]*=rs;
    }
    __syncthreads();   // yyT reads done
    #pragma unroll
    for(int r=0;r<4;r++){
        int pr=m0+kg*4+r;
        #pragma unroll
        for(int nt=0;nt<8;nt++) LA[pr*136+nt*16+l15]=__float2bfloat16(s[nt][r]);
    }
    __syncthreads();
    f32x4 o[8];
    #pragma unroll
    for(int nt=0;nt<8;nt++) o[nt]=(f32x4){0.f,0.f,0.f,0.f};
    #pragma unroll
    for(int jc=0;jc<4;jc++){
        bf16x8 a=*(const bf16x8*)(LB+(size_t)(m0+l15)*136+jc*32+kg*8);
        #pragma unroll
        for(int nt=0;nt<8;nt++){
            bf16x8 b=*(const bf16x8*)(LA+(size_t)(nt*16+l15)*136+jc*32+kg*8);
            o[nt]=__builtin_amdgcn_mfma_f32_16x16x32_bf16(a,b,o[nt],0,0,0);
        }
    }
    int c0=m0+kg*4;
    #pragma unroll
    for(int r=0;r<4;r++){
        float sm=0.f;
        #pragma unroll
        for(int nt=0;nt<8;nt++){ float v=o[nt][r]; if(nt==7&&l15>8) v=0.f; sm+=v; }
        sm+=__shfl_xor(sm,1); sm+=__shfl_xor(sm,2); sm+=__shfl_xor(sm,4); sm+=__shfl_xor(sm,8);
        if(l15==0) fl[c0+r]=sm*(1.f/121.f);
    }
    __syncthreads();
    if(t<C_){
        float a=bgf[t];
        #pragma unroll 8
        for(int k=0;k<C_;k++) a+=wgT[k*C_+t]*fl[k];
        fl[C_+t]=1.f/(1.f+__expf(-a));
    }
    __syncthreads();
    float gg[4];
    #pragma unroll
    for(int r=0;r<4;r++) gg[r]=fl[C_+c0+r];
    #pragma unroll
    for(int nt=0;nt<8;nt++){
        #pragma unroll
        for(int r=0;r<4;r++) res[nt][r]+=w1m*o[nt][r]*gg[r];
    }
}

// ---------- fused intra + left-msg + right-msg per (s,b), 512 threads ----------
// comb = w*(alpha*attn(h)+h) + (1-w)*(m_l*g_l*maskL + m_r*g_r*maskR), written ONCE (coalesced via LDS)
__global__ __launch_bounds__(512) void attn_all(
    bf16t* __restrict__ comb, const bf16t* __restrict__ hT,
    const bf16t* __restrict__ WqT, const bf16t* __restrict__ WkT, const bf16t* __restrict__ WvT,
    const float* __restrict__ bq, const float* __restrict__ bk, const float* __restrict__ bv,
    const bf16t* __restrict__ W2T, const float* __restrict__ b2l, const float* __restrict__ b2r,
    const float* __restrict__ wgT, const float* __restrict__ bgf,
    const float* __restrict__ alphap, const float* __restrict__ wp)
{
    __shared__ bf16t LA[128*136];
    __shared__ bf16t LB[128*136];
    __shared__ float fl[256];
    int sb=blockIdx.x, t=threadIdx.x, lane=t&63, w=t>>6;
    int l15=lane&15, kg=lane>>4;
    const bf16t* hp=hT+(size_t)sb*CP_;
    int ocr=w>>2, pcr=w&3;
    int m0=w*16;
    bf16x8 hreg[4][2];
    #pragma unroll
    for(int kc=0;kc<4;kc++){
        #pragma unroll
        for(int nt=0;nt<2;nt++)
            hreg[kc][nt]=*(const bf16x8*)(hp+(size_t)(pcr*32+nt*16+l15)*C_+kc*32+kg*8);
    }
    bf16x8 areg[4];
    #pragma unroll
    for(int kc=0;kc<4;kc++)
        areg[kc]=*(const bf16x8*)(hp+(size_t)(m0+l15)*C_+kc*32+kg*8);

    f32x4 acc[4][2];
    // q -> LA [p][c]
    gemm24r(acc,WqT,hreg,ocr,l15,kg);
    #pragma unroll
    for(int mt=0;mt<4;mt++){
        int oc0=ocr*64+mt*16+kg*4;
        #pragma unroll
        for(int nt=0;nt<2;nt++){
            int p=pcr*32+nt*16+l15;
            us4 pk;
            #pragma unroll
            for(int r=0;r<4;r++) pk[r]=f2bu(acc[mt][nt][r]+bq[oc0+r]);
            *(us4*)(LA+p*136+oc0)=pk;
        }
    }
    // k -> LB [p][c]
    gemm24r(acc,WkT,hreg,ocr,l15,kg);
    #pragma unroll
    for(int mt=0;mt<4;mt++){
        int oc0=ocr*64+mt*16+kg*4;
        #pragma unroll
        for(int nt=0;nt<2;nt++){
            int p=pcr*32+nt*16+l15;
            us4 pk;
            #pragma unroll
            for(int r=0;r<4;r++) pk[r]=f2bu(acc[mt][nt][r]+bk[oc0+r]);
            *(us4*)(LB+p*136+oc0)=pk;
        }
    }
    __syncthreads();
    // QK^T
    f32x4 s[8];
    #pragma unroll
    for(int nt=0;nt<8;nt++) s[nt]=(f32x4){0.f,0.f,0.f,0.f};
    #pragma unroll
    for(int kc=0;kc<4;kc++){
        bf16x8 a=*(const bf16x8*)(LA+(size_t)(m0+l15)*136+kc*32+kg*8);
        #pragma unroll
        for(int nt=0;nt<8;nt++){
            bf16x8 b=*(const bf16x8*)(LB+(size_t)(nt*16+l15)*136+kc*32+kg*8);
            s[nt]=__builtin_amdgcn_mfma_f32_16x16x32_bf16(a,b,s[nt],0,0,0);
        }
    }
    const float scale=0.08838834764831845f;
    #pragma unroll
    for(int nt=0;nt<8;nt++){
        #pragma unroll
        for(int r=0;r<4;r++) s[nt][r]*=scale;
    }
    if(l15>=9){
        #pragma unroll
        for(int r=0;r<4;r++) s[7][r]=-3.0e38f;
    }
    #pragma unroll
    for(int r=0;r<4;r++){
        float mx=s[0][r];
        #pragma unroll
        for(int nt=1;nt<8;nt++) mx=fmaxf(mx,s[nt][r]);
        #pragma unroll
        for(int o=1;o<16;o<<=1) mx=fmaxf(mx,__shfl_xor(mx,o));
        float sm=0.f;
        #pragma unroll
        for(int nt=0;nt<8;nt++){ float e=__expf(s[nt][r]-mx); s[nt][r]=e; sm+=e; }
        #pragma unroll
        for(int o=1;o<16;o<<=1) sm+=__shfl_xor(sm,o);
        float rs=1.f/sm;
        #pragma unroll
        for(int nt=0;nt<8;nt++) s[nt][r]*=rs;
    }
    __syncthreads();   // q/k reads done
    // v -> LA natural [c][p]; P -> LB [p][j]
    gemm24r(acc,WvT,hreg,ocr,l15,kg);
    #pragma unroll
    for(int mt=0;mt<4;mt++){
        int oc0=ocr*64+mt*16+kg*4;
        #pragma unroll
        for(int nt=0;nt<2;nt++){
            int p=pcr*32+nt*16+l15;
            #pragma unroll
            for(int r=0;r<4;r++)
                LA[(oc0+r)*136+p]=__float2bfloat16(p<P_? acc[mt][nt][r]+bv[oc0+r] : 0.f);
        }
    }
    #pragma unroll
    for(int r=0;r<4;r++){
        int pr=m0+kg*4+r;
        #pragma unroll
        for(int nt=0;nt<8;nt++) LB[pr*136+nt*16+l15]=__float2bfloat16(s[nt][r]);
    }
    __syncthreads();
    // PV
    f32x4 res[8];
    #pragma unroll
    for(int nt=0;nt<8;nt++) res[nt]=(f32x4){0.f,0.f,0.f,0.f};
    #pragma unroll
    for(int jc=0;jc<4;jc++){
        bf16x8 a=*(const bf16x8*)(LA+(size_t)(m0+l15)*136+jc*32+kg*8);
        #pragma unroll
        for(int nt=0;nt<8;nt++){
            bf16x8 b=*(const bf16x8*)(LB+(size_t)(nt*16+l15)*136+jc*32+kg*8);
            res[nt]=__builtin_amdgcn_mfma_f32_16x16x32_bf16(a,b,res[nt],0,0,0);
        }
    }
    float al=*alphap, wv=*wp, w1m=1.f-wv;
    int c0=m0+kg*4;
    // res = w*(alpha*PV + h)
    #pragma unroll
    for(int nt=0;nt<8;nt++){
        int p=nt*16+l15;
        int pc=(p<P_)?p:(P_-1);
        us4 hv=*(const us4*)(hp+(size_t)pc*C_+c0);
        #pragma unroll
        for(int r=0;r<4;r++) res[nt][r]=wv*(al*res[nt][r]+b2f(hv[r]));
    }
    // message phases (block-uniform branches)
    if(sb>=B_)
        msg_phase(res,hT,sb,-B_,W2T,b2l,wgT,bgf,w1m,areg,LA,LB,fl,t,w,l15,kg,ocr,pcr);
    if(sb<SBn-B_)
        msg_phase(res,hT,sb, B_,W2T,b2r,wgT,bgf,w1m,areg,LA,LB,fl,t,w,l15,kg,ocr,pcr);
    // coalesced comb write: stage [p][128c] in LA, copy out contiguous
    __syncthreads();   // PV-phase LDS reads done
    unsigned short* tl=(unsigned short*)LA;
    #pragma unroll
    for(int nt=0;nt<8;nt++){
        int p=nt*16+l15;
        if(p>=P_) continue;
        us4 pk;
        #pragma unroll
        for(int r=0;r<4;r++) pk[r]=f2bu(res[nt][r]);
        *(us4*)(tl+p*C_+c0)=pk;
    }
    __syncthreads();
    bf16t* ob=comb+(size_t)sb*CP_;
    for(int j=t;j<1936;j+=512)
        *(bf16x8*)(ob+j*8)=*(const bf16x8*)(tl+j*8);
}

// ---------- shared MFMA-step macros for 3x3 convs ----------
#define LOADA3(bidx, widx) { \
    _Pragma("unroll") \
    for(int mt=0;mt<4;mt++) abuf[bidx][mt]=*(const bf16x8*)(Wt+(size_t)(widx)*(OC*32)+mt*512+base_lane); }
#define STEP3(lbase, bidx, doff) { \
    bf16x8 bb[4]; \
    _Pragma("unroll") \
    for(int nt=0;nt<4;nt++) bb[nt]=*(const bf16x8*)((lbase)+boff[nt]+(doff)); \
    __builtin_amdgcn_s_setprio(1); \
    _Pragma("unroll") \
    for(int mt=0;mt<4;mt++){ \
        _Pragma("unroll") \
        for(int nt=0;nt<4;nt++) \
            acc[mt][nt]=__builtin_amdgcn_mfma_f32_16x16x32_bf16(abuf[bidx][mt],bb[nt],acc[mt][nt],0,0,0); } \
    __builtin_amdgcn_s_setprio(0); }

// ---------- zr conv: 512 threads, waves 0-3 -> Z (ocb 0), waves 4-7 -> RH (ocb 128) ----------
#define SLOADZ(stg) { \
    const bf16t* ssrc=(((stg)<2)? in0T:in1T)+(size_t)sb*CP_+((stg)&1)*64; \
    sreg[0]=*(const bf16x8*)(ssrc+(size_t)sp0*C_+(t&7)*8); \
    if(sv1) sreg[1]=*(const bf16x8*)(ssrc+(size_t)sp1*C_+(t&7)*8); }
#define SWRITEZ(lbase) { \
    *(bf16x8*)((lbase)+spix0*72+(t&7)*8)=sreg[0]; \
    if(sv1) *(bf16x8*)((lbase)+spix1*72+(t&7)*8)=sreg[1]; }

__global__ __launch_bounds__(512) void conv3_zr(
    bf16t* __restrict__ o0, bf16t* __restrict__ o1,
    const bf16t* __restrict__ in0T, const bf16t* __restrict__ in1T,
    const bf16t* __restrict__ Wt, const float* __restrict__ bias,
    const bf16t* __restrict__ hTb)
{
    constexpr int OC=256;
    __shared__ bf16t lin[2*12176];
    int sb=blockIdx.x;
    int t=threadIdx.x, lane=t&63, w=t>>6;
    int ocb=(w>=4)?128:0; int w2=w&3;
    int ocr=w2>>1, pcr=w2&1, l15=lane&15, kg=lane>>4;
    int boff[4]; bool pv_[4];
    #pragma unroll
    for(int nt=0;nt<4;nt++){
        int p=pcr*64+nt*16+l15;
        pv_[nt]=(p<P_); int pc=pv_[nt]?p:(P_-1);
        boff[nt]=((pc/11)*13+(pc%11))*72+kg*8;
    }
    f32x4 acc[4][4];
    #pragma unroll
    for(int i=0;i<4;i++){
        #pragma unroll
        for(int j=0;j<4;j++) acc[i][j]=(f32x4){0.f,0.f,0.f,0.f};
    }
    int base_lane=(ocb+ocr*64+l15)*32+kg*8;
    bf16x8 abuf[4][4];
    bf16x8 sreg[2];
    bool sv1=((t+512)<968);
    int sp0=t>>3, sp1=(t+512)>>3;
    if(sp1>120) sp1=120;
    int spix0=(sp0/11+1)*13+(sp0%11)+1;
    int spix1=(sp1/11+1)*13+(sp1%11)+1;
    LOADA3(0,0); LOADA3(1,1); LOADA3(2,8); LOADA3(3,9);
    SLOADZ(0);
    {
        bf16x8 z;
        #pragma unroll
        for(int e=0;e<8;e++) z[e]=0;
        for(int i=t;i<768;i+=512){
            int half=i>=384; int i2=i-half*384;
            int bi=i2>>3, cc=(i2&7)*8;
            int pix;
            if(bi<13) pix=bi;
            else if(bi<26) pix=156+(bi-13);
            else { int j2=bi-26; pix=(1+(j2>>1))*13+((j2&1)?12:0); }
            *(bf16x8*)(lin+half*12176+pix*72+cc)=z;
        }
    }
    SWRITEZ(lin);
    __syncthreads();
    #pragma unroll
    for(int st=0; st<4; ++st){
        if(st<3) SLOADZ(st+1);
        bf16t* lbase=lin+(st&1)*12176;
        #pragma unroll
        for(int k=0;k<18;k++){
            int s=st*18+k;
            int tap=k>>1, l=k&1;
            int doff=((tap/3)*13+(tap%3))*72+l*32;
            STEP3(lbase, s&3, doff);
            if(s<68){
                int s4=s+4, st4=s4/18, k4=s4-st4*18, tap4=k4>>1, l4=k4&1;
                LOADA3(s&3, tap4*8+st4*2+l4);
            }
        }
        if(st<3){ SWRITEZ(lin+((st+1)&1)*12176); }
        __syncthreads();
    }
    // coalesced epilogue: stage Z then RH as [p][128c] in lin, copy out contiguous
    unsigned short* tl=(unsigned short*)lin;
    if(ocb==0){
        #pragma unroll
        for(int mt=0;mt<4;mt++){
            int ocl=ocr*64+mt*16+kg*4;
            #pragma unroll
            for(int nt=0;nt<4;nt++){
                if(!pv_[nt]) continue;
                int p=pcr*64+nt*16+l15;
                us4 pk;
                #pragma unroll
                for(int r=0;r<4;r++){ float a=acc[mt][nt][r]+bias[ocl+r]; pk[r]=f2bu(1.f/(1.f+__expf(-a))); }
                *(us4*)(tl+p*C_+ocl)=pk;
            }
        }
    }
    __syncthreads();
    {
        bf16t* zb=o0+(size_t)sb*CP_;
        for(int j=t;j<1936;j+=512)
            *(bf16x8*)(zb+j*8)=*(const bf16x8*)(tl+j*8);
    }
    __syncthreads();
    if(ocb==128){
        #pragma unroll
        for(int mt=0;mt<4;mt++){
            int ocl=ocr*64+mt*16+kg*4;
            #pragma unroll
            for(int nt=0;nt<4;nt++){
                if(!pv_[nt]) continue;
                int p=pcr*64+nt*16+l15;
                size_t tb=(size_t)sb*CP_+(size_t)p*C_+ocl;
                us4 hv=*(const us4*)(hTb+tb);
                us4 pk;
                #pragma unroll
                for(int r=0;r<4;r++){ float a=acc[mt][nt][r]+bias[128+ocl+r]; float sg=1.f/(1.f+__expf(-a)); pk[r]=f2bu(sg*b2f(hv[r])); }
                *(us4*)(tl+p*C_+ocl)=pk;
            }
        }
    }
    __syncthreads();
    {
        bf16t* rb=o1+(size_t)sb*CP_;
        for(int j=t;j<1936;j+=512)
            *(bf16x8*)(rb+j*8)=*(const bf16x8*)(tl+j*8);
    }
}

// ---------- hhat conv + GRU-combine + LayerNorm: 256 threads ----------
#define SLOADH(stg) { \
    const bf16t* ssrc=(((stg)<2)? in0T:in1T)+(size_t)sb*CP_+((stg)&1)*64; \
    sreg[0]=*(const bf16x8*)(ssrc+(size_t)(t>>3)*C_+(t&7)*8); \
    sreg[1]=*(const bf16x8*)(ssrc+(size_t)((t+256)>>3)*C_+(t&7)*8); \
    if(sv2) sreg[2]=*(const bf16x8*)(ssrc+(size_t)sp2*C_+(t&7)*8); \
    if(sv3) sreg[3]=*(const bf16x8*)(ssrc+(size_t)sp3*C_+(t&7)*8); }
#define SWRITEH(lbase) { \
    *(bf16x8*)((lbase)+spix0*72+(t&7)*8)=sreg[0]; \
    *(bf16x8*)((lbase)+spix1*72+(t&7)*8)=sreg[1]; \
    if(sv2) *(bf16x8*)((lbase)+spix2*72+(t&7)*8)=sreg[2]; \
    if(sv3) *(bf16x8*)((lbase)+spix3*72+(t&7)*8)=sreg[3]; }

__global__ __launch_bounds__(256) void conv3_hh(
    bf16t* __restrict__ o0,
    const bf16t* __restrict__ in0T, const bf16t* __restrict__ in1T,
    const bf16t* __restrict__ Wt, const float* __restrict__ bias,
    const bf16t* __restrict__ zT, const bf16t* __restrict__ hTb,
    const float* __restrict__ gamT, const float* __restrict__ betT)
{
    constexpr int OC=128;
    __shared__ bf16t lin[2*12176];
    __shared__ float red[8];
    int sb=blockIdx.x;
    int t=threadIdx.x, lane=t&63, w=t>>6;
    int ocr=w>>1, pcr=w&1, l15=lane&15, kg=lane>>4;
    int boff[4]; bool pv_[4];
    #pragma unroll
    for(int nt=0;nt<4;nt++){
        int p=pcr*64+nt*16+l15;
        pv_[nt]=(p<P_); int pc=pv_[nt]?p:(P_-1);
        boff[nt]=((pc/11)*13+(pc%11))*72+kg*8;
    }
    f32x4 acc[4][4];
    #pragma unroll
    for(int i=0;i<4;i++){
        #pragma unroll
        for(int j=0;j<4;j++) acc[i][j]=(f32x4){0.f,0.f,0.f,0.f};
    }
    int base_lane=(ocr*64+l15)*32+kg*8;
    bf16x8 abuf[4][4];
    bf16x8 sreg[4];
    bool sv2=((t+512)<968), sv3=((t+768)<968);
    int sp0=t>>3, sp1=(t+256)>>3, sp2=(t+512)>>3, sp3=(t+768)>>3;
    if(sp2>120) sp2=120;
    if(sp3>120) sp3=120;
    int spix0=(sp0/11+1)*13+(sp0%11)+1;
    int spix1=(sp1/11+1)*13+(sp1%11)+1;
    int spix2=(sp2/11+1)*13+(sp2%11)+1;
    int spix3=(sp3/11+1)*13+(sp3%11)+1;
    LOADA3(0,0); LOADA3(1,1); LOADA3(2,8); LOADA3(3,9);
    SLOADH(0);
    {
        bf16x8 z;
        #pragma unroll
        for(int e=0;e<8;e++) z[e]=0;
        for(int i=t;i<768;i+=256){
            int half=i>=384; int i2=i-half*384;
            int bi=i2>>3, cc=(i2&7)*8;
            int pix;
            if(bi<13) pix=bi;
            else if(bi<26) pix=156+(bi-13);
            else { int j2=bi-26; pix=(1+(j2>>1))*13+((j2&1)?12:0); }
            *(bf16x8*)(lin+half*12176+pix*72+cc)=z;
        }
    }
    SWRITEH(lin);
    __syncthreads();
    #pragma unroll
    for(int st=0; st<4; ++st){
        if(st<3) SLOADH(st+1);
        bf16t* lbase=lin+(st&1)*12176;
        #pragma unroll
        for(int k=0;k<18;k++){
            int s=st*18+k;
            int tap=k>>1, l=k&1;
            int doff=((tap/3)*13+(tap%3))*72+l*32;
            STEP3(lbase, s&3, doff);
            if(s<68){
                int s4=s+4, st4=s4/18, k4=s4-st4*18, tap4=k4>>1, l4=k4&1;
                LOADA3(s&3, tap4*8+st4*2+l4);
            }
        }
        if(st<3){ SWRITEH(lin+((st+1)&1)*12176); }
        __syncthreads();
    }
    float ls=0.f, ls2=0.f;
    #pragma unroll
    for(int mt=0;mt<4;mt++){
        int ocl=ocr*64+mt*16+kg*4;
        #pragma unroll
        for(int nt=0;nt<4;nt++){
            if(!pv_[nt]) continue;
            int p=pcr*64+nt*16+l15;
            size_t tb=(size_t)sb*CP_+(size_t)p*C_+ocl;
            us4 hv=*(const us4*)(hTb+tb);
            us4 zv=*(const us4*)(zT+tb);
            us4 pk;
            #pragma unroll
            for(int r=0;r<4;r++){
                float a=acc[mt][nt][r]+bias[ocl+r];
                float ht=tanhf(a);
                float z=b2f(zv[r]), h=b2f(hv[r]);
                unsigned short u=f2bu((1.f-z)*h+z*ht+h);
                pk[r]=u;
                float nr=b2f(u); ls+=nr; ls2+=nr*nr;
            }
            *(us4*)((unsigned short*)lin + p*C_+ocl)=pk;
        }
    }
    #pragma unroll
    for(int o=32;o;o>>=1){ ls+=__shfl_xor(ls,o); ls2+=__shfl_xor(ls2,o); }
    if(lane==0){ red[w]=ls; red[4+w]=ls2; }
    __syncthreads();
    float Sx=red[0]+red[1]+red[2]+red[3];
    float Sx2=red[4]+red[5]+red[6]+red[7];
    float mu=Sx*(1.f/(float)CP_);
    float var=Sx2*(1.f/(float)CP_)-mu*mu;
    float rstd=rsqrtf(var+1e-5f);
    bf16t* ho=o0+(size_t)sb*CP_;
    const unsigned short* tl=(const unsigned short*)lin;
    for(int j=t;j<1936;j+=256){
        int base=j*8;
        bf16x8 ovec;
        #pragma unroll
        for(int e=0;e<8;e++){
            float v=(b2f(tl[base+e])-mu)*rstd*gamT[base+e]+betT[base+e];
            ovec[e]=(short)f2bu(v);
        }
        *(bf16x8*)(ho+base)=ovec;
    }
}

// ---------- final: hT [p][c] -> natural [c][p] output ----------
__global__ __launch_bounds__(256) void finalT_kernel(void* __restrict__ fout, const bf16t* __restrict__ hT, const int* __restrict__ flag){
    __shared__ bf16t tl[CP_];
    int sb=blockIdx.x, t=threadIdx.x, f=*flag;
    for(int i=t;i<CP_;i+=256) tl[i]=hT[(size_t)sb*CP_+i];
    __syncthreads();
    for(int i=t;i<CP_;i+=256){
        int c=i/P_, p=i-c*P_;
        float v=ldb(tl+p*C_+c);
        size_t oi=(size_t)sb*CP_+i;
        if(f) ((float*)fout)[oi]=v;
        else  ((bf16t*)fout)[oi]=__float2bfloat16(v);
    }
}

extern "C" void kernel_launch(void* const* d_in, const int* in_sizes, int n_in,
                              void* d_out, int out_size, void* d_ws, size_t ws_size,
                              hipStream_t stream) {
    (void)in_sizes; (void)n_in; (void)out_size;
    char* base=(char*)d_ws;
    size_t off=0;
    auto alloc=[&](size_t bytes){ void* p=base+off; off+=(bytes+255)&~(size_t)255; return p; };
    bf16t* b1=(bf16t*)alloc((size_t)NEl*2+8192);          // hT
    bf16t* b2=(bf16t*)alloc((size_t)NEl*2+8192);          // comb
    bf16t* b3=(bf16t*)alloc((size_t)NEl*2+8192);          // RH
    bf16t* b4=(bf16t*)d_out;                              // Z / final
    bf16t* wqT=(bf16t*)alloc(16384*2);
    bf16t* wkT=(bf16t*)alloc(16384*2);
    bf16t* wvT=(bf16t*)alloc(16384*2);
    bf16t* w2T=(bf16t*)alloc(16384*2);
    bf16t* wzrT=(bf16t*)alloc((size_t)589824*2);
    bf16t* whT =(bf16t*)alloc((size_t)294912*2);
    float* W2f=(float*)alloc(16384*4);
    float* b2l=(float*)alloc(128*4); float* b2r=(float*)alloc(128*4);
    float* bqf=(float*)alloc(128*4); float* bkf=(float*)alloc(128*4); float* bvf=(float*)alloc(128*4);
    float* bzrf=(float*)alloc(256*4); float* bhf=(float*)alloc(128*4);
    float* gamT=(float*)alloc(15488*4); float* betT=(float*)alloc(15488*4);
    float* wgTf=(float*)alloc(16384*4); float* bgf2=(float*)alloc(128*4);
    float* alphaf=(float*)alloc(4); float* weightf=(float*)alloc(4);
    int* flag=(int*)alloc(4);
    if(ws_size<off) return;  // ~100MB needed

    detect_kernel<<<1,64,0,stream>>>((const unsigned short*)d_in[0],flag);
    cvtT_kernel<<<SBn,256,0,stream>>>(b1,d_in[0],flag);
    prep_w1t<1><<<64,256,0,stream>>>(wqT,d_in[1],flag);
    cvt_kernel<<<1,128,0,stream>>>(bqf,d_in[2],128,flag);
    prep_w1t<1><<<64,256,0,stream>>>(wkT,d_in[3],flag);
    cvt_kernel<<<1,128,0,stream>>>(bkf,d_in[4],128,flag);
    prep_w1t<1><<<64,256,0,stream>>>(wvT,d_in[5],flag);
    cvt_kernel<<<1,128,0,stream>>>(bvf,d_in[6],128,flag);
    cvt_kernel<<<1,64,0,stream>>>(alphaf,d_in[7],1,flag);
    prep_msg_kernel<<<C_,C_,0,stream>>>(W2f,b2l,b2r,d_in[10],d_in[8],d_in[9],flag);
    prep_w1t<0><<<64,256,0,stream>>>(w2T,W2f,flag);
    cvt_kernel<<<1,64,0,stream>>>(weightf,d_in[11],1,flag);
    prep_wgt<<<64,256,0,stream>>>(wgTf,bgf2,d_in[12],d_in[13],flag);
    prep_w3t<<<(256*2304+255)/256,256,0,stream>>>(wzrT,d_in[14],flag,256);
    cvt_kernel<<<1,256,0,stream>>>(bzrf,d_in[15],256,flag);
    prep_w3t<<<(128*2304+255)/256,256,0,stream>>>(whT,d_in[16],flag,128);
    cvt_kernel<<<1,128,0,stream>>>(bhf,d_in[17],128,flag);
    prep_gbt<<<(CP_+255)/256,256,0,stream>>>(gamT,betT,d_in[18],d_in[19],flag);

    for(int it=0; it<3; ++it){
        // comb(b2) = w*(alpha*attn(h)+h) + (1-w)*(msgL+msgR), one kernel, coalesced write
        attn_all<<<SBn,512,0,stream>>>(b2,b1,wqT,wkT,wvT,bqf,bkf,bvf,
                                       w2T,b2l,b2r,wgTf,bgf2,alphaf,weightf);
        // GRU: zr([comb|h]) -> Z->b4, RH->b3 (coalesced epilogue)
        conv3_zr<<<SBn,512,0,stream>>>(b4,b3,b2,b1,wzrT,bzrf,b1);
        // hhat([comb|RH]) + GRU combine + LN -> new hT (b1)
        conv3_hh<<<SBn,256,0,stream>>>(b1,b2,b3,whT,bhf,b4,b1,gamT,betT);
    }
    finalT_kernel<<<SBn,256,0,stream>>>(d_out,b1,flag);
}

// Round 13
// 1386.887 us; speedup vs baseline: 15.6793x; 1.0223x over previous
//
#include <hip/hip_runtime.h>
#include <hip/hip_bf16.h>

// GraphProcessor: S=16,B=64,C=128,H=W=11,P=121, 3 iterations.
// Transposed [sb][p][128ch] bf16 storage; MFMA everywhere; deep fusion.
// This round: small-tile conv3 (32oc x 64p per wave) -> ~100 regs/wave -> 2x occupancy.
#define S_   16
#define B_   64
#define SBn  1024
#define C_   128
#define P_   121
#define CP_  15488
static const long NEl = 15859712L; // SBn*CP_

typedef __hip_bfloat16 bf16t;
typedef __attribute__((ext_vector_type(8))) short bf16x8;
typedef __attribute__((ext_vector_type(4))) float f32x4;
typedef __attribute__((ext_vector_type(4))) unsigned short us4;

__device__ __forceinline__ float ldb(const bf16t* p){ return __bfloat162float(*p); }
__device__ __forceinline__ float b2f(unsigned short u){ unsigned x=((unsigned)u)<<16; float f; __builtin_memcpy(&f,&x,4); return f; }
__device__ __forceinline__ unsigned short f2bu(float v){ __hip_bfloat16 b=__float2bfloat16(v); unsigned short u; __builtin_memcpy(&u,&b,2); return u; }
__device__ __forceinline__ float ldin(const void* s, long i, int f){
    return f ? ((const float*)s)[i] : b2f(((const unsigned short*)s)[i]);
}

// ---------- dtype detect: flag=1 if inputs are f32, 0 if bf16 ----------
__global__ void detect_kernel(const unsigned short* __restrict__ x, int* __restrict__ flag){
    if(blockIdx.x==0 && threadIdx.x==0){
        int crazy=0;
        for(int i=0;i<512;i++){
            unsigned e=(x[i]>>7)&0xFF;
            if(e!=0 && (e<64 || e>191)) crazy++;
        }
        *flag=(crazy>40)?1:0;
    }
}

// ---------- raw input -> f32 ----------
__global__ void cvt_kernel(float* __restrict__ dst, const void* __restrict__ src, long n, const int* __restrict__ flag){
    long i=(long)blockIdx.x*blockDim.x+threadIdx.x;
    long st=(long)gridDim.x*blockDim.x;
    int f=*flag;
    for(;i<n;i+=st) dst[i]=ldin(src,i,f);
}

// ---------- x [sb][c][p] -> hT [sb][p][c] bf16, LDS-tiled (coalesced both sides) ----------
__global__ __launch_bounds__(256) void cvtT_kernel(bf16t* __restrict__ hT, const void* __restrict__ x, const int* __restrict__ flag){
    __shared__ bf16t tl[CP_];   // [c][p]
    int sb=blockIdx.x, t=threadIdx.x; int f=*flag;
    for(int i=t;i<CP_;i+=256)
        tl[i]=__float2bfloat16(ldin(x,(long)sb*CP_+i,f));
    __syncthreads();
    bf16t* ho=hT+(size_t)sb*CP_;
    for(int j=t;j<CP_;j+=256){
        int p=j>>7, c=j&127;
        ho[j]=tl[c*P_+p];
    }
}

// ---------- fold w_lin @ w_msg[:, :C] into W2 (f32), edge bias into b2l/b2r ----------
__global__ __launch_bounds__(128) void prep_msg_kernel(float* __restrict__ W2, float* __restrict__ b2l, float* __restrict__ b2r,
        const void* __restrict__ wlin, const void* __restrict__ wmsg, const void* __restrict__ bmsg, const int* __restrict__ flag){
    int d=blockIdx.x, c=threadIdx.x; int f=*flag;
    float acc=0.f;
    for(int o2=0;o2<C_;o2++) acc += ldin(wlin,(long)d*C_+o2,f)*ldin(wmsg,(long)o2*(C_+1)+c,f);
    W2[d*C_+c]=acc;
    if(c<2){
        float e=(c==0)?1.f:-1.f; float a=0.f;
        for(int o2=0;o2<C_;o2++) a += ldin(wlin,(long)d*C_+o2,f)*(ldin(bmsg,o2,f)+e*ldin(wmsg,(long)o2*(C_+1)+C_,f));
        if(c==0) b2l[d]=a; else b2r[d]=a;
    }
}

// ---------- 1x1 weight [oc][128ic] -> tiled bf16 [icb(4)][oc(128)][32] ----------
template<int RAW>
__global__ void prep_w1t(bf16t* __restrict__ dst, const void* __restrict__ src, const int* __restrict__ flag){
    int idx=blockIdx.x*blockDim.x+threadIdx.x;
    if(idx>=16384) return;
    int r=idx&31, oc=(idx>>5)&127, icb=idx>>12;
    float v = RAW? ldin(src,(long)oc*C_+icb*32+r,*flag) : ((const float*)src)[(long)oc*C_+icb*32+r];
    dst[idx]=__float2bfloat16(v);
}

// ---------- 3x3 weight [oc][256ic][3][3] -> tiled bf16 [tap][icb(8)][oc][32] ----------
__global__ void prep_w3t(bf16t* __restrict__ dst, const void* __restrict__ src, const int* __restrict__ flag, int OC){
    int idx=blockIdx.x*blockDim.x+threadIdx.x;
    int tot=OC*2304;
    if(idx>=tot) return;
    int r=idx&31; int rest=idx>>5; int oc=rest%OC; int g2=rest/OC; int icb=g2&7, tap=g2>>3;
    float v=ldin(src,((long)(oc*256+icb*32+r))*9+tap,*flag);
    dst[idx]=__float2bfloat16(v);
}

// ---------- gamma/beta [c][p] -> transposed f32 [p][c] ----------
__global__ void prep_gbt(float* __restrict__ gamT, float* __restrict__ betT,
                         const void* __restrict__ gam, const void* __restrict__ bet, const int* __restrict__ flag){
    int idx=blockIdx.x*blockDim.x+threadIdx.x;
    if(idx>=CP_) return;
    int c=idx/P_, p=idx-c*P_; int f=*flag;
    gamT[p*C_+c]=ldin(gam,idx,f);
    betT[p*C_+c]=ldin(bet,idx,f);
}

// ---------- w_gate [c][k] -> transposed f32 [k][c]; b_gate -> f32 ----------
__global__ void prep_wgt(float* __restrict__ wgT, float* __restrict__ bg2,
                         const void* __restrict__ wg, const void* __restrict__ bg, const int* __restrict__ flag){
    int idx=blockIdx.x*blockDim.x+threadIdx.x;
    int f=*flag;
    if(idx<16384){ int k=idx>>7, c=idx&127; wgT[idx]=ldin(wg,(long)c*C_+k,f); }
    if(idx<128) bg2[idx]=ldin(bg,idx,f);
}

// ---------- 128x128x128 GEMM tile, 8 waves (2 ocr x 4 pcr), B from registers ----------
__device__ __forceinline__ void gemm24r(f32x4 (&acc)[4][2],
    const bf16t* __restrict__ Wt, const bf16x8 (&hreg)[4][2],
    int ocr,int l15,int kg)
{
    #pragma unroll
    for(int i=0;i<4;i++){
        #pragma unroll
        for(int j=0;j<2;j++) acc[i][j]=(f32x4){0.f,0.f,0.f,0.f};
    }
    #pragma unroll
    for(int kc=0;kc<4;kc++){
        bf16x8 a[4];
        #pragma unroll
        for(int mt=0;mt<4;mt++) a[mt]=*(const bf16x8*)(Wt+((size_t)(kc*C_+ocr*64+mt*16+l15))*32+kg*8);
        #pragma unroll
        for(int mt=0;mt<4;mt++){
            #pragma unroll
            for(int nt=0;nt<2;nt++)
                acc[mt][nt]=__builtin_amdgcn_mfma_f32_16x16x32_bf16(a[mt],hreg[kc][nt],acc[mt][nt],0,0,0);
        }
    }
}

// ---------- one message-direction phase: yy=W2@h_shift; m=softmax(h yy^T) yy; gate; res += (1-w)*m*g ----------
__device__ __forceinline__ void msg_phase(
    f32x4 (&res)[8], const bf16t* __restrict__ hT, int sb, int shift,
    const bf16t* __restrict__ W2T, const float* __restrict__ b2e,
    const float* __restrict__ wgT, const float* __restrict__ bgf, float w1m,
    const bf16x8 (&areg)[4],
    bf16t* LA, bf16t* LB, float* fl,
    int t,int w,int l15,int kg,int ocr,int pcr)
{
    __syncthreads();   // previous phase's LDS reads complete
    const bf16t* hsp=hT+(size_t)(sb+shift)*CP_;
    bf16x8 hregS[4][2];
    #pragma unroll
    for(int kc=0;kc<4;kc++){
        #pragma unroll
        for(int nt=0;nt<2;nt++)
            hregS[kc][nt]=*(const bf16x8*)(hsp+(size_t)(pcr*32+nt*16+l15)*C_+kc*32+kg*8);
    }
    f32x4 acc[4][2];
    gemm24r(acc,W2T,hregS,ocr,l15,kg);
    #pragma unroll
    for(int mt=0;mt<4;mt++){
        int oc0=ocr*64+mt*16+kg*4;
        #pragma unroll
        for(int nt=0;nt<2;nt++){
            int p=pcr*32+nt*16+l15;
            us4 pk;
            #pragma unroll
            for(int r=0;r<4;r++){
                float v=acc[mt][nt][r]+b2e[oc0+r];
                pk[r]=f2bu(v);
                LB[(oc0+r)*136+p]=__float2bfloat16(p<P_? v : 0.f);
            }
            *(us4*)(LA+p*136+oc0)=pk;
        }
    }
    __syncthreads();
    int m0=w*16;
    f32x4 s[8];
    #pragma unroll
    for(int nt=0;nt<8;nt++) s[nt]=(f32x4){0.f,0.f,0.f,0.f};
    #pragma unroll
    for(int kc=0;kc<4;kc++){
        #pragma unroll
        for(int nt=0;nt<8;nt++){
            bf16x8 b=*(const bf16x8*)(LA+(size_t)(nt*16+l15)*136+kc*32+kg*8);
            s[nt]=__builtin_amdgcn_mfma_f32_16x16x32_bf16(areg[kc],b,s[nt],0,0,0);
        }
    }
    if(l15>=9){
        #pragma unroll
        for(int r=0;r<4;r++) s[7][r]=-3.0e38f;
    }
    #pragma unroll
    for(int r=0;r<4;r++){
        float mx=s[0][r];
        #pragma unroll
        for(int nt=1;nt<8;nt++) mx=fmaxf(mx,s[nt][r]);
        #pragma unroll
        for(int o=1;o<16;o<<=1) mx=fmaxf(mx,__shfl_xor(mx,o));
        float sm=0.f;
        #pragma unroll
        for(int nt=0;nt<8;nt++){ float e=__expf(s[nt][r]-mx); s[nt][r]=e; sm+=e; }
        #pragma unroll
        for(int o=1;o<16;o<<=1) sm+=__shfl_xor(sm,o);
        float rs=1.f/sm;
        #pragma unroll
        for(int nt=0;nt<8;nt++) s[nt][r]*=rs;
    }
    __syncthreads();   // yyT reads done
    #pragma unroll
    for(int r=0;r<4;r++){
        int pr=m0+kg*4+r;
        #pragma unroll
        for(int nt=0;nt<8;nt++) LA[pr*136+nt*16+l15]=__float2bfloat16(s[nt][r]);
    }
    __syncthreads();
    f32x4 o[8];
    #pragma unroll
    for(int nt=0;nt<8;nt++) o[nt]=(f32x4){0.f,0.f,0.f,0.f};
    #pragma unroll
    for(int jc=0;jc<4;jc++){
        bf16x8 a=*(const bf16x8*)(LB+(size_t)(m0+l15)*136+jc*32+kg*8);
        #pragma unroll
        for(int nt=0;nt<8;nt++){
            bf16x8 b=*(const bf16x8*)(LA+(size_t)(nt*16+l15)*136+jc*32+kg*8);
            o[nt]=__builtin_amdgcn_mfma_f32_16x16x32_bf16(a,b,o[nt],0,0,0);
        }
    }
    int c0=m0+kg*4;
    #pragma unroll
    for(int r=0;r<4;r++){
        float sm=0.f;
        #pragma unroll
        for(int nt=0;nt<8;nt++){ float v=o[nt][r]; if(nt==7&&l15>8) v=0.f; sm+=v; }
        sm+=__shfl_xor(sm,1); sm+=__shfl_xor(sm,2); sm+=__shfl_xor(sm,4); sm+=__shfl_xor(sm,8);
        if(l15==0) fl[c0+r]=sm*(1.f/121.f);
    }
    __syncthreads();
    if(t<C_){
        float a=bgf[t];
        #pragma unroll 8
        for(int k=0;k<C_;k++) a+=wgT[k*C_+t]*fl[k];
        fl[C_+t]=1.f/(1.f+__expf(-a));
    }
    __syncthreads();
    float gg[4];
    #pragma unroll
    for(int r=0;r<4;r++) gg[r]=fl[C_+c0+r];
    #pragma unroll
    for(int nt=0;nt<8;nt++){
        #pragma unroll
        for(int r=0;r<4;r++) res[nt][r]+=w1m*o[nt][r]*gg[r];
    }
}

// ---------- fused intra + left-msg + right-msg per (s,b), 512 threads ----------
// comb = w*(alpha*attn(h)+h) + (1-w)*(m_l*g_l*maskL + m_r*g_r*maskR), written ONCE (coalesced via LDS)
__global__ __launch_bounds__(512) void attn_all(
    bf16t* __restrict__ comb, const bf16t* __restrict__ hT,
    const bf16t* __restrict__ WqT, const bf16t* __restrict__ WkT, const bf16t* __restrict__ WvT,
    const float* __restrict__ bq, const float* __restrict__ bk, const float* __restrict__ bv,
    const bf16t* __restrict__ W2T, const float* __restrict__ b2l, const float* __restrict__ b2r,
    const float* __restrict__ wgT, const float* __restrict__ bgf,
    const float* __restrict__ alphap, const float* __restrict__ wp)
{
    __shared__ bf16t LA[128*136];
    __shared__ bf16t LB[128*136];
    __shared__ float fl[256];
    int sb=blockIdx.x, t=threadIdx.x, lane=t&63, w=t>>6;
    int l15=lane&15, kg=lane>>4;
    const bf16t* hp=hT+(size_t)sb*CP_;
    int ocr=w>>2, pcr=w&3;
    int m0=w*16;
    bf16x8 hreg[4][2];
    #pragma unroll
    for(int kc=0;kc<4;kc++){
        #pragma unroll
        for(int nt=0;nt<2;nt++)
            hreg[kc][nt]=*(const bf16x8*)(hp+(size_t)(pcr*32+nt*16+l15)*C_+kc*32+kg*8);
    }
    bf16x8 areg[4];
    #pragma unroll
    for(int kc=0;kc<4;kc++)
        areg[kc]=*(const bf16x8*)(hp+(size_t)(m0+l15)*C_+kc*32+kg*8);

    f32x4 acc[4][2];
    // q -> LA [p][c]
    gemm24r(acc,WqT,hreg,ocr,l15,kg);
    #pragma unroll
    for(int mt=0;mt<4;mt++){
        int oc0=ocr*64+mt*16+kg*4;
        #pragma unroll
        for(int nt=0;nt<2;nt++){
            int p=pcr*32+nt*16+l15;
            us4 pk;
            #pragma unroll
            for(int r=0;r<4;r++) pk[r]=f2bu(acc[mt][nt][r]+bq[oc0+r]);
            *(us4*)(LA+p*136+oc0)=pk;
        }
    }
    // k -> LB [p][c]
    gemm24r(acc,WkT,hreg,ocr,l15,kg);
    #pragma unroll
    for(int mt=0;mt<4;mt++){
        int oc0=ocr*64+mt*16+kg*4;
        #pragma unroll
        for(int nt=0;nt<2;nt++){
            int p=pcr*32+nt*16+l15;
            us4 pk;
            #pragma unroll
            for(int r=0;r<4;r++) pk[r]=f2bu(acc[mt][nt][r]+bk[oc0+r]);
            *(us4*)(LB+p*136+oc0)=pk;
        }
    }
    __syncthreads();
    // QK^T
    f32x4 s[8];
    #pragma unroll
    for(int nt=0;nt<8;nt++) s[nt]=(f32x4){0.f,0.f,0.f,0.f};
    #pragma unroll
    for(int kc=0;kc<4;kc++){
        bf16x8 a=*(const bf16x8*)(LA+(size_t)(m0+l15)*136+kc*32+kg*8);
        #pragma unroll
        for(int nt=0;nt<8;nt++){
            bf16x8 b=*(const bf16x8*)(LB+(size_t)(nt*16+l15)*136+kc*32+kg*8);
            s[nt]=__builtin_amdgcn_mfma_f32_16x16x32_bf16(a,b,s[nt],0,0,0);
        }
    }
    const float scale=0.08838834764831845f;
    #pragma unroll
    for(int nt=0;nt<8;nt++){
        #pragma unroll
        for(int r=0;r<4;r++) s[nt][r]*=scale;
    }
    if(l15>=9){
        #pragma unroll
        for(int r=0;r<4;r++) s[7][r]=-3.0e38f;
    }
    #pragma unroll
    for(int r=0;r<4;r++){
        float mx=s[0][r];
        #pragma unroll
        for(int nt=1;nt<8;nt++) mx=fmaxf(mx,s[nt][r]);
        #pragma unroll
        for(int o=1;o<16;o<<=1) mx=fmaxf(mx,__shfl_xor(mx,o));
        float sm=0.f;
        #pragma unroll
        for(int nt=0;nt<8;nt++){ float e=__expf(s[nt][r]-mx); s[nt][r]=e; sm+=e; }
        #pragma unroll
        for(int o=1;o<16;o<<=1) sm+=__shfl_xor(sm,o);
        float rs=1.f/sm;
        #pragma unroll
        for(int nt=0;nt<8;nt++) s[nt][r]*=rs;
    }
    __syncthreads();   // q/k reads done
    // v -> LA natural [c][p]; P -> LB [p][j]
    gemm24r(acc,WvT,hreg,ocr,l15,kg);
    #pragma unroll
    for(int mt=0;mt<4;mt++){
        int oc0=ocr*64+mt*16+kg*4;
        #pragma unroll
        for(int nt=0;nt<2;nt++){
            int p=pcr*32+nt*16+l15;
            #pragma unroll
            for(int r=0;r<4;r++)
                LA[(oc0+r)*136+p]=__float2bfloat16(p<P_? acc[mt][nt][r]+bv[oc0+r] : 0.f);
        }
    }
    #pragma unroll
    for(int r=0;r<4;r++){
        int pr=m0+kg*4+r;
        #pragma unroll
        for(int nt=0;nt<8;nt++) LB[pr*136+nt*16+l15]=__float2bfloat16(s[nt][r]);
    }
    __syncthreads();
    // PV
    f32x4 res[8];
    #pragma unroll
    for(int nt=0;nt<8;nt++) res[nt]=(f32x4){0.f,0.f,0.f,0.f};
    #pragma unroll
    for(int jc=0;jc<4;jc++){
        bf16x8 a=*(const bf16x8*)(LA+(size_t)(m0+l15)*136+jc*32+kg*8);
        #pragma unroll
        for(int nt=0;nt<8;nt++){
            bf16x8 b=*(const bf16x8*)(LB+(size_t)(nt*16+l15)*136+jc*32+kg*8);
            res[nt]=__builtin_amdgcn_mfma_f32_16x16x32_bf16(a,b,res[nt],0,0,0);
        }
    }
    float al=*alphap, wv=*wp, w1m=1.f-wv;
    int c0=m0+kg*4;
    // res = w*(alpha*PV + h)
    #pragma unroll
    for(int nt=0;nt<8;nt++){
        int p=nt*16+l15;
        int pc=(p<P_)?p:(P_-1);
        us4 hv=*(const us4*)(hp+(size_t)pc*C_+c0);
        #pragma unroll
        for(int r=0;r<4;r++) res[nt][r]=wv*(al*res[nt][r]+b2f(hv[r]));
    }
    // message phases (block-uniform branches)
    if(sb>=B_)
        msg_phase(res,hT,sb,-B_,W2T,b2l,wgT,bgf,w1m,areg,LA,LB,fl,t,w,l15,kg,ocr,pcr);
    if(sb<SBn-B_)
        msg_phase(res,hT,sb, B_,W2T,b2r,wgT,bgf,w1m,areg,LA,LB,fl,t,w,l15,kg,ocr,pcr);
    // coalesced comb write: stage [p][128c] in LA, copy out contiguous
    __syncthreads();   // PV-phase LDS reads done
    unsigned short* tl=(unsigned short*)LA;
    #pragma unroll
    for(int nt=0;nt<8;nt++){
        int p=nt*16+l15;
        if(p>=P_) continue;
        us4 pk;
        #pragma unroll
        for(int r=0;r<4;r++) pk[r]=f2bu(res[nt][r]);
        *(us4*)(tl+p*C_+c0)=pk;
    }
    __syncthreads();
    bf16t* ob=comb+(size_t)sb*CP_;
    for(int j=t;j<1936;j+=512)
        *(bf16x8*)(ob+j*8)=*(const bf16x8*)(tl+j*8);
}

// ---------- shared MFMA-step macros for 3x3 convs (2-mt small tile) ----------
#define LOADA2(bidx, widx) { \
    _Pragma("unroll") \
    for(int mt=0;mt<2;mt++) abuf[bidx][mt]=*(const bf16x8*)(Wt+(size_t)(widx)*(OC*32)+mt*512+base_lane); }
#define STEP2(lbase, bidx, doff) { \
    bf16x8 bb[4]; \
    _Pragma("unroll") \
    for(int nt=0;nt<4;nt++) bb[nt]=*(const bf16x8*)((lbase)+boff[nt]+(doff)); \
    __builtin_amdgcn_s_setprio(1); \
    _Pragma("unroll") \
    for(int mt=0;mt<2;mt++){ \
        _Pragma("unroll") \
        for(int nt=0;nt<4;nt++) \
            acc[mt][nt]=__builtin_amdgcn_mfma_f32_16x16x32_bf16(abuf[bidx][mt],bb[nt],acc[mt][nt],0,0,0); } \
    __builtin_amdgcn_s_setprio(0); }

// ---------- zr conv: 1024 threads, 16 waves, wave tile 32oc x 64p ----------
#define SLOADZ(stg) { \
    const bf16t* ssrc=(((stg)<2)? in0T:in1T)+(size_t)sb*CP_+((stg)&1)*64; \
    if(sv0) sreg0=*(const bf16x8*)(ssrc+(size_t)sp0*C_+(t&7)*8); }
#define SWRITEZ(lbase) { \
    if(sv0) *(bf16x8*)((lbase)+spix0*72+(t&7)*8)=sreg0; }

__global__ __launch_bounds__(1024) void conv3_zr(
    bf16t* __restrict__ o0, bf16t* __restrict__ o1,
    const bf16t* __restrict__ in0T, const bf16t* __restrict__ in1T,
    const bf16t* __restrict__ Wt, const float* __restrict__ bias,
    const bf16t* __restrict__ hTb)
{
    constexpr int OC=256;
    __shared__ bf16t lin[2*12176];
    int sb=blockIdx.x;
    int t=threadIdx.x, lane=t&63, w=t>>6;      // w 0..15
    int ocb=(w>=8)?128:0; int w2=w&7;
    int ocr=w2>>1, pcr=w2&1, l15=lane&15, kg=lane>>4;
    int boff[4]; bool pv_[4];
    #pragma unroll
    for(int nt=0;nt<4;nt++){
        int p=pcr*64+nt*16+l15;
        pv_[nt]=(p<P_); int pc=pv_[nt]?p:(P_-1);
        boff[nt]=((pc/11)*13+(pc%11))*72+kg*8;
    }
    f32x4 acc[2][4];
    #pragma unroll
    for(int i=0;i<2;i++){
        #pragma unroll
        for(int j=0;j<4;j++) acc[i][j]=(f32x4){0.f,0.f,0.f,0.f};
    }
    int base_lane=(ocb+ocr*32+l15)*32+kg*8;
    bf16x8 abuf[4][2];
    bf16x8 sreg0;
    bool sv0=(t<968);
    int sp0=(t<968)? (t>>3):120;
    int spix0=(sp0/11+1)*13+(sp0%11)+1;
    LOADA2(0,0); LOADA2(1,1); LOADA2(2,8); LOADA2(3,9);
    SLOADZ(0);
    // zero border pixels (48) in BOTH buffers: 768 chunks
    {
        bf16x8 z;
        #pragma unroll
        for(int e=0;e<8;e++) z[e]=0;
        if(t<768){
            int half=t>=384; int i2=t-half*384;
            int bi=i2>>3, cc=(i2&7)*8;
            int pix;
            if(bi<13) pix=bi;
            else if(bi<26) pix=156+(bi-13);
            else { int j2=bi-26; pix=(1+(j2>>1))*13+((j2&1)?12:0); }
            *(bf16x8*)(lin+half*12176+pix*72+cc)=z;
        }
    }
    SWRITEZ(lin);
    __syncthreads();
    #pragma unroll
    for(int st=0; st<4; ++st){
        if(st<3) SLOADZ(st+1);
        bf16t* lbase=lin+(st&1)*12176;
        #pragma unroll
        for(int k=0;k<18;k++){
            int s=st*18+k;
            int tap=k>>1, l=k&1;
            int doff=((tap/3)*13+(tap%3))*72+l*32;
            STEP2(lbase, s&3, doff);
            if(s<68){
                int s4=s+4, st4=s4/18, k4=s4-st4*18, tap4=k4>>1, l4=k4&1;
                LOADA2(s&3, tap4*8+st4*2+l4);
            }
        }
        if(st<3){ SWRITEZ(lin+((st+1)&1)*12176); }
        __syncthreads();
    }
    // coalesced epilogue: stage Z then RH as [p][128c] in lin, copy out contiguous
    unsigned short* tl=(unsigned short*)lin;
    if(ocb==0){
        #pragma unroll
        for(int mt=0;mt<2;mt++){
            int ocl=ocr*32+mt*16+kg*4;
            #pragma unroll
            for(int nt=0;nt<4;nt++){
                if(!pv_[nt]) continue;
                int p=pcr*64+nt*16+l15;
                us4 pk;
                #pragma unroll
                for(int r=0;r<4;r++){ float a=acc[mt][nt][r]+bias[ocl+r]; pk[r]=f2bu(1.f/(1.f+__expf(-a))); }
                *(us4*)(tl+p*C_+ocl)=pk;
            }
        }
    }
    __syncthreads();
    {
        bf16t* zb=o0+(size_t)sb*CP_;
        *(bf16x8*)(zb+t*8)=*(const bf16x8*)(tl+t*8);
        if(t<912) *(bf16x8*)(zb+(t+1024)*8)=*(const bf16x8*)(tl+(t+1024)*8);
    }
    __syncthreads();
    if(ocb==128){
        #pragma unroll
        for(int mt=0;mt<2;mt++){
            int ocl=ocr*32+mt*16+kg*4;
            #pragma unroll
            for(int nt=0;nt<4;nt++){
                if(!pv_[nt]) continue;
                int p=pcr*64+nt*16+l15;
                size_t tb=(size_t)sb*CP_+(size_t)p*C_+ocl;
                us4 hv=*(const us4*)(hTb+tb);
                us4 pk;
                #pragma unroll
                for(int r=0;r<4;r++){ float a=acc[mt][nt][r]+bias[128+ocl+r]; float sg=1.f/(1.f+__expf(-a)); pk[r]=f2bu(sg*b2f(hv[r])); }
                *(us4*)(tl+p*C_+ocl)=pk;
            }
        }
    }
    __syncthreads();
    {
        bf16t* rb=o1+(size_t)sb*CP_;
        *(bf16x8*)(rb+t*8)=*(const bf16x8*)(tl+t*8);
        if(t<912) *(bf16x8*)(rb+(t+1024)*8)=*(const bf16x8*)(tl+(t+1024)*8);
    }
}

// ---------- hhat conv + GRU-combine + LayerNorm: 512 threads, wave tile 32oc x 64p ----------
#define SLOADH(stg) { \
    const bf16t* ssrc=(((stg)<2)? in0T:in1T)+(size_t)sb*CP_+((stg)&1)*64; \
    sreg[0]=*(const bf16x8*)(ssrc+(size_t)(t>>3)*C_+(t&7)*8); \
    if(sv1) sreg[1]=*(const bf16x8*)(ssrc+(size_t)sp1*C_+(t&7)*8); }
#define SWRITEH(lbase) { \
    *(bf16x8*)((lbase)+spix0*72+(t&7)*8)=sreg[0]; \
    if(sv1) *(bf16x8*)((lbase)+spix1*72+(t&7)*8)=sreg[1]; }

__global__ __launch_bounds__(512,4) void conv3_hh(
    bf16t* __restrict__ o0,
    const bf16t* __restrict__ in0T, const bf16t* __restrict__ in1T,
    const bf16t* __restrict__ Wt, const float* __restrict__ bias,
    const bf16t* __restrict__ zT, const bf16t* __restrict__ hTb,
    const float* __restrict__ gamT, const float* __restrict__ betT)
{
    constexpr int OC=128;
    __shared__ bf16t lin[2*12176];
    __shared__ float red[16];
    int sb=blockIdx.x;
    int t=threadIdx.x, lane=t&63, w=t>>6;      // w 0..7
    int ocr=w>>1, pcr=w&1, l15=lane&15, kg=lane>>4;
    int boff[4]; bool pv_[4];
    #pragma unroll
    for(int nt=0;nt<4;nt++){
        int p=pcr*64+nt*16+l15;
        pv_[nt]=(p<P_); int pc=pv_[nt]?p:(P_-1);
        boff[nt]=((pc/11)*13+(pc%11))*72+kg*8;
    }
    f32x4 acc[2][4];
    #pragma unroll
    for(int i=0;i<2;i++){
        #pragma unroll
        for(int j=0;j<4;j++) acc[i][j]=(f32x4){0.f,0.f,0.f,0.f};
    }
    int base_lane=(ocr*32+l15)*32+kg*8;
    bf16x8 abuf[4][2];
    bf16x8 sreg[2];
    bool sv1=((t+512)<968);
    int sp0=t>>3, sp1=(t+512)>>3;
    if(sp1>120) sp1=120;
    int spix0=(sp0/11+1)*13+(sp0%11)+1;
    int spix1=(sp1/11+1)*13+(sp1%11)+1;
    LOADA2(0,0); LOADA2(1,1); LOADA2(2,8); LOADA2(3,9);
    SLOADH(0);
    {
        bf16x8 z;
        #pragma unroll
        for(int e=0;e<8;e++) z[e]=0;
        for(int i=t;i<768;i+=512){
            int half=i>=384; int i2=i-half*384;
            int bi=i2>>3, cc=(i2&7)*8;
            int pix;
            if(bi<13) pix=bi;
            else if(bi<26) pix=156+(bi-13);
            else { int j2=bi-26; pix=(1+(j2>>1))*13+((j2&1)?12:0); }
            *(bf16x8*)(lin+half*12176+pix*72+cc)=z;
        }
    }
    SWRITEH(lin);
    __syncthreads();
    #pragma unroll
    for(int st=0; st<4; ++st){
        if(st<3) SLOADH(st+1);
        bf16t* lbase=lin+(st&1)*12176;
        #pragma unroll
        for(int k=0;k<18;k++){
            int s=st*18+k;
            int tap=k>>1, l=k&1;
            int doff=((tap/3)*13+(tap%3))*72+l*32;
            STEP2(lbase, s&3, doff);
            if(s<68){
                int s4=s+4, st4=s4/18, k4=s4-st4*18, tap4=k4>>1, l4=k4&1;
                LOADA2(s&3, tap4*8+st4*2+l4);
            }
        }
        if(st<3){ SWRITEH(lin+((st+1)&1)*12176); }
        __syncthreads();
    }
    // GRU combine -> NH in LDS [p][c], LayerNorm, write new hT
    float ls=0.f, ls2=0.f;
    #pragma unroll
    for(int mt=0;mt<2;mt++){
        int ocl=ocr*32+mt*16+kg*4;
        #pragma unroll
        for(int nt=0;nt<4;nt++){
            if(!pv_[nt]) continue;
            int p=pcr*64+nt*16+l15;
            size_t tb=(size_t)sb*CP_+(size_t)p*C_+ocl;
            us4 hv=*(const us4*)(hTb+tb);
            us4 zv=*(const us4*)(zT+tb);
            us4 pk;
            #pragma unroll
            for(int r=0;r<4;r++){
                float a=acc[mt][nt][r]+bias[ocl+r];
                float ht=tanhf(a);
                float z=b2f(zv[r]), h=b2f(hv[r]);
                unsigned short u=f2bu((1.f-z)*h+z*ht+h);
                pk[r]=u;
                float nr=b2f(u); ls+=nr; ls2+=nr*nr;
            }
            *(us4*)((unsigned short*)lin + p*C_+ocl)=pk;
        }
    }
    #pragma unroll
    for(int o=32;o;o>>=1){ ls+=__shfl_xor(ls,o); ls2+=__shfl_xor(ls2,o); }
    if(lane==0){ red[w]=ls; red[8+w]=ls2; }
    __syncthreads();
    float Sx=0.f,Sx2=0.f;
    #pragma unroll
    for(int i=0;i<8;i++){ Sx+=red[i]; Sx2+=red[8+i]; }
    float mu=Sx*(1.f/(float)CP_);
    float var=Sx2*(1.f/(float)CP_)-mu*mu;
    float rstd=rsqrtf(var+1e-5f);
    bf16t* ho=o0+(size_t)sb*CP_;
    const unsigned short* tl=(const unsigned short*)lin;
    for(int j=t;j<1936;j+=512){
        int base=j*8;
        bf16x8 ovec;
        #pragma unroll
        for(int e=0;e<8;e++){
            float v=(b2f(tl[base+e])-mu)*rstd*gamT[base+e]+betT[base+e];
            ovec[e]=(short)f2bu(v);
        }
        *(bf16x8*)(ho+base)=ovec;
    }
}

// ---------- final: hT [p][c] -> natural [c][p] output ----------
__global__ __launch_bounds__(256) void finalT_kernel(void* __restrict__ fout, const bf16t* __restrict__ hT, const int* __restrict__ flag){
    __shared__ bf16t tl[CP_];
    int sb=blockIdx.x, t=threadIdx.x, f=*flag;
    for(int i=t;i<CP_;i+=256) tl[i]=hT[(size_t)sb*CP_+i];
    __syncthreads();
    for(int i=t;i<CP_;i+=256){
        int c=i/P_, p=i-c*P_;
        float v=ldb(tl+p*C_+c);
        size_t oi=(size_t)sb*CP_+i;
        if(f) ((float*)fout)[oi]=v;
        else  ((bf16t*)fout)[oi]=__float2bfloat16(v);
    }
}

extern "C" void kernel_launch(void* const* d_in, const int* in_sizes, int n_in,
                              void* d_out, int out_size, void* d_ws, size_t ws_size,
                              hipStream_t stream) {
    (void)in_sizes; (void)n_in; (void)out_size;
    char* base=(char*)d_ws;
    size_t off=0;
    auto alloc=[&](size_t bytes){ void* p=base+off; off+=(bytes+255)&~(size_t)255; return p; };
    bf16t* b1=(bf16t*)alloc((size_t)NEl*2+8192);          // hT
    bf16t* b2=(bf16t*)alloc((size_t)NEl*2+8192);          // comb
    bf16t* b3=(bf16t*)alloc((size_t)NEl*2+8192);          // RH
    bf16t* b4=(bf16t*)d_out;                              // Z / final
    bf16t* wqT=(bf16t*)alloc(16384*2);
    bf16t* wkT=(bf16t*)alloc(16384*2);
    bf16t* wvT=(bf16t*)alloc(16384*2);
    bf16t* w2T=(bf16t*)alloc(16384*2);
    bf16t* wzrT=(bf16t*)alloc((size_t)589824*2);
    bf16t* whT =(bf16t*)alloc((size_t)294912*2);
    float* W2f=(float*)alloc(16384*4);
    float* b2l=(float*)alloc(128*4); float* b2r=(float*)alloc(128*4);
    float* bqf=(float*)alloc(128*4); float* bkf=(float*)alloc(128*4); float* bvf=(float*)alloc(128*4);
    float* bzrf=(float*)alloc(256*4); float* bhf=(float*)alloc(128*4);
    float* gamT=(float*)alloc(15488*4); float* betT=(float*)alloc(15488*4);
    float* wgTf=(float*)alloc(16384*4); float* bgf2=(float*)alloc(128*4);
    float* alphaf=(float*)alloc(4); float* weightf=(float*)alloc(4);
    int* flag=(int*)alloc(4);
    if(ws_size<off) return;  // ~100MB needed

    detect_kernel<<<1,64,0,stream>>>((const unsigned short*)d_in[0],flag);
    cvtT_kernel<<<SBn,256,0,stream>>>(b1,d_in[0],flag);
    prep_w1t<1><<<64,256,0,stream>>>(wqT,d_in[1],flag);
    cvt_kernel<<<1,128,0,stream>>>(bqf,d_in[2],128,flag);
    prep_w1t<1><<<64,256,0,stream>>>(wkT,d_in[3],flag);
    cvt_kernel<<<1,128,0,stream>>>(bkf,d_in[4],128,flag);
    prep_w1t<1><<<64,256,0,stream>>>(wvT,d_in[5],flag);
    cvt_kernel<<<1,128,0,stream>>>(bvf,d_in[6],128,flag);
    cvt_kernel<<<1,64,0,stream>>>(alphaf,d_in[7],1,flag);
    prep_msg_kernel<<<C_,C_,0,stream>>>(W2f,b2l,b2r,d_in[10],d_in[8],d_in[9],flag);
    prep_w1t<0><<<64,256,0,stream>>>(w2T,W2f,flag);
    cvt_kernel<<<1,64,0,stream>>>(weightf,d_in[11],1,flag);
    prep_wgt<<<64,256,0,stream>>>(wgTf,bgf2,d_in[12],d_in[13],flag);
    prep_w3t<<<(256*2304+255)/256,256,0,stream>>>(wzrT,d_in[14],flag,256);
    cvt_kernel<<<1,256,0,stream>>>(bzrf,d_in[15],256,flag);
    prep_w3t<<<(128*2304+255)/256,256,0,stream>>>(whT,d_in[16],flag,128);
    cvt_kernel<<<1,128,0,stream>>>(bhf,d_in[17],128,flag);
    prep_gbt<<<(CP_+255)/256,256,0,stream>>>(gamT,betT,d_in[18],d_in[19],flag);

    for(int it=0; it<3; ++it){
        // comb(b2) = w*(alpha*attn(h)+h) + (1-w)*(msgL+msgR), one kernel, coalesced write
        attn_all<<<SBn,512,0,stream>>>(b2,b1,wqT,wkT,wvT,bqf,bkf,bvf,
                                       w2T,b2l,b2r,wgTf,bgf2,alphaf,weightf);
        // GRU: zr([comb|h]) -> Z->b4, RH->b3 (1024-thr, small-tile waves)
        conv3_zr<<<SBn,1024,0,stream>>>(b4,b3,b2,b1,wzrT,bzrf,b1);
        // hhat([comb|RH]) + GRU combine + LN -> new hT (b1)
        conv3_hh<<<SBn,512,0,stream>>>(b1,b2,b3,whT,bhf,b4,b1,gamT,betT);
    }
    finalT_kernel<<<SBn,256,0,stream>>>(d_out,b1,flag);
}